// Round 2
// baseline (465.732 us; speedup 1.0000x reference)
//
#include <hip/hip_runtime.h>
#include <hip/hip_bf16.h>

// LSH Attention, MI355X gfx950.
// Pipeline:
//  1) cast x -> bf16; transpose+cast Wq/Wk/Wv/Wo -> bf16 [n][k]
//  2) P = W(:, h*64:h*64+64) @ R[n]^T in fp32 (bucket projection fold)
//  3) bf16 MFMA GEMMs: Q,K -> [B,H,S,DK], V -> [B,H,DK,S] (transposed)
//  4) fp32 logits = x@P + b.R, fused argmax -> qb/kb  (fp32 path: bucket
//     flips vs reference are the dominant correctness hazard)
//  5) flash attention with bucket-equality mask (bf16 MFMA, fp32 softmax)
//  6) bf16 MFMA output GEMM -> fp32 d_out
//
// MFMA 16x16x32 bf16 layouts (verified in guide):
//  A: lane holds A[m=lane&15][k=(lane>>4)*8+j]
//  B: lane holds B[k=(lane>>4)*8+j][n=lane&15]
//  C/D: lane holds D[m=(lane>>4)*4+r][n=lane&15]

typedef __bf16 bf16;
typedef __bf16 bf16x8 __attribute__((ext_vector_type(8)));
typedef __bf16 bf16x4 __attribute__((ext_vector_type(4)));
typedef float f32x4 __attribute__((ext_vector_type(4)));

#define DEV static __device__ __forceinline__

DEV f32x4 zero4() { f32x4 z; z[0]=0.f; z[1]=0.f; z[2]=0.f; z[3]=0.f; return z; }

DEV f32x4 mfma_bf16(bf16x8 a, bf16x8 b, f32x4 c) {
  return __builtin_amdgcn_mfma_f32_16x16x32_bf16(a, b, c, 0, 0, 0);
}

#define B_  2
#define S_  2048
#define D_  1024
#define H_  16
#define NH_ 8
#define DK_ 64
#define M_  4096   // B_*S_

// ---------------------------------------------------------------- prep
__global__ void k_cast_x(const float* __restrict__ x, bf16* __restrict__ xb) {
  int i = (blockIdx.x * 256 + threadIdx.x) * 4;
  f32x4 v = *(const f32x4*)(x + i);
  bf16x4 o; o[0]=(bf16)v[0]; o[1]=(bf16)v[1]; o[2]=(bf16)v[2]; o[3]=(bf16)v[3];
  *(bf16x4*)(xb + i) = o;
}

// W [k][n] fp32 -> Wt [n][k] bf16 (64x64 LDS tile transpose)
__global__ void k_transW(const float* __restrict__ W, bf16* __restrict__ Wt) {
  __shared__ float tile[64][65];
  int k0 = blockIdx.x * 64, n0 = blockIdx.y * 64;
  int c = threadIdx.x & 63, r4 = threadIdx.x >> 6;
#pragma unroll
  for (int i = 0; i < 16; i++) {
    int r = r4 * 16 + i;
    tile[r][c] = W[(k0 + r) * D_ + n0 + c];
  }
  __syncthreads();
#pragma unroll
  for (int i = 0; i < 16; i++) {
    int r = r4 * 16 + i;
    Wt[(n0 + r) * D_ + k0 + c] = (bf16)tile[c][r];
  }
}

// P[d][h*8+n] = sum_k W[d][h*64+k] * R[n][k]   (fp32)
__global__ void k_computeP(const float* __restrict__ W, const float* __restrict__ R,
                           float* __restrict__ P) {
  int d = blockIdx.x;
  int t = threadIdx.x;           // 128 threads = h*8+n
  int h = t >> 3, n = t & 7;
  const float* wrow = W + d * D_ + h * 64;
  const float* rrow = R + n * 64;
  float acc = 0.f;
#pragma unroll 8
  for (int k = 0; k < 64; k++) acc += wrow[k] * rrow[k];
  P[d * 128 + t] = acc;
}

// bterm[0:128]=bq.R, [128:256]=bk.R
__global__ void k_bterm(const float* __restrict__ bq, const float* __restrict__ bk,
                        const float* __restrict__ R, float* __restrict__ bt) {
  int t = threadIdx.x;  // 256
  const float* b = (t < 128) ? bq : bk;
  int hn = t & 127, h = hn >> 3, n = hn & 7;
  float acc = 0.f;
#pragma unroll 8
  for (int k = 0; k < 64; k++) acc += b[h * 64 + k] * R[n * 64 + k];
  bt[t] = acc;
}

// ---------------------------------------------------------------- bf16 GEMM
// C[m][n] = sum_k A[m][k]*Bt[n][k] + bias[n];  M=4096, N=1024, K=1024
// tile 128(m) x 64(n), 256 threads (wave w owns rows w*32..w*32+31)
// MODE 0: out bf16 [B,H,S,DK];  MODE 1: out bf16 [B,H,DK,S];  MODE 2: out fp32 [m][n]
template <int MODE>
__global__ __launch_bounds__(256) void k_gemm(const bf16* __restrict__ A,
                                              const bf16* __restrict__ Bt,
                                              const float* __restrict__ bias,
                                              void* __restrict__ out) {
  constexpr int LDA = 40;  // bf16 row stride: 80B -> 2-way (free) LDS conflicts
  __shared__ bf16 Al[128 * LDA];
  __shared__ bf16 Bl[64 * LDA];
  const int t = threadIdx.x;
  const int m0 = blockIdx.x * 128;
  const int n0 = blockIdx.y * 64;
  const int lane = t & 63, w = t >> 6;
  const int lm = lane & 15, qd = lane >> 4;

  f32x4 acc[2][4];
#pragma unroll
  for (int i = 0; i < 2; i++)
#pragma unroll
    for (int j = 0; j < 4; j++) acc[i][j] = zero4();

  for (int k0 = 0; k0 < D_; k0 += 32) {
    __syncthreads();
    // stage A: 128 rows x 4 segs(16B) = 512 segs; B: 256 segs
#pragma unroll
    for (int ss = 0; ss < 2; ss++) {
      int seg = t + ss * 256;
      int row = seg >> 2, sg = seg & 3;
      *(bf16x8*)&Al[row * LDA + sg * 8] =
          *(const bf16x8*)&A[(m0 + row) * D_ + k0 + sg * 8];
    }
    {
      int row = t >> 2, sg = t & 3;
      *(bf16x8*)&Bl[row * LDA + sg * 8] =
          *(const bf16x8*)&Bt[(n0 + row) * D_ + k0 + sg * 8];
    }
    __syncthreads();
    bf16x8 af[2], bfr[4];
#pragma unroll
    for (int i = 0; i < 2; i++)
      af[i] = *(const bf16x8*)&Al[(w * 32 + i * 16 + lm) * LDA + qd * 8];
#pragma unroll
    for (int j = 0; j < 4; j++)
      bfr[j] = *(const bf16x8*)&Bl[(j * 16 + lm) * LDA + qd * 8];
#pragma unroll
    for (int i = 0; i < 2; i++)
#pragma unroll
      for (int j = 0; j < 4; j++) acc[i][j] = mfma_bf16(af[i], bfr[j], acc[i][j]);
  }

#pragma unroll
  for (int i = 0; i < 2; i++)
#pragma unroll
    for (int j = 0; j < 4; j++) {
      int n = n0 + j * 16 + lm;
      float bv = bias[n];
      int mbase = m0 + w * 32 + i * 16 + qd * 4;  // rows mbase..mbase+3
      if (MODE == 1) {
        int bb = mbase >> 11, s = mbase & 2047;
        int h = n >> 6, d = n & 63;
        bf16x4 pk;
#pragma unroll
        for (int r = 0; r < 4; r++) pk[r] = (bf16)(acc[i][j][r] + bv);
        *(bf16x4*)((bf16*)out + (((bb * H_ + h) * DK_ + d) * S_ + s)) = pk;
      } else {
#pragma unroll
        for (int r = 0; r < 4; r++) {
          int m = mbase + r;
          float v = acc[i][j][r] + bv;
          if (MODE == 0) {
            int bb = m >> 11, s = m & 2047, h = n >> 6, d = n & 63;
            ((bf16*)out)[((bb * H_ + h) * S_ + s) * DK_ + d] = (bf16)v;
          } else {
            ((float*)out)[m * D_ + n] = v;
          }
        }
      }
    }
}

// ---------------------------------------------------------------- logits + argmax
// L[row][c] = sum_d x[row][d]*P[d][c] + bterm[c];  argmax over n within head -> buckets
__global__ __launch_bounds__(256) void k_logits(const float* __restrict__ x,
                                                const float* __restrict__ Pq,
                                                const float* __restrict__ Pk,
                                                const float* __restrict__ bt,
                                                int* __restrict__ qb,
                                                int* __restrict__ kb) {
  const int sel = blockIdx.y;
  const float* P = sel ? Pk : Pq;
  const float* bterm = bt + sel * 128;
  int* outb = sel ? kb : qb;
  const int r0 = blockIdx.x * 16;
  const int c = threadIdx.x & 127, rh = threadIdx.x >> 7;

  float acc[8];
#pragma unroll
  for (int i = 0; i < 8; i++) acc[i] = 0.f;
  const float* xr = x + (r0 + rh * 8) * D_;
  for (int k = 0; k < D_; k += 4) {
    float p0 = P[(k + 0) * 128 + c];
    float p1 = P[(k + 1) * 128 + c];
    float p2 = P[(k + 2) * 128 + c];
    float p3 = P[(k + 3) * 128 + c];
#pragma unroll
    for (int i = 0; i < 8; i++) {
      f32x4 xv = *(const f32x4*)(xr + i * D_ + k);
      acc[i] += (xv[0] * p0 + xv[1] * p1) + (xv[2] * p2 + xv[3] * p3);
    }
  }
  __shared__ float L[16][128];
#pragma unroll
  for (int i = 0; i < 8; i++) L[rh * 8 + i][c] = acc[i] + bterm[c];
  __syncthreads();
  int row = threadIdx.x >> 4, hh = threadIdx.x & 15;
  float best = L[row][hh * 8];
  int bi = 0;
#pragma unroll
  for (int n = 1; n < 8; n++) {
    float v = L[row][hh * 8 + n];
    if (v > best) { best = v; bi = n; }  // strict > keeps first (np.argmax ties)
  }
  int rg = r0 + row, bb = rg >> 11, s = rg & 2047;
  outb[(bb * H_ + hh) * S_ + s] = bi;
}

// ---------------------------------------------------------------- attention
// one block: (b, h, 64 q-rows); wave w owns q-rows i0+w*16..+15
__global__ __launch_bounds__(256) void k_attn(const bf16* __restrict__ Q,
                                              const bf16* __restrict__ K,
                                              const bf16* __restrict__ Vt,
                                              const int* __restrict__ qb,
                                              const int* __restrict__ kb,
                                              bf16* __restrict__ O) {
  constexpr int LDK = 72;  // 144B row stride: 16B-aligned, 2-way (free) conflicts
  __shared__ bf16 Kl[64 * LDK];
  __shared__ bf16 Vl[64 * LDK];
  __shared__ bf16 Pl[4 * 16 * LDK];
  __shared__ int kbl[64];
  const int t = threadIdx.x;
  const int i0 = blockIdx.x * 64;
  const int h = blockIdx.y, b = blockIdx.z;
  const int lane = t & 63, w = t >> 6;
  const int lm = lane & 15, qd = lane >> 4;
  const int bh = b * H_ + h;

  const bf16* Qp = Q + (bh * S_ + i0 + w * 16 + lm) * DK_;
  bf16x8 qf0 = *(const bf16x8*)(Qp + qd * 8);
  bf16x8 qf1 = *(const bf16x8*)(Qp + 32 + qd * 8);

  int qbv[4];
#pragma unroll
  for (int r = 0; r < 4; r++) qbv[r] = qb[bh * S_ + i0 + w * 16 + qd * 4 + r];

  f32x4 oacc[4];
  float mrun[4], lrun[4];
#pragma unroll
  for (int nb = 0; nb < 4; nb++) oacc[nb] = zero4();
#pragma unroll
  for (int r = 0; r < 4; r++) { mrun[r] = -1e30f; lrun[r] = 0.f; }

  const bf16* Kbase = K + bh * S_ * DK_;
  const bf16* Vbase = Vt + bh * DK_ * S_;
  const int* kbbase = kb + bh * S_;

  for (int j0 = 0; j0 < S_; j0 += 64) {
    __syncthreads();
    // stage K tile (64 keys x 64 dims) and V tile (64 dims x 64 keys):
    // 64 rows x 8 segs(16B) = 512 segs each, 2 rounds of 256 threads
#pragma unroll
    for (int ss = 0; ss < 2; ss++) {
      int seg = t + ss * 256;
      int row = seg >> 3, sg = seg & 7;
      *(bf16x8*)&Kl[row * LDK + sg * 8] =
          *(const bf16x8*)&Kbase[(j0 + row) * DK_ + sg * 8];
      *(bf16x8*)&Vl[row * LDK + sg * 8] =
          *(const bf16x8*)&Vbase[row * S_ + j0 + sg * 8];
    }
    if (t < 64) kbl[t] = kbbase[j0 + t];
    __syncthreads();

    // scores 16x64 per wave (C-layout: row=qd*4+r, col=nb*16+lm)
    f32x4 sc[4];
#pragma unroll
    for (int nb = 0; nb < 4; nb++) {
      bf16x8 kf0 = *(const bf16x8*)&Kl[(nb * 16 + lm) * LDK + qd * 8];
      bf16x8 kf1 = *(const bf16x8*)&Kl[(nb * 16 + lm) * LDK + 32 + qd * 8];
      f32x4 z = zero4();
      z = mfma_bf16(qf0, kf0, z);
      z = mfma_bf16(qf1, kf1, z);
      sc[nb] = z;
    }
    // bucket mask + scale 1/sqrt(64)
#pragma unroll
    for (int nb = 0; nb < 4; nb++) {
      int kv = kbl[nb * 16 + lm];
#pragma unroll
      for (int r = 0; r < 4; r++)
        sc[nb][r] = (qbv[r] == kv) ? sc[nb][r] * 0.125f : -1e30f;
    }
    // online softmax
    float mnew[4], alpha[4], rs[4];
#pragma unroll
    for (int r = 0; r < 4; r++) {
      float tm = fmaxf(fmaxf(sc[0][r], sc[1][r]), fmaxf(sc[2][r], sc[3][r]));
      tm = fmaxf(tm, __shfl_xor(tm, 1));
      tm = fmaxf(tm, __shfl_xor(tm, 2));
      tm = fmaxf(tm, __shfl_xor(tm, 4));
      tm = fmaxf(tm, __shfl_xor(tm, 8));
      mnew[r] = fmaxf(mrun[r], tm);
      alpha[r] = __expf(mrun[r] - mnew[r]);  // both -1e30 -> exp(0)=1, harmless
      mrun[r] = mnew[r];
      rs[r] = 0.f;
    }
    // masked entries contribute EXACTLY 0 (guards all-masked tiles where
    // mnew is still -1e30 and exp(sc-mnew) would be exp(0)=1)
#pragma unroll
    for (int nb = 0; nb < 4; nb++)
#pragma unroll
      for (int r = 0; r < 4; r++) {
        float p = (sc[nb][r] > -1e29f) ? __expf(sc[nb][r] - mnew[r]) : 0.f;
        sc[nb][r] = p;
        rs[r] += p;
      }
#pragma unroll
    for (int r = 0; r < 4; r++) {
      float s = rs[r];
      s += __shfl_xor(s, 1);
      s += __shfl_xor(s, 2);
      s += __shfl_xor(s, 4);
      s += __shfl_xor(s, 8);
      lrun[r] = lrun[r] * alpha[r] + s;
    }
#pragma unroll
    for (int nb = 0; nb < 4; nb++)
#pragma unroll
      for (int r = 0; r < 4; r++) oacc[nb][r] *= alpha[r];
    // P: C-layout -> A-layout via LDS
#pragma unroll
    for (int nb = 0; nb < 4; nb++)
#pragma unroll
      for (int r = 0; r < 4; r++)
        Pl[(w * 16 + qd * 4 + r) * LDK + nb * 16 + lm] = (bf16)sc[nb][r];
    __syncthreads();
    bf16x8 pa0 = *(const bf16x8*)&Pl[(w * 16 + lm) * LDK + qd * 8];
    bf16x8 pa1 = *(const bf16x8*)&Pl[(w * 16 + lm) * LDK + 32 + qd * 8];
#pragma unroll
    for (int nb = 0; nb < 4; nb++) {
      bf16x8 vf0 = *(const bf16x8*)&Vl[(nb * 16 + lm) * LDK + qd * 8];
      bf16x8 vf1 = *(const bf16x8*)&Vl[(nb * 16 + lm) * LDK + 32 + qd * 8];
      oacc[nb] = mfma_bf16(pa0, vf0, oacc[nb]);
      oacc[nb] = mfma_bf16(pa1, vf1, oacc[nb]);
    }
  }
  // epilogue: O[b,s,h,d] bf16
#pragma unroll
  for (int r = 0; r < 4; r++) {
    float l = lrun[r];
    float inv = (l > 0.f) ? 1.f / l : 0.f;
    int s = i0 + w * 16 + qd * 4 + r;
#pragma unroll
    for (int nb = 0; nb < 4; nb++)
      O[((b * S_ + s) * H_ + h) * DK_ + nb * 16 + lm] = (bf16)(oacc[nb][r] * inv);
  }
}

// ---------------------------------------------------------------- launch
extern "C" void kernel_launch(void* const* d_in, const int* in_sizes, int n_in,
                              void* d_out, int out_size, void* d_ws, size_t ws_size,
                              hipStream_t stream) {
  (void)in_sizes; (void)n_in; (void)out_size; (void)ws_size;
  const float* x  = (const float*)d_in[0];
  const float* Wq = (const float*)d_in[1];
  const float* bq = (const float*)d_in[2];
  const float* Wk = (const float*)d_in[3];
  const float* bk = (const float*)d_in[4];
  const float* Wv = (const float*)d_in[5];
  const float* bv = (const float*)d_in[6];
  const float* Wo = (const float*)d_in[7];
  const float* bo = (const float*)d_in[8];
  const float* R  = (const float*)d_in[9];

  char* ws = (char*)d_ws;
  bf16*  xb   = (bf16*)(ws + 0);          // 8 MB
  bf16*  Qb   = (bf16*)(ws + 8388608);    // 8 MB  [B,H,S,DK]
  bf16*  Kb   = (bf16*)(ws + 16777216);   // 8 MB  [B,H,S,DK]
  bf16*  Vtb  = (bf16*)(ws + 25165824);   // 8 MB  [B,H,DK,S]
  bf16*  Ob   = (bf16*)(ws + 33554432);   // 8 MB  [B,S,H,DK]
  bf16*  Wtq  = (bf16*)(ws + 41943040);   // 2 MB each
  bf16*  Wtk  = (bf16*)(ws + 44040192);
  bf16*  Wtv  = (bf16*)(ws + 46137344);
  bf16*  Wto  = (bf16*)(ws + 48234496);
  float* Pq   = (float*)(ws + 50331648);  // 512 KB each
  float* Pk   = (float*)(ws + 50855936);
  int*   qbuf = (int*)(ws + 51380224);    // 256 KB each
  int*   kbuf = (int*)(ws + 51642368);
  float* bt   = (float*)(ws + 51904512);  // 1 KB

  k_cast_x<<<dim3(4096), dim3(256), 0, stream>>>(x, xb);
  k_transW<<<dim3(16, 16), dim3(256), 0, stream>>>(Wq, Wtq);
  k_transW<<<dim3(16, 16), dim3(256), 0, stream>>>(Wk, Wtk);
  k_transW<<<dim3(16, 16), dim3(256), 0, stream>>>(Wv, Wtv);
  k_transW<<<dim3(16, 16), dim3(256), 0, stream>>>(Wo, Wto);
  k_computeP<<<dim3(1024), dim3(128), 0, stream>>>(Wq, R, Pq);
  k_computeP<<<dim3(1024), dim3(128), 0, stream>>>(Wk, R, Pk);
  k_bterm<<<dim3(1), dim3(256), 0, stream>>>(bq, bk, R, bt);

  k_gemm<0><<<dim3(32, 16), dim3(256), 0, stream>>>(xb, Wtq, bq, (void*)Qb);
  k_gemm<0><<<dim3(32, 16), dim3(256), 0, stream>>>(xb, Wtk, bk, (void*)Kb);
  k_gemm<1><<<dim3(32, 16), dim3(256), 0, stream>>>(xb, Wtv, bv, (void*)Vtb);

  k_logits<<<dim3(256, 2), dim3(256), 0, stream>>>(x, Pq, Pk, bt, qbuf, kbuf);

  k_attn<<<dim3(32, 16, 2), dim3(256), 0, stream>>>(Qb, Kb, Vtb, qbuf, kbuf, Ob);

  k_gemm<2><<<dim3(32, 16), dim3(256), 0, stream>>>(Ob, Wto, bo, d_out);
}

// Round 3
// 366.638 us; speedup vs baseline: 1.2703x; 1.2703x over previous
//
#include <hip/hip_runtime.h>
#include <hip/hip_bf16.h>

// LSH Attention, MI355X gfx950.
// Pipeline:
//  1) split-cast x -> bf16 (xh, xm, xl): 24-bit mantissa coverage for the
//     bucket-logit GEMM; xh doubles as the A matrix for Q/K/V GEMMs
//  2) P[d][c] = W(:, h*64:h*64+64) @ R[n]^T in fp32 (c = sel*128 + h*8 + n),
//     then transpose+3-split to bf16 Pt_h/m/l [256][1024]
//  3) bf16 MFMA GEMMs: Q,K -> [B,H,S,DK], V -> [B,H,DK,S] (transposed)
//  4) k_lgemm: 6-term split-bf16 MFMA GEMM (error ~3e-7, fp32-equivalent for
//     argmax) + fused shuffle-argmax epilogue -> qb/kb buckets
//  5) flash attention with bucket-equality mask (bf16 MFMA, fp32 softmax)
//  6) bf16 MFMA output GEMM -> fp32 d_out
//
// Workspace aliasing (stream order serializes kernels):
//  xm lives in the Ob region (dead before k_attn writes Ob)
//  xl lives in d_out (dead before final GEMM writes d_out)
//
// MFMA 16x16x32 bf16 layouts (verified in guide):
//  A: lane holds A[m=lane&15][k=(lane>>4)*8+j]
//  B: lane holds B[k=(lane>>4)*8+j][n=lane&15]
//  C/D: lane holds D[m=(lane>>4)*4+r][n=lane&15]

typedef __bf16 bf16;
typedef __bf16 bf16x8 __attribute__((ext_vector_type(8)));
typedef __bf16 bf16x4 __attribute__((ext_vector_type(4)));
typedef float f32x4 __attribute__((ext_vector_type(4)));

#define DEV static __device__ __forceinline__

DEV f32x4 zero4() { f32x4 z; z[0]=0.f; z[1]=0.f; z[2]=0.f; z[3]=0.f; return z; }

DEV f32x4 mfma_bf16(bf16x8 a, bf16x8 b, f32x4 c) {
  return __builtin_amdgcn_mfma_f32_16x16x32_bf16(a, b, c, 0, 0, 0);
}

#define B_  2
#define S_  2048
#define D_  1024
#define H_  16
#define NH_ 8
#define DK_ 64
#define M_  4096   // B_*S_

// ---------------------------------------------------------------- prep
// x -> xh + xm + xl (3-way bf16 split, ~24 mantissa bits total)
__global__ void k_cast_split(const float* __restrict__ x, bf16* __restrict__ xh,
                             bf16* __restrict__ xm, bf16* __restrict__ xl) {
  int i = (blockIdx.x * 256 + threadIdx.x) * 4;
  f32x4 v = *(const f32x4*)(x + i);
  bf16x4 oh, om, ol;
#pragma unroll
  for (int j = 0; j < 4; j++) {
    float f = v[j];
    bf16 h = (bf16)f;
    float rm = f - (float)h;
    bf16 m = (bf16)rm;
    float rl = rm - (float)m;
    oh[j] = h; om[j] = m; ol[j] = (bf16)rl;
  }
  *(bf16x4*)(xh + i) = oh;
  *(bf16x4*)(xm + i) = om;
  *(bf16x4*)(xl + i) = ol;
}

// W [k][n] fp32 -> Wt [n][k] bf16 (64x64 LDS tile transpose)
__global__ void k_transW(const float* __restrict__ W, bf16* __restrict__ Wt) {
  __shared__ float tile[64][65];
  int k0 = blockIdx.x * 64, n0 = blockIdx.y * 64;
  int c = threadIdx.x & 63, r4 = threadIdx.x >> 6;
#pragma unroll
  for (int i = 0; i < 16; i++) {
    int r = r4 * 16 + i;
    tile[r][c] = W[(k0 + r) * D_ + n0 + c];
  }
  __syncthreads();
#pragma unroll
  for (int i = 0; i < 16; i++) {
    int r = r4 * 16 + i;
    Wt[(n0 + r) * D_ + k0 + c] = (bf16)tile[c][r];
  }
}

// P[d][c] = sum_k W[d][h*64+k] * R[n][k], c = sel*128 + h*8 + n  (fp32)
__global__ void k_computeP(const float* __restrict__ Wq, const float* __restrict__ Wk,
                           const float* __restrict__ R, float* __restrict__ P) {
  int d = blockIdx.x;
  int t = threadIdx.x;           // 256 threads: c
  int hn = t & 127, h = hn >> 3, n = hn & 7;
  const float* W = (t < 128) ? Wq : Wk;
  const float* wrow = W + d * D_ + h * 64;
  const float* rrow = R + n * 64;
  float acc = 0.f;
#pragma unroll 8
  for (int k = 0; k < 64; k++) acc += wrow[k] * rrow[k];
  P[d * 256 + t] = acc;
}

// P fp32 [1024][256] -> Pt_{h,m,l} bf16 [256][1024] (transpose + 3-split)
__global__ void k_transP(const float* __restrict__ P, bf16* __restrict__ Pth,
                         bf16* __restrict__ Ptm, bf16* __restrict__ Ptl) {
  __shared__ float tile[64][65];
  int k0 = blockIdx.x * 64, n0 = blockIdx.y * 64;
  int c = threadIdx.x & 63, r4 = threadIdx.x >> 6;
#pragma unroll
  for (int i = 0; i < 16; i++) {
    int r = r4 * 16 + i;
    tile[r][c] = P[(k0 + r) * 256 + n0 + c];
  }
  __syncthreads();
#pragma unroll
  for (int i = 0; i < 16; i++) {
    int r = r4 * 16 + i;
    float v = tile[c][r];
    bf16 h = (bf16)v;
    float rm = v - (float)h;
    bf16 m = (bf16)rm;
    bf16 l = (bf16)(rm - (float)m);
    int o = (n0 + r) * D_ + k0 + c;
    Pth[o] = h; Ptm[o] = m; Ptl[o] = l;
  }
}

// bterm[0:128]=bq.R, [128:256]=bk.R
__global__ void k_bterm(const float* __restrict__ bq, const float* __restrict__ bk,
                        const float* __restrict__ R, float* __restrict__ bt) {
  int t = threadIdx.x;  // 256
  const float* b = (t < 128) ? bq : bk;
  int hn = t & 127, h = hn >> 3, n = hn & 7;
  float acc = 0.f;
#pragma unroll 8
  for (int k = 0; k < 64; k++) acc += b[h * 64 + k] * R[n * 64 + k];
  bt[t] = acc;
}

// ---------------------------------------------------------------- logits GEMM
// logits[m][n] = (xh+xm+xl)[m][:] . (Ph+Pm+Pl)[n][:] + bt[n], 6-term expansion
// (dropped terms <= 2^-26 relative -> argmax-safe). Fused argmax -> qb/kb.
// tile 64(m) x 64(n), 256 threads, wave w owns rows w*16..+15
__global__ __launch_bounds__(256) void k_lgemm(const bf16* __restrict__ xh,
                                               const bf16* __restrict__ xm,
                                               const bf16* __restrict__ xl,
                                               const bf16* __restrict__ Pth,
                                               const bf16* __restrict__ Ptm,
                                               const bf16* __restrict__ Ptl,
                                               const float* __restrict__ bt,
                                               int* __restrict__ qb,
                                               int* __restrict__ kb) {
  constexpr int LDA = 40;
  __shared__ bf16 As[3][64 * LDA];
  __shared__ bf16 Bs[3][64 * LDA];
  const int t = threadIdx.x;
  const int m0 = blockIdx.x * 64, n0 = blockIdx.y * 64;
  const int lane = t & 63, w = t >> 6;
  const int lm = lane & 15, qd = lane >> 4;
  const bf16* Asrc[3] = {xh, xm, xl};
  const bf16* Bsrc[3] = {Pth, Ptm, Ptl};

  f32x4 acc[4];
#pragma unroll
  for (int nb = 0; nb < 4; nb++) acc[nb] = zero4();

  const int row = t >> 2, sg = t & 3;  // 256 segs = 64 rows x 4 segs(16B)
  for (int k0 = 0; k0 < D_; k0 += 32) {
    __syncthreads();
#pragma unroll
    for (int i3 = 0; i3 < 3; i3++) {
      *(bf16x8*)&As[i3][row * LDA + sg * 8] =
          *(const bf16x8*)&Asrc[i3][(m0 + row) * D_ + k0 + sg * 8];
      *(bf16x8*)&Bs[i3][row * LDA + sg * 8] =
          *(const bf16x8*)&Bsrc[i3][(n0 + row) * D_ + k0 + sg * 8];
    }
    __syncthreads();
    bf16x8 af[3], bfr[3][4];
#pragma unroll
    for (int i3 = 0; i3 < 3; i3++) {
      af[i3] = *(const bf16x8*)&As[i3][(w * 16 + lm) * LDA + qd * 8];
#pragma unroll
      for (int nb = 0; nb < 4; nb++)
        bfr[i3][nb] = *(const bf16x8*)&Bs[i3][(nb * 16 + lm) * LDA + qd * 8];
    }
#pragma unroll
    for (int nb = 0; nb < 4; nb++) {
      f32x4 a = acc[nb];
      a = mfma_bf16(af[0], bfr[0][nb], a);  // hh
      a = mfma_bf16(af[0], bfr[1][nb], a);  // hm
      a = mfma_bf16(af[1], bfr[0][nb], a);  // mh
      a = mfma_bf16(af[0], bfr[2][nb], a);  // hl
      a = mfma_bf16(af[2], bfr[0][nb], a);  // lh
      a = mfma_bf16(af[1], bfr[1][nb], a);  // mm
      acc[nb] = a;
    }
  }

  // fused argmax over groups of 8 cols (first-max tie-break = np.argmax)
#pragma unroll
  for (int nb = 0; nb < 4; nb++) {
    int n = n0 + nb * 16 + lm;
    float btv = bt[n];
#pragma unroll
    for (int r = 0; r < 4; r++) {
      float v = acc[nb][r] + btv;
      int idx = lm & 7;
#pragma unroll
      for (int mask = 1; mask <= 4; mask <<= 1) {
        float pv = __shfl_xor(v, mask);
        int pi = __shfl_xor(idx, mask);
        if (pv > v || (pv == v && pi < idx)) { v = pv; idx = pi; }
      }
      if ((lm & 7) == 0) {
        int m = m0 + w * 16 + qd * 4 + r;
        int g = n >> 3;                 // 0..31
        int sel = g >> 4, head = g & 15;
        int bb = m >> 11, s = m & 2047;
        (sel ? kb : qb)[(bb * H_ + head) * S_ + s] = idx;
      }
    }
  }
}

// ---------------------------------------------------------------- bf16 GEMM
// C[m][n] = sum_k A[m][k]*Bt[n][k] + bias[n];  M=4096, N=1024, K=1024
// tile 128(m) x 64(n), 256 threads (wave w owns rows w*32..w*32+31)
// MODE 0: out bf16 [B,H,S,DK];  MODE 1: out bf16 [B,H,DK,S];  MODE 2: out fp32 [m][n]
template <int MODE>
__global__ __launch_bounds__(256) void k_gemm(const bf16* __restrict__ A,
                                              const bf16* __restrict__ Bt,
                                              const float* __restrict__ bias,
                                              void* __restrict__ out) {
  constexpr int LDA = 40;  // bf16 row stride: 80B -> 2-way (free) LDS conflicts
  __shared__ bf16 Al[128 * LDA];
  __shared__ bf16 Bl[64 * LDA];
  const int t = threadIdx.x;
  const int m0 = blockIdx.x * 128;
  const int n0 = blockIdx.y * 64;
  const int lane = t & 63, w = t >> 6;
  const int lm = lane & 15, qd = lane >> 4;

  f32x4 acc[2][4];
#pragma unroll
  for (int i = 0; i < 2; i++)
#pragma unroll
    for (int j = 0; j < 4; j++) acc[i][j] = zero4();

  for (int k0 = 0; k0 < D_; k0 += 32) {
    __syncthreads();
    // stage A: 128 rows x 4 segs(16B) = 512 segs; B: 256 segs
#pragma unroll
    for (int ss = 0; ss < 2; ss++) {
      int seg = t + ss * 256;
      int row = seg >> 2, sg = seg & 3;
      *(bf16x8*)&Al[row * LDA + sg * 8] =
          *(const bf16x8*)&A[(m0 + row) * D_ + k0 + sg * 8];
    }
    {
      int row = t >> 2, sg = t & 3;
      *(bf16x8*)&Bl[row * LDA + sg * 8] =
          *(const bf16x8*)&Bt[(n0 + row) * D_ + k0 + sg * 8];
    }
    __syncthreads();
    bf16x8 af[2], bfr[4];
#pragma unroll
    for (int i = 0; i < 2; i++)
      af[i] = *(const bf16x8*)&Al[(w * 32 + i * 16 + lm) * LDA + qd * 8];
#pragma unroll
    for (int j = 0; j < 4; j++)
      bfr[j] = *(const bf16x8*)&Bl[(j * 16 + lm) * LDA + qd * 8];
#pragma unroll
    for (int i = 0; i < 2; i++)
#pragma unroll
      for (int j = 0; j < 4; j++) acc[i][j] = mfma_bf16(af[i], bfr[j], acc[i][j]);
  }

#pragma unroll
  for (int i = 0; i < 2; i++)
#pragma unroll
    for (int j = 0; j < 4; j++) {
      int n = n0 + j * 16 + lm;
      float bv = bias[n];
      int mbase = m0 + w * 32 + i * 16 + qd * 4;  // rows mbase..mbase+3
      if (MODE == 1) {
        int bb = mbase >> 11, s = mbase & 2047;
        int h = n >> 6, d = n & 63;
        bf16x4 pk;
#pragma unroll
        for (int r = 0; r < 4; r++) pk[r] = (bf16)(acc[i][j][r] + bv);
        *(bf16x4*)((bf16*)out + (((bb * H_ + h) * DK_ + d) * S_ + s)) = pk;
      } else {
#pragma unroll
        for (int r = 0; r < 4; r++) {
          int m = mbase + r;
          float v = acc[i][j][r] + bv;
          if (MODE == 0) {
            int bb = m >> 11, s = m & 2047, h = n >> 6, d = n & 63;
            ((bf16*)out)[((bb * H_ + h) * S_ + s) * DK_ + d] = (bf16)v;
          } else {
            ((float*)out)[m * D_ + n] = v;
          }
        }
      }
    }
}

// ---------------------------------------------------------------- attention
// one block: (b, h, 64 q-rows); wave w owns q-rows i0+w*16..+15
__global__ __launch_bounds__(256) void k_attn(const bf16* __restrict__ Q,
                                              const bf16* __restrict__ K,
                                              const bf16* __restrict__ Vt,
                                              const int* __restrict__ qb,
                                              const int* __restrict__ kb,
                                              bf16* __restrict__ O) {
  constexpr int LDK = 72;  // 144B row stride: 16B-aligned, 2-way (free) conflicts
  __shared__ bf16 Kl[64 * LDK];
  __shared__ bf16 Vl[64 * LDK];
  __shared__ bf16 Pl[4 * 16 * LDK];
  __shared__ int kbl[64];
  const int t = threadIdx.x;
  const int i0 = blockIdx.x * 64;
  const int h = blockIdx.y, b = blockIdx.z;
  const int lane = t & 63, w = t >> 6;
  const int lm = lane & 15, qd = lane >> 4;
  const int bh = b * H_ + h;

  const bf16* Qp = Q + (bh * S_ + i0 + w * 16 + lm) * DK_;
  bf16x8 qf0 = *(const bf16x8*)(Qp + qd * 8);
  bf16x8 qf1 = *(const bf16x8*)(Qp + 32 + qd * 8);

  int qbv[4];
#pragma unroll
  for (int r = 0; r < 4; r++) qbv[r] = qb[bh * S_ + i0 + w * 16 + qd * 4 + r];

  f32x4 oacc[4];
  float mrun[4], lrun[4];
#pragma unroll
  for (int nb = 0; nb < 4; nb++) oacc[nb] = zero4();
#pragma unroll
  for (int r = 0; r < 4; r++) { mrun[r] = -1e30f; lrun[r] = 0.f; }

  const bf16* Kbase = K + bh * S_ * DK_;
  const bf16* Vbase = Vt + bh * DK_ * S_;
  const int* kbbase = kb + bh * S_;

  for (int j0 = 0; j0 < S_; j0 += 64) {
    __syncthreads();
    // stage K tile (64 keys x 64 dims) and V tile (64 dims x 64 keys):
    // 64 rows x 8 segs(16B) = 512 segs each, 2 rounds of 256 threads
#pragma unroll
    for (int ss = 0; ss < 2; ss++) {
      int seg = t + ss * 256;
      int row = seg >> 3, sg = seg & 7;
      *(bf16x8*)&Kl[row * LDK + sg * 8] =
          *(const bf16x8*)&Kbase[(j0 + row) * DK_ + sg * 8];
      *(bf16x8*)&Vl[row * LDK + sg * 8] =
          *(const bf16x8*)&Vbase[row * S_ + j0 + sg * 8];
    }
    if (t < 64) kbl[t] = kbbase[j0 + t];
    __syncthreads();

    // scores 16x64 per wave (C-layout: row=qd*4+r, col=nb*16+lm)
    f32x4 sc[4];
#pragma unroll
    for (int nb = 0; nb < 4; nb++) {
      bf16x8 kf0 = *(const bf16x8*)&Kl[(nb * 16 + lm) * LDK + qd * 8];
      bf16x8 kf1 = *(const bf16x8*)&Kl[(nb * 16 + lm) * LDK + 32 + qd * 8];
      f32x4 z = zero4();
      z = mfma_bf16(qf0, kf0, z);
      z = mfma_bf16(qf1, kf1, z);
      sc[nb] = z;
    }
    // bucket mask + scale 1/sqrt(64)
#pragma unroll
    for (int nb = 0; nb < 4; nb++) {
      int kv = kbl[nb * 16 + lm];
#pragma unroll
      for (int r = 0; r < 4; r++)
        sc[nb][r] = (qbv[r] == kv) ? sc[nb][r] * 0.125f : -1e30f;
    }
    // online softmax
    float mnew[4], alpha[4], rs[4];
#pragma unroll
    for (int r = 0; r < 4; r++) {
      float tm = fmaxf(fmaxf(sc[0][r], sc[1][r]), fmaxf(sc[2][r], sc[3][r]));
      tm = fmaxf(tm, __shfl_xor(tm, 1));
      tm = fmaxf(tm, __shfl_xor(tm, 2));
      tm = fmaxf(tm, __shfl_xor(tm, 4));
      tm = fmaxf(tm, __shfl_xor(tm, 8));
      mnew[r] = fmaxf(mrun[r], tm);
      alpha[r] = __expf(mrun[r] - mnew[r]);  // both -1e30 -> exp(0)=1, harmless
      mrun[r] = mnew[r];
      rs[r] = 0.f;
    }
    // masked entries contribute EXACTLY 0 (guards all-masked tiles where
    // mnew is still -1e30 and exp(sc-mnew) would be exp(0)=1)
#pragma unroll
    for (int nb = 0; nb < 4; nb++)
#pragma unroll
      for (int r = 0; r < 4; r++) {
        float p = (sc[nb][r] > -1e29f) ? __expf(sc[nb][r] - mnew[r]) : 0.f;
        sc[nb][r] = p;
        rs[r] += p;
      }
#pragma unroll
    for (int r = 0; r < 4; r++) {
      float s = rs[r];
      s += __shfl_xor(s, 1);
      s += __shfl_xor(s, 2);
      s += __shfl_xor(s, 4);
      s += __shfl_xor(s, 8);
      lrun[r] = lrun[r] * alpha[r] + s;
    }
#pragma unroll
    for (int nb = 0; nb < 4; nb++)
#pragma unroll
      for (int r = 0; r < 4; r++) oacc[nb][r] *= alpha[r];
    // P: C-layout -> A-layout via LDS
#pragma unroll
    for (int nb = 0; nb < 4; nb++)
#pragma unroll
      for (int r = 0; r < 4; r++)
        Pl[(w * 16 + qd * 4 + r) * LDK + nb * 16 + lm] = (bf16)sc[nb][r];
    __syncthreads();
    bf16x8 pa0 = *(const bf16x8*)&Pl[(w * 16 + lm) * LDK + qd * 8];
    bf16x8 pa1 = *(const bf16x8*)&Pl[(w * 16 + lm) * LDK + 32 + qd * 8];
#pragma unroll
    for (int nb = 0; nb < 4; nb++) {
      bf16x8 vf0 = *(const bf16x8*)&Vl[(nb * 16 + lm) * LDK + qd * 8];
      bf16x8 vf1 = *(const bf16x8*)&Vl[(nb * 16 + lm) * LDK + 32 + qd * 8];
      oacc[nb] = mfma_bf16(pa0, vf0, oacc[nb]);
      oacc[nb] = mfma_bf16(pa1, vf1, oacc[nb]);
    }
  }
  // epilogue: O[b,s,h,d] bf16
#pragma unroll
  for (int r = 0; r < 4; r++) {
    float l = lrun[r];
    float inv = (l > 0.f) ? 1.f / l : 0.f;
    int s = i0 + w * 16 + qd * 4 + r;
#pragma unroll
    for (int nb = 0; nb < 4; nb++)
      O[((b * S_ + s) * H_ + h) * DK_ + nb * 16 + lm] = (bf16)(oacc[nb][r] * inv);
  }
}

// ---------------------------------------------------------------- launch
extern "C" void kernel_launch(void* const* d_in, const int* in_sizes, int n_in,
                              void* d_out, int out_size, void* d_ws, size_t ws_size,
                              hipStream_t stream) {
  (void)in_sizes; (void)n_in; (void)out_size; (void)ws_size;
  const float* x  = (const float*)d_in[0];
  const float* Wq = (const float*)d_in[1];
  const float* bq = (const float*)d_in[2];
  const float* Wk = (const float*)d_in[3];
  const float* bk = (const float*)d_in[4];
  const float* Wv = (const float*)d_in[5];
  const float* bv = (const float*)d_in[6];
  const float* Wo = (const float*)d_in[7];
  const float* bo = (const float*)d_in[8];
  const float* R  = (const float*)d_in[9];

  char* ws = (char*)d_ws;
  bf16*  xh   = (bf16*)(ws + 0);          // 8 MB
  bf16*  Qb   = (bf16*)(ws + 8388608);    // 8 MB  [B,H,S,DK]
  bf16*  Kb   = (bf16*)(ws + 16777216);   // 8 MB  [B,H,S,DK]
  bf16*  Vtb  = (bf16*)(ws + 25165824);   // 8 MB  [B,H,DK,S]
  bf16*  Ob   = (bf16*)(ws + 33554432);   // 8 MB  [B,S,H,DK]; xm aliases (dead before k_attn)
  bf16*  xm   = (bf16*)(ws + 33554432);
  bf16*  Wtq  = (bf16*)(ws + 41943040);   // 2 MB each
  bf16*  Wtk  = (bf16*)(ws + 44040192);
  bf16*  Wtv  = (bf16*)(ws + 46137344);
  bf16*  Wto  = (bf16*)(ws + 48234496);
  float* Pfull= (float*)(ws + 50331648);  // 1 MB fp32 [1024][256]
  int*   qbuf = (int*)(ws + 51380224);    // 256 KB each
  int*   kbuf = (int*)(ws + 51642368);
  float* bt   = (float*)(ws + 51904512);  // 1 KB
  bf16*  Pth  = (bf16*)(ws + 51905536);   // 512 KB each
  bf16*  Ptm  = (bf16*)(ws + 52429824);
  bf16*  Ptl  = (bf16*)(ws + 52954112);   // ends ~53.5 MB
  bf16*  xl   = (bf16*)d_out;             // 8 MB in d_out (dead before final GEMM)

  k_cast_split<<<dim3(4096), dim3(256), 0, stream>>>(x, xh, xm, xl);
  k_transW<<<dim3(16, 16), dim3(256), 0, stream>>>(Wq, Wtq);
  k_transW<<<dim3(16, 16), dim3(256), 0, stream>>>(Wk, Wtk);
  k_transW<<<dim3(16, 16), dim3(256), 0, stream>>>(Wv, Wtv);
  k_transW<<<dim3(16, 16), dim3(256), 0, stream>>>(Wo, Wto);
  k_computeP<<<dim3(1024), dim3(256), 0, stream>>>(Wq, Wk, R, Pfull);
  k_bterm<<<dim3(1), dim3(256), 0, stream>>>(bq, bk, R, bt);
  k_transP<<<dim3(16, 4), dim3(256), 0, stream>>>(Pfull, Pth, Ptm, Ptl);

  // buckets (must precede k_attn; also xm/xl die here)
  k_lgemm<<<dim3(64, 4), dim3(256), 0, stream>>>(xh, xm, xl, Pth, Ptm, Ptl,
                                                 bt, qbuf, kbuf);

  k_gemm<0><<<dim3(32, 16), dim3(256), 0, stream>>>(xh, Wtq, bq, (void*)Qb);
  k_gemm<0><<<dim3(32, 16), dim3(256), 0, stream>>>(xh, Wtk, bk, (void*)Kb);
  k_gemm<1><<<dim3(32, 16), dim3(256), 0, stream>>>(xh, Wtv, bv, (void*)Vtb);

  k_attn<<<dim3(32, 16, 2), dim3(256), 0, stream>>>(Qb, Kb, Vtb, qbuf, kbuf, Ob);

  k_gemm<2><<<dim3(32, 16), dim3(256), 0, stream>>>(Ob, Wto, bo, d_out);
}

// Round 4
// 290.892 us; speedup vs baseline: 1.6010x; 1.2604x over previous
//
#include <hip/hip_runtime.h>
#include <hip/hip_bf16.h>

// LSH Attention, MI355X gfx950.
// Pipeline:
//  1) split-cast x -> bf16 (xh, xm, xl)
//  2) P = W @ R^T folds (fp32) -> transpose+3-split bf16
//  3) k_lgemm: 6-term split-bf16 MFMA logits + fused argmax -> qb/kb
//  4) k_sort: per-(b,h) counting sort of q/k indices by bucket, 64-aligned
//     padded bucket starts + per-q-tile {kstart, nktiles} metadata
//  5) bf16 MFMA GEMMs: Q,K,V -> [B,H,S,DK]
//  6) bucket-sorted flash attention: each 64-q tile attends only its own
//     bucket's keys (6.3x fewer tiles than dense-masked)
//  7) bf16 MFMA output GEMM -> fp32 d_out
//
// MFMA 16x16x32 bf16 layouts (verified in guide):
//  A: lane holds A[m=lane&15][k=(lane>>4)*8+j]
//  B: lane holds B[k=(lane>>4)*8+j][n=lane&15]
//  C/D: lane holds D[m=(lane>>4)*4+r][n=lane&15]

typedef __bf16 bf16;
typedef __bf16 bf16x8 __attribute__((ext_vector_type(8)));
typedef __bf16 bf16x4 __attribute__((ext_vector_type(4)));
typedef float f32x4 __attribute__((ext_vector_type(4)));

#define DEV static __device__ __forceinline__

DEV f32x4 zero4() { f32x4 z; z[0]=0.f; z[1]=0.f; z[2]=0.f; z[3]=0.f; return z; }

DEV f32x4 mfma_bf16(bf16x8 a, bf16x8 b, f32x4 c) {
  return __builtin_amdgcn_mfma_f32_16x16x32_bf16(a, b, c, 0, 0, 0);
}

#define B_  2
#define S_  2048
#define D_  1024
#define H_  16
#define NH_ 8
#define DK_ 64
#define M_  4096   // B_*S_
#define QPAD 2560  // 2048 + 8*64 (per-bucket 64-alignment padding)
#define NQT  40    // max q-tiles per (b,h): 32 + 8

// ---------------------------------------------------------------- prep
__global__ void k_cast_split(const float* __restrict__ x, bf16* __restrict__ xh,
                             bf16* __restrict__ xm, bf16* __restrict__ xl) {
  int i = (blockIdx.x * 256 + threadIdx.x) * 4;
  f32x4 v = *(const f32x4*)(x + i);
  bf16x4 oh, om, ol;
#pragma unroll
  for (int j = 0; j < 4; j++) {
    float f = v[j];
    bf16 h = (bf16)f;
    float rm = f - (float)h;
    bf16 m = (bf16)rm;
    float rl = rm - (float)m;
    oh[j] = h; om[j] = m; ol[j] = (bf16)rl;
  }
  *(bf16x4*)(xh + i) = oh;
  *(bf16x4*)(xm + i) = om;
  *(bf16x4*)(xl + i) = ol;
}

// W [k][n] fp32 -> Wt [n][k] bf16 (64x64 LDS tile transpose)
__global__ void k_transW(const float* __restrict__ W, bf16* __restrict__ Wt) {
  __shared__ float tile[64][65];
  int k0 = blockIdx.x * 64, n0 = blockIdx.y * 64;
  int c = threadIdx.x & 63, r4 = threadIdx.x >> 6;
#pragma unroll
  for (int i = 0; i < 16; i++) {
    int r = r4 * 16 + i;
    tile[r][c] = W[(k0 + r) * D_ + n0 + c];
  }
  __syncthreads();
#pragma unroll
  for (int i = 0; i < 16; i++) {
    int r = r4 * 16 + i;
    Wt[(n0 + r) * D_ + k0 + c] = (bf16)tile[c][r];
  }
}

// P[d][c] = sum_k W[d][h*64+k] * R[n][k], c = sel*128 + h*8 + n  (fp32)
__global__ void k_computeP(const float* __restrict__ Wq, const float* __restrict__ Wk,
                           const float* __restrict__ R, float* __restrict__ P) {
  int d = blockIdx.x;
  int t = threadIdx.x;           // 256 threads: c
  int hn = t & 127, h = hn >> 3, n = hn & 7;
  const float* W = (t < 128) ? Wq : Wk;
  const float* wrow = W + d * D_ + h * 64;
  const float* rrow = R + n * 64;
  float acc = 0.f;
#pragma unroll 8
  for (int k = 0; k < 64; k++) acc += wrow[k] * rrow[k];
  P[d * 256 + t] = acc;
}

// P fp32 [1024][256] -> Pt_{h,m,l} bf16 [256][1024] (transpose + 3-split)
__global__ void k_transP(const float* __restrict__ P, bf16* __restrict__ Pth,
                         bf16* __restrict__ Ptm, bf16* __restrict__ Ptl) {
  __shared__ float tile[64][65];
  int k0 = blockIdx.x * 64, n0 = blockIdx.y * 64;
  int c = threadIdx.x & 63, r4 = threadIdx.x >> 6;
#pragma unroll
  for (int i = 0; i < 16; i++) {
    int r = r4 * 16 + i;
    tile[r][c] = P[(k0 + r) * 256 + n0 + c];
  }
  __syncthreads();
#pragma unroll
  for (int i = 0; i < 16; i++) {
    int r = r4 * 16 + i;
    float v = tile[c][r];
    bf16 h = (bf16)v;
    float rm = v - (float)h;
    bf16 m = (bf16)rm;
    bf16 l = (bf16)(rm - (float)m);
    int o = (n0 + r) * D_ + k0 + c;
    Pth[o] = h; Ptm[o] = m; Ptl[o] = l;
  }
}

// bterm[0:128]=bq.R, [128:256]=bk.R
__global__ void k_bterm(const float* __restrict__ bq, const float* __restrict__ bk,
                        const float* __restrict__ R, float* __restrict__ bt) {
  int t = threadIdx.x;  // 256
  const float* b = (t < 128) ? bq : bk;
  int hn = t & 127, h = hn >> 3, n = hn & 7;
  float acc = 0.f;
#pragma unroll 8
  for (int k = 0; k < 64; k++) acc += b[h * 64 + k] * R[n * 64 + k];
  bt[t] = acc;
}

// ---------------------------------------------------------------- logits GEMM
// logits[m][n] = (xh+xm+xl).(Ph+Pm+Pl) + bt[n], 6-term split (argmax-exact)
__global__ __launch_bounds__(256) void k_lgemm(const bf16* __restrict__ xh,
                                               const bf16* __restrict__ xm,
                                               const bf16* __restrict__ xl,
                                               const bf16* __restrict__ Pth,
                                               const bf16* __restrict__ Ptm,
                                               const bf16* __restrict__ Ptl,
                                               const float* __restrict__ bt,
                                               int* __restrict__ qb,
                                               int* __restrict__ kb) {
  constexpr int LDA = 40;
  __shared__ bf16 As[3][64 * LDA];
  __shared__ bf16 Bs[3][64 * LDA];
  const int t = threadIdx.x;
  const int m0 = blockIdx.x * 64, n0 = blockIdx.y * 64;
  const int lane = t & 63, w = t >> 6;
  const int lm = lane & 15, qd = lane >> 4;
  const bf16* Asrc[3] = {xh, xm, xl};
  const bf16* Bsrc[3] = {Pth, Ptm, Ptl};

  f32x4 acc[4];
#pragma unroll
  for (int nb = 0; nb < 4; nb++) acc[nb] = zero4();

  const int row = t >> 2, sg = t & 3;  // 256 segs = 64 rows x 4 segs(16B)
  for (int k0 = 0; k0 < D_; k0 += 32) {
    __syncthreads();
#pragma unroll
    for (int i3 = 0; i3 < 3; i3++) {
      *(bf16x8*)&As[i3][row * LDA + sg * 8] =
          *(const bf16x8*)&Asrc[i3][(m0 + row) * D_ + k0 + sg * 8];
      *(bf16x8*)&Bs[i3][row * LDA + sg * 8] =
          *(const bf16x8*)&Bsrc[i3][(n0 + row) * D_ + k0 + sg * 8];
    }
    __syncthreads();
    bf16x8 af[3], bfr[3][4];
#pragma unroll
    for (int i3 = 0; i3 < 3; i3++) {
      af[i3] = *(const bf16x8*)&As[i3][(w * 16 + lm) * LDA + qd * 8];
#pragma unroll
      for (int nb = 0; nb < 4; nb++)
        bfr[i3][nb] = *(const bf16x8*)&Bs[i3][(nb * 16 + lm) * LDA + qd * 8];
    }
#pragma unroll
    for (int nb = 0; nb < 4; nb++) {
      f32x4 a = acc[nb];
      a = mfma_bf16(af[0], bfr[0][nb], a);  // hh
      a = mfma_bf16(af[0], bfr[1][nb], a);  // hm
      a = mfma_bf16(af[1], bfr[0][nb], a);  // mh
      a = mfma_bf16(af[0], bfr[2][nb], a);  // hl
      a = mfma_bf16(af[2], bfr[0][nb], a);  // lh
      a = mfma_bf16(af[1], bfr[1][nb], a);  // mm
      acc[nb] = a;
    }
  }

  // fused argmax over groups of 8 cols (first-max tie-break = np.argmax)
#pragma unroll
  for (int nb = 0; nb < 4; nb++) {
    int n = n0 + nb * 16 + lm;
    float btv = bt[n];
#pragma unroll
    for (int r = 0; r < 4; r++) {
      float v = acc[nb][r] + btv;
      int idx = lm & 7;
#pragma unroll
      for (int mask = 1; mask <= 4; mask <<= 1) {
        float pv = __shfl_xor(v, mask);
        int pi = __shfl_xor(idx, mask);
        if (pv > v || (pv == v && pi < idx)) { v = pv; idx = pi; }
      }
      if ((lm & 7) == 0) {
        int m = m0 + w * 16 + qd * 4 + r;
        int g = n >> 3;                 // 0..31
        int sel = g >> 4, head = g & 15;
        int bb = m >> 11, s = m & 2047;
        (sel ? kb : qb)[(bb * H_ + head) * S_ + s] = idx;
      }
    }
  }
}

// ---------------------------------------------------------------- bucket sort
// One block per (b,h). Stable counting sort of q and k positions by bucket,
// bucket starts padded to 64; per-q-tile metadata {kstart, nktiles}.
__global__ __launch_bounds__(256) void k_sort(const int* __restrict__ qb,
                                              const int* __restrict__ kb,
                                              int* __restrict__ qidx,
                                              int* __restrict__ kidx,
                                              int2* __restrict__ meta) {
  __shared__ int cnt[8][257];
  __shared__ int bst[2][9];
  __shared__ int tot[2][8];
  const int bh = blockIdx.x;
  const int t = threadIdx.x;
  for (int which = 0; which < 2; which++) {
    const int* src = (which ? kb : qb) + bh * S_;
    int* dst = (which ? kidx : qidx) + bh * QPAD;
    for (int i = t; i < QPAD; i += 256) dst[i] = -1;
    int vals[8];
    int lc[8] = {0, 0, 0, 0, 0, 0, 0, 0};
#pragma unroll
    for (int j = 0; j < 8; j++) { int b = src[t * 8 + j]; vals[j] = b; lc[b]++; }
#pragma unroll
    for (int b = 0; b < 8; b++) cnt[b][t] = lc[b];
    __syncthreads();
    if (t < 8) {  // exclusive scan per bucket over 256 thread slots
      int run = 0;
      for (int i = 0; i < 256; i++) { int c = cnt[t][i]; cnt[t][i] = run; run += c; }
      tot[which][t] = run;
    }
    __syncthreads();
    if (t == 0) {
      int pos = 0;
      for (int b = 0; b < 8; b++) {
        bst[which][b] = pos;
        pos += (tot[which][b] + 63) & ~63;
      }
      bst[which][8] = pos;
    }
    __syncthreads();
    int run2[8] = {0, 0, 0, 0, 0, 0, 0, 0};
#pragma unroll
    for (int j = 0; j < 8; j++) {
      int b = vals[j];
      int pos = bst[which][b] + cnt[b][t] + run2[b]++;
      dst[pos] = t * 8 + j;
    }
    __syncthreads();
  }
  if (t == 0) {
    for (int tt = 0; tt < NQT; tt++) meta[bh * NQT + tt] = make_int2(0, 0);
    for (int b = 0; b < 8; b++) {
      int t0 = bst[0][b] >> 6;
      int nt = ((tot[0][b] + 63) & ~63) >> 6;
      int ks = bst[1][b];
      int nkt = (tot[1][b] + 63) >> 6;
      for (int tt = t0; tt < t0 + nt; tt++)
        meta[bh * NQT + tt] = make_int2(ks, nkt);
    }
  }
}

// ---------------------------------------------------------------- bf16 GEMM
// C[m][n] = sum_k A[m][k]*Bt[n][k] + bias[n];  M=4096, N=1024, K=1024
// MODE 0: out bf16 [B,H,S,DK];  MODE 2: out fp32 [m][n]
template <int MODE>
__global__ __launch_bounds__(256) void k_gemm(const bf16* __restrict__ A,
                                              const bf16* __restrict__ Bt,
                                              const float* __restrict__ bias,
                                              void* __restrict__ out) {
  constexpr int LDA = 40;  // bf16 row stride: 80B -> 2-way (free) LDS conflicts
  __shared__ bf16 Al[128 * LDA];
  __shared__ bf16 Bl[64 * LDA];
  const int t = threadIdx.x;
  const int m0 = blockIdx.x * 128;
  const int n0 = blockIdx.y * 64;
  const int lane = t & 63, w = t >> 6;
  const int lm = lane & 15, qd = lane >> 4;

  f32x4 acc[2][4];
#pragma unroll
  for (int i = 0; i < 2; i++)
#pragma unroll
    for (int j = 0; j < 4; j++) acc[i][j] = zero4();

  for (int k0 = 0; k0 < D_; k0 += 32) {
    __syncthreads();
#pragma unroll
    for (int ss = 0; ss < 2; ss++) {
      int seg = t + ss * 256;
      int row = seg >> 2, sg = seg & 3;
      *(bf16x8*)&Al[row * LDA + sg * 8] =
          *(const bf16x8*)&A[(m0 + row) * D_ + k0 + sg * 8];
    }
    {
      int row = t >> 2, sg = t & 3;
      *(bf16x8*)&Bl[row * LDA + sg * 8] =
          *(const bf16x8*)&Bt[(n0 + row) * D_ + k0 + sg * 8];
    }
    __syncthreads();
    bf16x8 af[2], bfr[4];
#pragma unroll
    for (int i = 0; i < 2; i++)
      af[i] = *(const bf16x8*)&Al[(w * 32 + i * 16 + lm) * LDA + qd * 8];
#pragma unroll
    for (int j = 0; j < 4; j++)
      bfr[j] = *(const bf16x8*)&Bl[(j * 16 + lm) * LDA + qd * 8];
#pragma unroll
    for (int i = 0; i < 2; i++)
#pragma unroll
      for (int j = 0; j < 4; j++) acc[i][j] = mfma_bf16(af[i], bfr[j], acc[i][j]);
  }

#pragma unroll
  for (int i = 0; i < 2; i++)
#pragma unroll
    for (int j = 0; j < 4; j++) {
      int n = n0 + j * 16 + lm;
      float bv = bias[n];
      int mbase = m0 + w * 32 + i * 16 + qd * 4;
#pragma unroll
      for (int r = 0; r < 4; r++) {
        int m = mbase + r;
        float v = acc[i][j][r] + bv;
        if (MODE == 0) {
          int bb = m >> 11, s = m & 2047, h = n >> 6, d = n & 63;
          ((bf16*)out)[((bb * H_ + h) * S_ + s) * DK_ + d] = (bf16)v;
        } else {
          ((float*)out)[m * D_ + n] = v;
        }
      }
    }
}

// ---------------------------------------------------------------- attention
// Bucket-sorted flash attention. Block = (q-tile slot, h, b); the tile's 64
// queries (sorted order, sentinel-padded) attend only to their bucket's keys.
__global__ __launch_bounds__(256) void k_attn(const bf16* __restrict__ Q,
                                              const bf16* __restrict__ K,
                                              const bf16* __restrict__ V,
                                              const int* __restrict__ qidx,
                                              const int* __restrict__ kidx,
                                              const int2* __restrict__ meta,
                                              bf16* __restrict__ O) {
  constexpr int LDK = 72;  // 144B row stride: 16B-aligned, 2-way (free)
  __shared__ bf16 Kl[64 * LDK];
  __shared__ bf16 Vl[64 * LDK];   // [dim][key]
  __shared__ bf16 Pl[64 * LDK];
  __shared__ int kbl[64];
  __shared__ int qsl[64];
  const int t = threadIdx.x;
  const int qt = blockIdx.x, h = blockIdx.y, b = blockIdx.z;
  const int lane = t & 63, w = t >> 6;
  const int lm = lane & 15, qd = lane >> 4;
  const int bh = b * H_ + h;

  const int2 mt = meta[bh * NQT + qt];
  const int kstart = mt.x, nkt = mt.y;

  if (t < 64) qsl[t] = qidx[bh * QPAD + qt * 64 + t];
  __syncthreads();

  if (nkt == 0) {  // unused tile slot, or (never in practice) empty key bucket
#pragma unroll
    for (int r = 0; r < 4; r++) {
      int qs = qsl[w * 16 + qd * 4 + r];
      if (qs >= 0)
#pragma unroll
        for (int nb = 0; nb < 4; nb++)
          O[((b * S_ + qs) * H_ + h) * DK_ + nb * 16 + lm] = (bf16)0.f;
    }
    return;
  }

  int qrow = qsl[w * 16 + lm];
  const bf16* Qp = Q + (bh * S_ + (qrow < 0 ? 0 : qrow)) * DK_;
  bf16x8 qf0 = *(const bf16x8*)(Qp + qd * 8);
  bf16x8 qf1 = *(const bf16x8*)(Qp + 32 + qd * 8);

  f32x4 oacc[4];
  float mrun[4], lrun[4];
#pragma unroll
  for (int nb = 0; nb < 4; nb++) oacc[nb] = zero4();
#pragma unroll
  for (int r = 0; r < 4; r++) { mrun[r] = -1e30f; lrun[r] = 0.f; }

  const bf16* Kbase = K + bh * S_ * DK_;
  const bf16* Vbase = V + bh * S_ * DK_;
  const int* kix = kidx + bh * QPAD + kstart;

  for (int kt = 0; kt < nkt; kt++) {
    const int kt0 = kt * 64;
    __syncthreads();
    if (t < 64) kbl[t] = kix[kt0 + t];
    // K tile [key][dim], gathered rows (128B each)
#pragma unroll
    for (int ss = 0; ss < 2; ss++) {
      int seg = t + ss * 256;
      int row = seg >> 3, sg = seg & 7;
      int ki = kix[kt0 + row]; ki = ki < 0 ? 0 : ki;
      *(bf16x8*)&Kl[row * LDK + sg * 8] =
          *(const bf16x8*)&Kbase[ki * DK_ + sg * 8];
    }
    // V tile transposed into [dim][key]; wave writes 64 consecutive keys at
    // uniform dim -> 2 lanes/bank, conflict-free
#pragma unroll
    for (int ss = 0; ss < 2; ss++) {
      int seg = t + ss * 256;
      int vrow = seg & 63, vsg = seg >> 6;
      int ki = kix[kt0 + vrow]; ki = ki < 0 ? 0 : ki;
      bf16x8 v8 = *(const bf16x8*)&Vbase[ki * DK_ + vsg * 8];
#pragma unroll
      for (int j = 0; j < 8; j++) Vl[(vsg * 8 + j) * LDK + vrow] = v8[j];
    }
    __syncthreads();

    // scores 16x64 per wave (C-layout: row=qd*4+r, col=nb*16+lm)
    f32x4 sc[4];
#pragma unroll
    for (int nb = 0; nb < 4; nb++) {
      bf16x8 kf0 = *(const bf16x8*)&Kl[(nb * 16 + lm) * LDK + qd * 8];
      bf16x8 kf1 = *(const bf16x8*)&Kl[(nb * 16 + lm) * LDK + 32 + qd * 8];
      f32x4 z = zero4();
      z = mfma_bf16(qf0, kf0, z);
      z = mfma_bf16(qf1, kf1, z);
      sc[nb] = z;
    }
    // sentinel slots (bucket padding) -> masked; valid -> scale 1/sqrt(64)
#pragma unroll
    for (int nb = 0; nb < 4; nb++) {
      bool valid = kbl[nb * 16 + lm] >= 0;
#pragma unroll
      for (int r = 0; r < 4; r++)
        sc[nb][r] = valid ? sc[nb][r] * 0.125f : -1e30f;
    }
    // online softmax
    float mnew[4], alpha[4], rs[4];
#pragma unroll
    for (int r = 0; r < 4; r++) {
      float tm = fmaxf(fmaxf(sc[0][r], sc[1][r]), fmaxf(sc[2][r], sc[3][r]));
      tm = fmaxf(tm, __shfl_xor(tm, 1));
      tm = fmaxf(tm, __shfl_xor(tm, 2));
      tm = fmaxf(tm, __shfl_xor(tm, 4));
      tm = fmaxf(tm, __shfl_xor(tm, 8));
      mnew[r] = fmaxf(mrun[r], tm);
      alpha[r] = __expf(mrun[r] - mnew[r]);
      mrun[r] = mnew[r];
      rs[r] = 0.f;
    }
#pragma unroll
    for (int nb = 0; nb < 4; nb++)
#pragma unroll
      for (int r = 0; r < 4; r++) {
        float p = (sc[nb][r] > -1e29f) ? __expf(sc[nb][r] - mnew[r]) : 0.f;
        sc[nb][r] = p;
        rs[r] += p;
      }
#pragma unroll
    for (int r = 0; r < 4; r++) {
      float s = rs[r];
      s += __shfl_xor(s, 1);
      s += __shfl_xor(s, 2);
      s += __shfl_xor(s, 4);
      s += __shfl_xor(s, 8);
      lrun[r] = lrun[r] * alpha[r] + s;
    }
#pragma unroll
    for (int nb = 0; nb < 4; nb++)
#pragma unroll
      for (int r = 0; r < 4; r++) oacc[nb][r] *= alpha[r];
    // P: C-layout -> A-layout via LDS
#pragma unroll
    for (int nb = 0; nb < 4; nb++)
#pragma unroll
      for (int r = 0; r < 4; r++)
        Pl[(w * 16 + qd * 4 + r) * LDK + nb * 16 + lm] = (bf16)sc[nb][r];
    __syncthreads();
    bf16x8 pa0 = *(const bf16x8*)&Pl[(w * 16 + lm) * LDK + qd * 8];
    bf16x8 pa1 = *(const bf16x8*)&Pl[(w * 16 + lm) * LDK + 32 + qd * 8];
#pragma unroll
    for (int nb = 0; nb < 4; nb++) {
      bf16x8 vf0 = *(const bf16x8*)&Vl[(nb * 16 + lm) * LDK + qd * 8];
      bf16x8 vf1 = *(const bf16x8*)&Vl[(nb * 16 + lm) * LDK + 32 + qd * 8];
      oacc[nb] = mfma_bf16(pa0, vf0, oacc[nb]);
      oacc[nb] = mfma_bf16(pa1, vf1, oacc[nb]);
    }
  }
  // epilogue: scatter O rows back to original positions
#pragma unroll
  for (int r = 0; r < 4; r++) {
    int qs = qsl[w * 16 + qd * 4 + r];
    if (qs < 0) continue;
    float l = lrun[r];
    float inv = (l > 0.f) ? 1.f / l : 0.f;
#pragma unroll
    for (int nb = 0; nb < 4; nb++)
      O[((b * S_ + qs) * H_ + h) * DK_ + nb * 16 + lm] = (bf16)(oacc[nb][r] * inv);
  }
}

// ---------------------------------------------------------------- launch
extern "C" void kernel_launch(void* const* d_in, const int* in_sizes, int n_in,
                              void* d_out, int out_size, void* d_ws, size_t ws_size,
                              hipStream_t stream) {
  (void)in_sizes; (void)n_in; (void)out_size; (void)ws_size;
  const float* x  = (const float*)d_in[0];
  const float* Wq = (const float*)d_in[1];
  const float* bq = (const float*)d_in[2];
  const float* Wk = (const float*)d_in[3];
  const float* bk = (const float*)d_in[4];
  const float* Wv = (const float*)d_in[5];
  const float* bv = (const float*)d_in[6];
  const float* Wo = (const float*)d_in[7];
  const float* bo = (const float*)d_in[8];
  const float* R  = (const float*)d_in[9];

  char* ws = (char*)d_ws;
  bf16*  xh   = (bf16*)(ws + 0);          // 8 MB
  bf16*  Qb   = (bf16*)(ws + 8388608);    // 8 MB  [B,H,S,DK]
  bf16*  Kb   = (bf16*)(ws + 16777216);   // 8 MB  [B,H,S,DK]
  bf16*  Vb   = (bf16*)(ws + 25165824);   // 8 MB  [B,H,S,DK]
  bf16*  Ob   = (bf16*)(ws + 33554432);   // 8 MB  [B,S,H,DK]; xm aliases
  bf16*  xm   = (bf16*)(ws + 33554432);
  bf16*  Wtq  = (bf16*)(ws + 41943040);   // 2 MB each
  bf16*  Wtk  = (bf16*)(ws + 44040192);
  bf16*  Wtv  = (bf16*)(ws + 46137344);
  bf16*  Wto  = (bf16*)(ws + 48234496);
  float* Pfull= (float*)(ws + 50331648);  // 1 MB fp32 [1024][256]
  int*   qbuf = (int*)(ws + 51380224);    // 256 KB each
  int*   kbuf = (int*)(ws + 51642368);
  float* bt   = (float*)(ws + 51904512);  // 1 KB
  bf16*  Pth  = (bf16*)(ws + 51905536);   // 512 KB each
  bf16*  Ptm  = (bf16*)(ws + 52429824);
  bf16*  Ptl  = (bf16*)(ws + 52954112);
  int*   qidxp= (int*)(ws + 53478400);    // 32*2560*4 = 320 KB
  int*   kidxp= (int*)(ws + 53806080);    // 320 KB
  int2*  meta = (int2*)(ws + 54133760);   // 10 KB; end ~54.2 MB
  bf16*  xl   = (bf16*)d_out;             // 8 MB in d_out (dead before final GEMM)

  k_cast_split<<<dim3(4096), dim3(256), 0, stream>>>(x, xh, xm, xl);
  k_transW<<<dim3(16, 16), dim3(256), 0, stream>>>(Wq, Wtq);
  k_transW<<<dim3(16, 16), dim3(256), 0, stream>>>(Wk, Wtk);
  k_transW<<<dim3(16, 16), dim3(256), 0, stream>>>(Wv, Wtv);
  k_transW<<<dim3(16, 16), dim3(256), 0, stream>>>(Wo, Wto);
  k_computeP<<<dim3(1024), dim3(256), 0, stream>>>(Wq, Wk, R, Pfull);
  k_bterm<<<dim3(1), dim3(256), 0, stream>>>(bq, bk, R, bt);
  k_transP<<<dim3(16, 4), dim3(256), 0, stream>>>(Pfull, Pth, Ptm, Ptl);

  k_lgemm<<<dim3(64, 4), dim3(256), 0, stream>>>(xh, xm, xl, Pth, Ptm, Ptl,
                                                 bt, qbuf, kbuf);
  k_sort<<<dim3(32), dim3(256), 0, stream>>>(qbuf, kbuf, qidxp, kidxp, meta);

  k_gemm<0><<<dim3(32, 16), dim3(256), 0, stream>>>(xh, Wtq, bq, (void*)Qb);
  k_gemm<0><<<dim3(32, 16), dim3(256), 0, stream>>>(xh, Wtk, bk, (void*)Kb);
  k_gemm<0><<<dim3(32, 16), dim3(256), 0, stream>>>(xh, Wtv, bv, (void*)Vb);

  k_attn<<<dim3(NQT, H_, B_), dim3(256), 0, stream>>>(Qb, Kb, Vb, qidxp, kidxp,
                                                      meta, Ob);

  k_gemm<2><<<dim3(32, 16), dim3(256), 0, stream>>>(Ob, Wto, bo, d_out);
}

// Round 5
// 251.468 us; speedup vs baseline: 1.8521x; 1.1568x over previous
//
#include <hip/hip_runtime.h>
#include <hip/hip_bf16.h>

// LSH Attention, MI355X gfx950.
// Pipeline:
//  1) split-cast x -> bf16 (xh, xm, xl)
//  2) P = W @ R^T folds (fp32) -> transpose+3-split bf16
//  3) k_lgemm: 6-term split-bf16 MFMA logits + fused argmax -> qb/kb
//     (global_load_lds staging)
//  4) k_sort: per-(b,h) counting sort by bucket, 64-aligned starts
//  5) k_gemm128<0>: fused Q/K/V projection, m97-style 128x128 tile with
//     global_load_lds width-16 (768 blocks = 3 blocks/CU queue depth)
//  6) bucket-sorted flash attention (64-q tiles attend own bucket only)
//  7) k_gemm128<2>: output GEMM -> fp32 d_out
//
// MFMA 16x16x32 bf16 layouts (verified in guide):
//  A: lane holds A[m=lane&15][k=(lane>>4)*8+j]
//  B: lane holds B[k=(lane>>4)*8+j][n=lane&15]
//  C/D: lane holds D[m=(lane>>4)*4+r][n=lane&15]

typedef __bf16 bf16;
typedef __bf16 bf16x8 __attribute__((ext_vector_type(8)));
typedef __bf16 bf16x4 __attribute__((ext_vector_type(4)));
typedef float f32x4 __attribute__((ext_vector_type(4)));

#define DEV static __device__ __forceinline__

DEV f32x4 zero4() { f32x4 z; z[0]=0.f; z[1]=0.f; z[2]=0.f; z[3]=0.f; return z; }

DEV f32x4 mfma_bf16(bf16x8 a, bf16x8 b, f32x4 c) {
  return __builtin_amdgcn_mfma_f32_16x16x32_bf16(a, b, c, 0, 0, 0);
}

// async global->LDS, 16B/lane; LDS dest = wave-uniform base + lane*16
DEV void load_lds16(const bf16* g, bf16* l) {
  __builtin_amdgcn_global_load_lds(
      (const __attribute__((address_space(1))) void*)g,
      (__attribute__((address_space(3))) void*)l, 16, 0, 0);
}

#define B_  2
#define S_  2048
#define D_  1024
#define H_  16
#define NH_ 8
#define DK_ 64
#define M_  4096   // B_*S_
#define QPAD 2560  // 2048 + 8*64 (per-bucket 64-alignment padding)
#define NQT  40    // max q-tiles per (b,h): 32 + 8

// ---------------------------------------------------------------- prep
__global__ void k_cast_split(const float* __restrict__ x, bf16* __restrict__ xh,
                             bf16* __restrict__ xm, bf16* __restrict__ xl) {
  int i = (blockIdx.x * 256 + threadIdx.x) * 4;
  f32x4 v = *(const f32x4*)(x + i);
  bf16x4 oh, om, ol;
#pragma unroll
  for (int j = 0; j < 4; j++) {
    float f = v[j];
    bf16 h = (bf16)f;
    float rm = f - (float)h;
    bf16 m = (bf16)rm;
    float rl = rm - (float)m;
    oh[j] = h; om[j] = m; ol[j] = (bf16)rl;
  }
  *(bf16x4*)(xh + i) = oh;
  *(bf16x4*)(xm + i) = om;
  *(bf16x4*)(xl + i) = ol;
}

// W [k][n] fp32 -> Wt [n][k] bf16 (64x64 LDS tile transpose), z selects matrix
__global__ void k_transW(const float* __restrict__ W0, const float* __restrict__ W1,
                         const float* __restrict__ W2, const float* __restrict__ W3,
                         bf16* __restrict__ T0, bf16* __restrict__ T1,
                         bf16* __restrict__ T2, bf16* __restrict__ T3) {
  __shared__ float tile[64][65];
  const float* W = blockIdx.z == 0 ? W0 : blockIdx.z == 1 ? W1 : blockIdx.z == 2 ? W2 : W3;
  bf16* Wt = blockIdx.z == 0 ? T0 : blockIdx.z == 1 ? T1 : blockIdx.z == 2 ? T2 : T3;
  int k0 = blockIdx.x * 64, n0 = blockIdx.y * 64;
  int c = threadIdx.x & 63, r4 = threadIdx.x >> 6;
#pragma unroll
  for (int i = 0; i < 16; i++) {
    int r = r4 * 16 + i;
    tile[r][c] = W[(k0 + r) * D_ + n0 + c];
  }
  __syncthreads();
#pragma unroll
  for (int i = 0; i < 16; i++) {
    int r = r4 * 16 + i;
    Wt[(n0 + r) * D_ + k0 + c] = (bf16)tile[c][r];
  }
}

// P[d][c] = sum_k W[d][h*64+k] * R[n][k], c = sel*128 + h*8 + n  (fp32)
__global__ void k_computeP(const float* __restrict__ Wq, const float* __restrict__ Wk,
                           const float* __restrict__ R, float* __restrict__ P) {
  int d = blockIdx.x;
  int t = threadIdx.x;           // 256 threads: c
  int hn = t & 127, h = hn >> 3, n = hn & 7;
  const float* W = (t < 128) ? Wq : Wk;
  const float* wrow = W + d * D_ + h * 64;
  const float* rrow = R + n * 64;
  float acc = 0.f;
#pragma unroll 8
  for (int k = 0; k < 64; k++) acc += wrow[k] * rrow[k];
  P[d * 256 + t] = acc;
}

// P fp32 [1024][256] -> Pt_{h,m,l} bf16 [256][1024] (transpose + 3-split)
__global__ void k_transP(const float* __restrict__ P, bf16* __restrict__ Pth,
                         bf16* __restrict__ Ptm, bf16* __restrict__ Ptl) {
  __shared__ float tile[64][65];
  int k0 = blockIdx.x * 64, n0 = blockIdx.y * 64;
  int c = threadIdx.x & 63, r4 = threadIdx.x >> 6;
#pragma unroll
  for (int i = 0; i < 16; i++) {
    int r = r4 * 16 + i;
    tile[r][c] = P[(k0 + r) * 256 + n0 + c];
  }
  __syncthreads();
#pragma unroll
  for (int i = 0; i < 16; i++) {
    int r = r4 * 16 + i;
    float v = tile[c][r];
    bf16 h = (bf16)v;
    float rm = v - (float)h;
    bf16 m = (bf16)rm;
    bf16 l = (bf16)(rm - (float)m);
    int o = (n0 + r) * D_ + k0 + c;
    Pth[o] = h; Ptm[o] = m; Ptl[o] = l;
  }
}

// bterm[0:128]=bq.R, [128:256]=bk.R
__global__ void k_bterm(const float* __restrict__ bq, const float* __restrict__ bk,
                        const float* __restrict__ R, float* __restrict__ bt) {
  int t = threadIdx.x;  // 256
  const float* b = (t < 128) ? bq : bk;
  int hn = t & 127, h = hn >> 3, n = hn & 7;
  float acc = 0.f;
#pragma unroll 8
  for (int k = 0; k < 64; k++) acc += b[h * 64 + k] * R[n * 64 + k];
  bt[t] = acc;
}

// ---------------------------------------------------------------- logits GEMM
// logits[m][n] = (xh+xm+xl).(Ph+Pm+Pl) + bt[n], 6-term split (argmax-exact).
// 64x64 tile, global_load_lds staging (6 tiles x 4 quarters = 24 wave-instrs).
__global__ __launch_bounds__(256) void k_lgemm(const bf16* __restrict__ xh,
                                               const bf16* __restrict__ xm,
                                               const bf16* __restrict__ xl,
                                               const bf16* __restrict__ Pth,
                                               const bf16* __restrict__ Ptm,
                                               const bf16* __restrict__ Ptl,
                                               const float* __restrict__ bt,
                                               int* __restrict__ qb,
                                               int* __restrict__ kb) {
  __shared__ bf16 Ls[6][64 * 32];   // [xh,xm,xl,Ph,Pm,Pl] tiles, unpadded
  const int t = threadIdx.x;
  const int m0 = blockIdx.x * 64, n0 = blockIdx.y * 64;
  const int lane = t & 63, w = t >> 6;
  const int lm = lane & 15, qd = lane >> 4;
  const bf16* src6[6] = {xh, xm, xl, Pth, Ptm, Ptl};
  const int srow = lane >> 2, sseg = lane & 3;  // 16 rows x 4 segs per instr

  f32x4 acc[4];
#pragma unroll
  for (int nb = 0; nb < 4; nb++) acc[nb] = zero4();

  for (int k0 = 0; k0 < D_; k0 += 32) {
    __syncthreads();
#pragma unroll
    for (int r3 = 0; r3 < 6; r3++) {
      int ii = r3 * 4 + w;          // 0..23, bijective over (tile, quarter)
      int tt = ii >> 2, qq = ii & 3;
      int base = (tt < 3 ? m0 : n0) + qq * 16 + srow;
      load_lds16(&src6[tt][base * D_ + k0 + sseg * 8], &Ls[tt][qq * 16 * 32]);
    }
    __syncthreads();
    bf16x8 af[3], bfr[3][4];
#pragma unroll
    for (int i3 = 0; i3 < 3; i3++) {
      af[i3] = *(const bf16x8*)&Ls[i3][(w * 16 + lm) * 32 + qd * 8];
#pragma unroll
      for (int nb = 0; nb < 4; nb++)
        bfr[i3][nb] = *(const bf16x8*)&Ls[3 + i3][(nb * 16 + lm) * 32 + qd * 8];
    }
#pragma unroll
    for (int nb = 0; nb < 4; nb++) {
      f32x4 a = acc[nb];
      a = mfma_bf16(af[0], bfr[0][nb], a);  // hh
      a = mfma_bf16(af[0], bfr[1][nb], a);  // hm
      a = mfma_bf16(af[1], bfr[0][nb], a);  // mh
      a = mfma_bf16(af[0], bfr[2][nb], a);  // hl
      a = mfma_bf16(af[2], bfr[0][nb], a);  // lh
      a = mfma_bf16(af[1], bfr[1][nb], a);  // mm
      acc[nb] = a;
    }
  }

  // fused argmax over groups of 8 cols (first-max tie-break = np.argmax)
#pragma unroll
  for (int nb = 0; nb < 4; nb++) {
    int n = n0 + nb * 16 + lm;
    float btv = bt[n];
#pragma unroll
    for (int r = 0; r < 4; r++) {
      float v = acc[nb][r] + btv;
      int idx = lm & 7;
#pragma unroll
      for (int mask = 1; mask <= 4; mask <<= 1) {
        float pv = __shfl_xor(v, mask);
        int pi = __shfl_xor(idx, mask);
        if (pv > v || (pv == v && pi < idx)) { v = pv; idx = pi; }
      }
      if ((lm & 7) == 0) {
        int m = m0 + w * 16 + qd * 4 + r;
        int g = n >> 3;                 // 0..31
        int sel = g >> 4, head = g & 15;
        int bb = m >> 11, s = m & 2047;
        (sel ? kb : qb)[(bb * H_ + head) * S_ + s] = idx;
      }
    }
  }
}

// ---------------------------------------------------------------- bucket sort
// One block per (b,h). Stable counting sort of q and k positions by bucket,
// bucket starts padded to 64; per-q-tile metadata {kstart, nktiles}.
__global__ __launch_bounds__(256) void k_sort(const int* __restrict__ qb,
                                              const int* __restrict__ kb,
                                              int* __restrict__ qidx,
                                              int* __restrict__ kidx,
                                              int2* __restrict__ meta) {
  __shared__ int cnt[8][257];
  __shared__ int bst[2][9];
  __shared__ int tot[2][8];
  const int bh = blockIdx.x;
  const int t = threadIdx.x;
  for (int which = 0; which < 2; which++) {
    const int* src = (which ? kb : qb) + bh * S_;
    int* dst = (which ? kidx : qidx) + bh * QPAD;
    for (int i = t; i < QPAD; i += 256) dst[i] = -1;
    int vals[8];
    int lc[8] = {0, 0, 0, 0, 0, 0, 0, 0};
#pragma unroll
    for (int j = 0; j < 8; j++) { int b = src[t * 8 + j]; vals[j] = b; lc[b]++; }
#pragma unroll
    for (int b = 0; b < 8; b++) cnt[b][t] = lc[b];
    __syncthreads();
    if (t < 8) {  // exclusive scan per bucket over 256 thread slots
      int run = 0;
      for (int i = 0; i < 256; i++) { int c = cnt[t][i]; cnt[t][i] = run; run += c; }
      tot[which][t] = run;
    }
    __syncthreads();
    if (t == 0) {
      int pos = 0;
      for (int b = 0; b < 8; b++) {
        bst[which][b] = pos;
        pos += (tot[which][b] + 63) & ~63;
      }
      bst[which][8] = pos;
    }
    __syncthreads();
    int run2[8] = {0, 0, 0, 0, 0, 0, 0, 0};
#pragma unroll
    for (int j = 0; j < 8; j++) {
      int b = vals[j];
      int pos = bst[which][b] + cnt[b][t] + run2[b]++;
      dst[pos] = t * 8 + j;
    }
    __syncthreads();
  }
  if (t == 0) {
    for (int tt = 0; tt < NQT; tt++) meta[bh * NQT + tt] = make_int2(0, 0);
    for (int b = 0; b < 8; b++) {
      int t0 = bst[0][b] >> 6;
      int nt = ((tot[0][b] + 63) & ~63) >> 6;
      int ks = bst[1][b];
      int nkt = (tot[1][b] + 63) >> 6;
      for (int tt = t0; tt < t0 + nt; tt++)
        meta[bh * NQT + tt] = make_int2(ks, nkt);
    }
  }
}

// ---------------------------------------------------------------- m97 GEMM
// C[m][n] = sum_k A[m][k]*Bt[n][k] + bias[n];  128x128 tile, BK=32,
// global_load_lds width-16, 4 waves in 2x2 quadrants, 4x4 acc each.
// blockIdx.y >> 3 selects matrix {0,1,2} (fused QKV); grid.y=8 -> always 0.
// MODE 0: out bf16 [B,H,S,DK];  MODE 2: out fp32 [m][n]
template <int MODE>
__global__ __launch_bounds__(256) void k_gemm128(
    const bf16* __restrict__ A,
    const bf16* __restrict__ Bt0, const bf16* __restrict__ Bt1,
    const bf16* __restrict__ Bt2,
    const float* __restrict__ bi0, const float* __restrict__ bi1,
    const float* __restrict__ bi2,
    void* __restrict__ o0, void* __restrict__ o1, void* __restrict__ o2) {
  __shared__ bf16 Al[128 * 32];
  __shared__ bf16 Bl[128 * 32];
  const int t = threadIdx.x;
  const int lane = t & 63, w = t >> 6;
  const int m0 = blockIdx.x * 128;
  const int mat = blockIdx.y >> 3;
  const int n0 = (blockIdx.y & 7) * 128;
  const bf16* Bt = mat == 0 ? Bt0 : (mat == 1 ? Bt1 : Bt2);
  const float* bias = mat == 0 ? bi0 : (mat == 1 ? bi1 : bi2);
  void* out = mat == 0 ? o0 : (mat == 1 ? o1 : o2);
  const int lm = lane & 15, qd = lane >> 4;
  const int wm = w >> 1, wn = w & 1;            // wave quadrant in 2x2
  const int srow = lane >> 2, sseg = lane & 3;  // 16 rows x 4 segs per instr

  f32x4 acc[4][4];
#pragma unroll
  for (int i = 0; i < 4; i++)
#pragma unroll
    for (int j = 0; j < 4; j++) acc[i][j] = zero4();

  for (int k0 = 0; k0 < D_; k0 += 32) {
    __syncthreads();
    // A/B tiles 128x32: 8 wave-instrs each (2 per wave)
    load_lds16(&A[(m0 + w * 16 + srow) * D_ + k0 + sseg * 8],
               &Al[(w * 16) * 32]);
    load_lds16(&A[(m0 + 64 + w * 16 + srow) * D_ + k0 + sseg * 8],
               &Al[(64 + w * 16) * 32]);
    load_lds16(&Bt[(n0 + w * 16 + srow) * D_ + k0 + sseg * 8],
               &Bl[(w * 16) * 32]);
    load_lds16(&Bt[(n0 + 64 + w * 16 + srow) * D_ + k0 + sseg * 8],
               &Bl[(64 + w * 16) * 32]);
    __syncthreads();
    bf16x8 af[4], bfr[4];
#pragma unroll
    for (int i = 0; i < 4; i++)
      af[i] = *(const bf16x8*)&Al[(wm * 64 + i * 16 + lm) * 32 + qd * 8];
#pragma unroll
    for (int j = 0; j < 4; j++)
      bfr[j] = *(const bf16x8*)&Bl[(wn * 64 + j * 16 + lm) * 32 + qd * 8];
#pragma unroll
    for (int i = 0; i < 4; i++)
#pragma unroll
      for (int j = 0; j < 4; j++) acc[i][j] = mfma_bf16(af[i], bfr[j], acc[i][j]);
  }

#pragma unroll
  for (int j = 0; j < 4; j++) {
    int n = n0 + wn * 64 + j * 16 + lm;
    float bv = bias[n];
#pragma unroll
    for (int i = 0; i < 4; i++) {
      int mbase = m0 + wm * 64 + i * 16 + qd * 4;
#pragma unroll
      for (int r = 0; r < 4; r++) {
        int m = mbase + r;
        float v = acc[i][j][r] + bv;
        if (MODE == 0) {
          int bb = m >> 11, s = m & 2047, hh = n >> 6, d = n & 63;
          ((bf16*)out)[((bb * H_ + hh) * S_ + s) * DK_ + d] = (bf16)v;
        } else {
          ((float*)out)[m * D_ + n] = v;
        }
      }
    }
  }
}

// ---------------------------------------------------------------- attention
// Bucket-sorted flash attention. Block = (q-tile slot, h, b); the tile's 64
// queries (sorted order, sentinel-padded) attend only to their bucket's keys.
__global__ __launch_bounds__(256) void k_attn(const bf16* __restrict__ Q,
                                              const bf16* __restrict__ K,
                                              const bf16* __restrict__ V,
                                              const int* __restrict__ qidx,
                                              const int* __restrict__ kidx,
                                              const int2* __restrict__ meta,
                                              bf16* __restrict__ O) {
  constexpr int LDK = 72;  // 144B row stride: 16B-aligned, 2-way (free)
  __shared__ bf16 Kl[64 * LDK];
  __shared__ bf16 Vl[64 * LDK];   // [dim][key]
  __shared__ bf16 Pl[64 * LDK];
  __shared__ int kbl[64];
  __shared__ int qsl[64];
  const int t = threadIdx.x;
  const int qt = blockIdx.x, h = blockIdx.y, b = blockIdx.z;
  const int lane = t & 63, w = t >> 6;
  const int lm = lane & 15, qd = lane >> 4;
  const int bh = b * H_ + h;

  const int2 mt = meta[bh * NQT + qt];
  const int kstart = mt.x, nkt = mt.y;

  if (t < 64) qsl[t] = qidx[bh * QPAD + qt * 64 + t];
  __syncthreads();

  if (nkt == 0) {  // unused tile slot, or (never in practice) empty key bucket
#pragma unroll
    for (int r = 0; r < 4; r++) {
      int qs = qsl[w * 16 + qd * 4 + r];
      if (qs >= 0)
#pragma unroll
        for (int nb = 0; nb < 4; nb++)
          O[((b * S_ + qs) * H_ + h) * DK_ + nb * 16 + lm] = (bf16)0.f;
    }
    return;
  }

  int qrow = qsl[w * 16 + lm];
  const bf16* Qp = Q + (bh * S_ + (qrow < 0 ? 0 : qrow)) * DK_;
  bf16x8 qf0 = *(const bf16x8*)(Qp + qd * 8);
  bf16x8 qf1 = *(const bf16x8*)(Qp + 32 + qd * 8);

  f32x4 oacc[4];
  float mrun[4], lrun[4];
#pragma unroll
  for (int nb = 0; nb < 4; nb++) oacc[nb] = zero4();
#pragma unroll
  for (int r = 0; r < 4; r++) { mrun[r] = -1e30f; lrun[r] = 0.f; }

  const bf16* Kbase = K + bh * S_ * DK_;
  const bf16* Vbase = V + bh * S_ * DK_;
  const int* kix = kidx + bh * QPAD + kstart;

  for (int kt = 0; kt < nkt; kt++) {
    const int kt0 = kt * 64;
    __syncthreads();
    if (t < 64) kbl[t] = kix[kt0 + t];
    // K tile [key][dim], gathered rows (128B each)
#pragma unroll
    for (int ss = 0; ss < 2; ss++) {
      int seg = t + ss * 256;
      int row = seg >> 3, sg = seg & 7;
      int ki = kix[kt0 + row]; ki = ki < 0 ? 0 : ki;
      *(bf16x8*)&Kl[row * LDK + sg * 8] =
          *(const bf16x8*)&Kbase[ki * DK_ + sg * 8];
    }
    // V tile transposed into [dim][key]; wave writes 64 consecutive keys at
    // uniform dim -> 2 lanes/bank, conflict-free
#pragma unroll
    for (int ss = 0; ss < 2; ss++) {
      int seg = t + ss * 256;
      int vrow = seg & 63, vsg = seg >> 6;
      int ki = kix[kt0 + vrow]; ki = ki < 0 ? 0 : ki;
      bf16x8 v8 = *(const bf16x8*)&Vbase[ki * DK_ + vsg * 8];
#pragma unroll
      for (int j = 0; j < 8; j++) Vl[(vsg * 8 + j) * LDK + vrow] = v8[j];
    }
    __syncthreads();

    // scores 16x64 per wave (C-layout: row=qd*4+r, col=nb*16+lm)
    f32x4 sc[4];
#pragma unroll
    for (int nb = 0; nb < 4; nb++) {
      bf16x8 kf0 = *(const bf16x8*)&Kl[(nb * 16 + lm) * LDK + qd * 8];
      bf16x8 kf1 = *(const bf16x8*)&Kl[(nb * 16 + lm) * LDK + 32 + qd * 8];
      f32x4 z = zero4();
      z = mfma_bf16(qf0, kf0, z);
      z = mfma_bf16(qf1, kf1, z);
      sc[nb] = z;
    }
    // sentinel slots (bucket padding) -> masked; valid -> scale 1/sqrt(64)
#pragma unroll
    for (int nb = 0; nb < 4; nb++) {
      bool valid = kbl[nb * 16 + lm] >= 0;
#pragma unroll
      for (int r = 0; r < 4; r++)
        sc[nb][r] = valid ? sc[nb][r] * 0.125f : -1e30f;
    }
    // online softmax
    float mnew[4], alpha[4], rs[4];
#pragma unroll
    for (int r = 0; r < 4; r++) {
      float tm = fmaxf(fmaxf(sc[0][r], sc[1][r]), fmaxf(sc[2][r], sc[3][r]));
      tm = fmaxf(tm, __shfl_xor(tm, 1));
      tm = fmaxf(tm, __shfl_xor(tm, 2));
      tm = fmaxf(tm, __shfl_xor(tm, 4));
      tm = fmaxf(tm, __shfl_xor(tm, 8));
      mnew[r] = fmaxf(mrun[r], tm);
      alpha[r] = __expf(mrun[r] - mnew[r]);
      mrun[r] = mnew[r];
      rs[r] = 0.f;
    }
#pragma unroll
    for (int nb = 0; nb < 4; nb++)
#pragma unroll
      for (int r = 0; r < 4; r++) {
        float p = (sc[nb][r] > -1e29f) ? __expf(sc[nb][r] - mnew[r]) : 0.f;
        sc[nb][r] = p;
        rs[r] += p;
      }
#pragma unroll
    for (int r = 0; r < 4; r++) {
      float s = rs[r];
      s += __shfl_xor(s, 1);
      s += __shfl_xor(s, 2);
      s += __shfl_xor(s, 4);
      s += __shfl_xor(s, 8);
      lrun[r] = lrun[r] * alpha[r] + s;
    }
#pragma unroll
    for (int nb = 0; nb < 4; nb++)
#pragma unroll
      for (int r = 0; r < 4; r++) oacc[nb][r] *= alpha[r];
    // P: C-layout -> A-layout via LDS
#pragma unroll
    for (int nb = 0; nb < 4; nb++)
#pragma unroll
      for (int r = 0; r < 4; r++)
        Pl[(w * 16 + qd * 4 + r) * LDK + nb * 16 + lm] = (bf16)sc[nb][r];
    __syncthreads();
    bf16x8 pa0 = *(const bf16x8*)&Pl[(w * 16 + lm) * LDK + qd * 8];
    bf16x8 pa1 = *(const bf16x8*)&Pl[(w * 16 + lm) * LDK + 32 + qd * 8];
#pragma unroll
    for (int nb = 0; nb < 4; nb++) {
      bf16x8 vf0 = *(const bf16x8*)&Vl[(nb * 16 + lm) * LDK + qd * 8];
      bf16x8 vf1 = *(const bf16x8*)&Vl[(nb * 16 + lm) * LDK + 32 + qd * 8];
      oacc[nb] = mfma_bf16(pa0, vf0, oacc[nb]);
      oacc[nb] = mfma_bf16(pa1, vf1, oacc[nb]);
    }
  }
  // epilogue: scatter O rows back to original positions
#pragma unroll
  for (int r = 0; r < 4; r++) {
    int qs = qsl[w * 16 + qd * 4 + r];
    if (qs < 0) continue;
    float l = lrun[r];
    float inv = (l > 0.f) ? 1.f / l : 0.f;
#pragma unroll
    for (int nb = 0; nb < 4; nb++)
      O[((b * S_ + qs) * H_ + h) * DK_ + nb * 16 + lm] = (bf16)(oacc[nb][r] * inv);
  }
}

// ---------------------------------------------------------------- launch
extern "C" void kernel_launch(void* const* d_in, const int* in_sizes, int n_in,
                              void* d_out, int out_size, void* d_ws, size_t ws_size,
                              hipStream_t stream) {
  (void)in_sizes; (void)n_in; (void)out_size; (void)ws_size;
  const float* x  = (const float*)d_in[0];
  const float* Wq = (const float*)d_in[1];
  const float* bq = (const float*)d_in[2];
  const float* Wk = (const float*)d_in[3];
  const float* bk = (const float*)d_in[4];
  const float* Wv = (const float*)d_in[5];
  const float* bv = (const float*)d_in[6];
  const float* Wo = (const float*)d_in[7];
  const float* bo = (const float*)d_in[8];
  const float* R  = (const float*)d_in[9];

  char* ws = (char*)d_ws;
  bf16*  xh   = (bf16*)(ws + 0);          // 8 MB
  bf16*  Qb   = (bf16*)(ws + 8388608);    // 8 MB  [B,H,S,DK]
  bf16*  Kb   = (bf16*)(ws + 16777216);   // 8 MB  [B,H,S,DK]
  bf16*  Vb   = (bf16*)(ws + 25165824);   // 8 MB  [B,H,S,DK]
  bf16*  Ob   = (bf16*)(ws + 33554432);   // 8 MB  [B,S,H,DK]; xm aliases
  bf16*  xm   = (bf16*)(ws + 33554432);
  bf16*  Wtq  = (bf16*)(ws + 41943040);   // 2 MB each
  bf16*  Wtk  = (bf16*)(ws + 44040192);
  bf16*  Wtv  = (bf16*)(ws + 46137344);
  bf16*  Wto  = (bf16*)(ws + 48234496);
  float* Pfull= (float*)(ws + 50331648);  // 1 MB fp32 [1024][256]
  int*   qbuf = (int*)(ws + 51380224);    // 256 KB each
  int*   kbuf = (int*)(ws + 51642368);
  float* bt   = (float*)(ws + 51904512);  // 1 KB
  bf16*  Pth  = (bf16*)(ws + 51905536);   // 512 KB each
  bf16*  Ptm  = (bf16*)(ws + 52429824);
  bf16*  Ptl  = (bf16*)(ws + 52954112);
  int*   qidxp= (int*)(ws + 53478400);    // 32*2560*4 = 320 KB
  int*   kidxp= (int*)(ws + 53806080);    // 320 KB
  int2*  meta = (int2*)(ws + 54133760);   // 10 KB; end ~54.2 MB
  bf16*  xl   = (bf16*)d_out;             // 8 MB in d_out (dead before final GEMM)

  k_cast_split<<<dim3(4096), dim3(256), 0, stream>>>(x, xh, xm, xl);
  k_transW<<<dim3(16, 16, 4), dim3(256), 0, stream>>>(Wq, Wk, Wv, Wo,
                                                      Wtq, Wtk, Wtv, Wto);
  k_computeP<<<dim3(1024), dim3(256), 0, stream>>>(Wq, Wk, R, Pfull);
  k_bterm<<<dim3(1), dim3(256), 0, stream>>>(bq, bk, R, bt);
  k_transP<<<dim3(16, 4), dim3(256), 0, stream>>>(Pfull, Pth, Ptm, Ptl);

  k_lgemm<<<dim3(64, 4), dim3(256), 0, stream>>>(xh, xm, xl, Pth, Ptm, Ptl,
                                                 bt, qbuf, kbuf);
  k_sort<<<dim3(32), dim3(256), 0, stream>>>(qbuf, kbuf, qidxp, kidxp, meta);

  // fused Q/K/V projection: grid.y = 3 mats x 8 n-tiles = 768 blocks
  k_gemm128<0><<<dim3(32, 24), dim3(256), 0, stream>>>(
      xh, Wtq, Wtk, Wtv, bq, bk, bv, (void*)Qb, (void*)Kb, (void*)Vb);

  k_attn<<<dim3(NQT, H_, B_), dim3(256), 0, stream>>>(Qb, Kb, Vb, qidxp, kidxp,
                                                      meta, Ob);

  k_gemm128<2><<<dim3(32, 8), dim3(256), 0, stream>>>(
      Ob, Wto, Wto, Wto, bo, bo, bo, d_out, d_out, d_out);
}

// Round 6
// 240.776 us; speedup vs baseline: 1.9343x; 1.0444x over previous
//
#include <hip/hip_runtime.h>
#include <hip/hip_bf16.h>

// LSH Attention, MI355X gfx950.  5-dispatch pipeline:
//  1) k_prep  (z-branch): transW x4, x->bf16 cast, P=W@R^T fold + 3-split,
//     bterm  — all independent prep in ONE launch
//  2) k_main  (y-branch): fused bucket-logit GEMM (6-term split-bf16,
//     in-register x split, fused argmax -> qb/kb) + Q/K/V projection GEMM
//     (m97-style 128x128, global_load_lds width-16)
//  3) k_sort: per-(b,h) counting sort by bucket (wave-parallel prefix scan)
//  4) k_attn: bucket-sorted flash attention
//  5) k_gout: output GEMM 64x128 tiles -> fp32 d_out
//
// MFMA 16x16x32 bf16 layouts (verified in guide):
//  A: lane holds A[m=lane&15][k=(lane>>4)*8+j]
//  B: lane holds B[k=(lane>>4)*8+j][n=lane&15]
//  C/D: lane holds D[m=(lane>>4)*4+r][n=lane&15]

typedef __bf16 bf16;
typedef __bf16 bf16x8 __attribute__((ext_vector_type(8)));
typedef __bf16 bf16x4 __attribute__((ext_vector_type(4)));
typedef float f32x4 __attribute__((ext_vector_type(4)));

#define DEV static __device__ __forceinline__

DEV f32x4 zero4() { f32x4 z; z[0]=0.f; z[1]=0.f; z[2]=0.f; z[3]=0.f; return z; }

DEV f32x4 mfma_bf16(bf16x8 a, bf16x8 b, f32x4 c) {
  return __builtin_amdgcn_mfma_f32_16x16x32_bf16(a, b, c, 0, 0, 0);
}

// async global->LDS, 16B/lane; LDS dest = wave-uniform base + lane*16
DEV void load_lds16(const bf16* g, bf16* l) {
  __builtin_amdgcn_global_load_lds(
      (const __attribute__((address_space(1))) void*)g,
      (__attribute__((address_space(3))) void*)l, 16, 0, 0);
}

DEV void split3(float f, bf16& h, bf16& m, bf16& l) {
  h = (bf16)f;
  float rm = f - (float)h;
  m = (bf16)rm;
  l = (bf16)(rm - (float)m);
}

#define B_  2
#define S_  2048
#define D_  1024
#define H_  16
#define NH_ 8
#define DK_ 64
#define M_  4096   // B_*S_
#define QPAD 2560  // 2048 + 8*64 (per-bucket 64-alignment padding)
#define NQT  40    // max q-tiles per (b,h): 32 + 8

// ---------------------------------------------------------------- prep
// z<4: transW (64x64 transpose+cast); z=4: x->bf16; z=5 (64 blocks):
// P[d][c]=W(:,h*64:)@R[n]^T fold, 3-split transposed write, + bterm.
__global__ __launch_bounds__(256) void k_prep(
    const float* __restrict__ Wq, const float* __restrict__ Wk,
    const float* __restrict__ Wv, const float* __restrict__ Wo,
    const float* __restrict__ x, const float* __restrict__ bq,
    const float* __restrict__ bk, const float* __restrict__ R,
    bf16* __restrict__ Wtq, bf16* __restrict__ Wtk,
    bf16* __restrict__ Wtv, bf16* __restrict__ Wto,
    bf16* __restrict__ xh, bf16* __restrict__ Pth, bf16* __restrict__ Ptm,
    bf16* __restrict__ Ptl, float* __restrict__ bt) {
  __shared__ float tile[64][65];
  __shared__ float Rl[512];
  const int t = threadIdx.x;
  const int z = blockIdx.z;
  if (z < 4) {
    const float* W = z == 0 ? Wq : z == 1 ? Wk : z == 2 ? Wv : Wo;
    bf16* Wt = z == 0 ? Wtq : z == 1 ? Wtk : z == 2 ? Wtv : Wto;
    int k0 = blockIdx.x * 64, n0 = blockIdx.y * 64;
    int c = t & 63, r4 = t >> 6;
#pragma unroll
    for (int i = 0; i < 16; i++) {
      int r = r4 * 16 + i;
      tile[r][c] = W[(k0 + r) * D_ + n0 + c];
    }
    __syncthreads();
#pragma unroll
    for (int i = 0; i < 16; i++) {
      int r = r4 * 16 + i;
      Wt[(n0 + r) * D_ + k0 + c] = (bf16)tile[c][r];
    }
  } else if (z == 4) {
    int bid = blockIdx.y * 16 + blockIdx.x;
    int base = bid * 16384 + t * 4;
#pragma unroll 4
    for (int it = 0; it < 16; it++) {
      int i = base + it * 1024;
      f32x4 v = *(const f32x4*)(x + i);
      bf16x4 o;
#pragma unroll
      for (int j = 0; j < 4; j++) o[j] = (bf16)v[j];
      *(bf16x4*)(xh + i) = o;
    }
  } else {
    int bid = blockIdx.y * 16 + blockIdx.x;
    if (bid >= 64) return;
    Rl[t] = R[t];
    Rl[t + 256] = R[t + 256];
    __syncthreads();
    const int d0 = bid * 16;
    const int sel = t >> 7, hn = t & 127, h = hn >> 3, n = hn & 7;
    const float* W = sel ? Wk : Wq;
    const float* Rr = &Rl[n * 64];
    bf16x8 vh[2], vm[2], vl[2];
#pragma unroll
    for (int dl = 0; dl < 16; dl++) {
      const float* wr = W + (d0 + dl) * D_ + h * 64;
      float acc = 0.f;
#pragma unroll
      for (int k = 0; k < 64; k += 4) {
        f32x4 wv = *(const f32x4*)(wr + k);
        acc += (wv[0] * Rr[k] + wv[1] * Rr[k + 1]) +
               (wv[2] * Rr[k + 2] + wv[3] * Rr[k + 3]);
      }
      bf16 hh, mm, ll;
      split3(acc, hh, mm, ll);
      vh[dl >> 3][dl & 7] = hh;
      vm[dl >> 3][dl & 7] = mm;
      vl[dl >> 3][dl & 7] = ll;
    }
    *(bf16x8*)&Pth[t * D_ + d0] = vh[0];
    *(bf16x8*)&Pth[t * D_ + d0 + 8] = vh[1];
    *(bf16x8*)&Ptm[t * D_ + d0] = vm[0];
    *(bf16x8*)&Ptm[t * D_ + d0 + 8] = vm[1];
    *(bf16x8*)&Ptl[t * D_ + d0] = vl[0];
    *(bf16x8*)&Ptl[t * D_ + d0 + 8] = vl[1];
    if (bid == 0) {
      const float* bb = sel ? bk : bq;
      float acc = 0.f;
#pragma unroll 8
      for (int k = 0; k < 64; k++) acc += bb[h * 64 + k] * Rr[k];
      bt[t] = acc;
    }
  }
}

// ---------------------------------------------------------------- main fused
// y<24 (x<32): QKV projection GEMM, 128x128 tile, mat=y>>3, n0=(y&7)*128.
// y>=24: bucket-logit GEMM 64x64, m0=x*64, n0=(y-24)*64: 6-term split-bf16
// (x split h/m/l in-register during staging) + fused argmax -> qb/kb.
__global__ __launch_bounds__(256) void k_main(
    const float* __restrict__ x, const bf16* __restrict__ xh,
    const bf16* __restrict__ Wtq, const bf16* __restrict__ Wtk,
    const bf16* __restrict__ Wtv, const float* __restrict__ bq,
    const float* __restrict__ bk, const float* __restrict__ bv,
    const bf16* __restrict__ Pth, const bf16* __restrict__ Ptm,
    const bf16* __restrict__ Ptl, const float* __restrict__ bt,
    bf16* __restrict__ Qb, bf16* __restrict__ Kb, bf16* __restrict__ Vb,
    int* __restrict__ qb, int* __restrict__ kb) {
  __shared__ __align__(16) bf16 SA[3][2048];
  __shared__ __align__(16) bf16 SB[3][2048];
  const int t = threadIdx.x;
  const int lane = t & 63, w = t >> 6;
  const int lm = lane & 15, qd = lane >> 4;
  const int srow = lane >> 2, sseg = lane & 3;  // 16 rows x 4 segs per instr

  if (blockIdx.y < 24) {  // ---------------- QKV GEMM
    if (blockIdx.x >= 32) return;
    bf16* Al = &SA[0][0];  // 128x32 contiguous
    bf16* Bl = &SB[0][0];
    const int m0 = blockIdx.x * 128;
    const int mat = blockIdx.y >> 3;
    const int n0 = (blockIdx.y & 7) * 128;
    const bf16* Bt = mat == 0 ? Wtq : (mat == 1 ? Wtk : Wtv);
    const float* bias = mat == 0 ? bq : (mat == 1 ? bk : bv);
    bf16* out = mat == 0 ? Qb : (mat == 1 ? Kb : Vb);
    const int wm = w >> 1, wn = w & 1;

    f32x4 acc[4][4];
#pragma unroll
    for (int i = 0; i < 4; i++)
#pragma unroll
      for (int j = 0; j < 4; j++) acc[i][j] = zero4();

    for (int k0 = 0; k0 < D_; k0 += 32) {
      __syncthreads();
      load_lds16(&xh[(m0 + w * 16 + srow) * D_ + k0 + sseg * 8],
                 &Al[(w * 16) * 32]);
      load_lds16(&xh[(m0 + 64 + w * 16 + srow) * D_ + k0 + sseg * 8],
                 &Al[(64 + w * 16) * 32]);
      load_lds16(&Bt[(n0 + w * 16 + srow) * D_ + k0 + sseg * 8],
                 &Bl[(w * 16) * 32]);
      load_lds16(&Bt[(n0 + 64 + w * 16 + srow) * D_ + k0 + sseg * 8],
                 &Bl[(64 + w * 16) * 32]);
      __syncthreads();
      bf16x8 af[4], bfr[4];
#pragma unroll
      for (int i = 0; i < 4; i++)
        af[i] = *(const bf16x8*)&Al[(wm * 64 + i * 16 + lm) * 32 + qd * 8];
#pragma unroll
      for (int j = 0; j < 4; j++)
        bfr[j] = *(const bf16x8*)&Bl[(wn * 64 + j * 16 + lm) * 32 + qd * 8];
#pragma unroll
      for (int i = 0; i < 4; i++)
#pragma unroll
        for (int j = 0; j < 4; j++)
          acc[i][j] = mfma_bf16(af[i], bfr[j], acc[i][j]);
    }
#pragma unroll
    for (int j = 0; j < 4; j++) {
      int n = n0 + wn * 64 + j * 16 + lm;
      float bv2 = bias[n];
#pragma unroll
      for (int i = 0; i < 4; i++) {
        int mbase = m0 + wm * 64 + i * 16 + qd * 4;
#pragma unroll
        for (int r = 0; r < 4; r++) {
          int m = mbase + r;
          int bb = m >> 11, s = m & 2047, hh = n >> 6, d = n & 63;
          out[((bb * H_ + hh) * S_ + s) * DK_ + d] = (bf16)(acc[i][j][r] + bv2);
        }
      }
    }
  } else {  // ---------------- bucket-logit GEMM
    const int m0 = blockIdx.x * 64, n0 = (blockIdx.y - 24) * 64;
    f32x4 acc[4];
#pragma unroll
    for (int nb = 0; nb < 4; nb++) acc[nb] = zero4();
    const int xrow = t >> 2, xc8 = (t & 3) * 8;

    for (int k0 = 0; k0 < D_; k0 += 32) {
      __syncthreads();
      // x fp32 -> 3-way bf16 split in-register -> LDS
      f32x4 xa = *(const f32x4*)&x[(m0 + xrow) * D_ + k0 + xc8];
      f32x4 xb2 = *(const f32x4*)&x[(m0 + xrow) * D_ + k0 + xc8 + 4];
      bf16x8 vh, vm, vl;
#pragma unroll
      for (int j = 0; j < 4; j++) {
        bf16 hh, mm, ll;
        split3(xa[j], hh, mm, ll);
        vh[j] = hh; vm[j] = mm; vl[j] = ll;
        split3(xb2[j], hh, mm, ll);
        vh[4 + j] = hh; vm[4 + j] = mm; vl[4 + j] = ll;
      }
      *(bf16x8*)&SA[0][xrow * 32 + xc8] = vh;
      *(bf16x8*)&SA[1][xrow * 32 + xc8] = vm;
      *(bf16x8*)&SA[2][xrow * 32 + xc8] = vl;
      // P splits: async, wave w stages quarter w of each array
      load_lds16(&Pth[(n0 + w * 16 + srow) * D_ + k0 + sseg * 8],
                 &SB[0][(w * 16) * 32]);
      load_lds16(&Ptm[(n0 + w * 16 + srow) * D_ + k0 + sseg * 8],
                 &SB[1][(w * 16) * 32]);
      load_lds16(&Ptl[(n0 + w * 16 + srow) * D_ + k0 + sseg * 8],
                 &SB[2][(w * 16) * 32]);
      __syncthreads();
      bf16x8 af[3], bfr[3][4];
#pragma unroll
      for (int i3 = 0; i3 < 3; i3++) {
        af[i3] = *(const bf16x8*)&SA[i3][(w * 16 + lm) * 32 + qd * 8];
#pragma unroll
        for (int nb = 0; nb < 4; nb++)
          bfr[i3][nb] = *(const bf16x8*)&SB[i3][(nb * 16 + lm) * 32 + qd * 8];
      }
#pragma unroll
      for (int nb = 0; nb < 4; nb++) {
        f32x4 a = acc[nb];
        a = mfma_bf16(af[0], bfr[0][nb], a);  // hh
        a = mfma_bf16(af[0], bfr[1][nb], a);  // hm
        a = mfma_bf16(af[1], bfr[0][nb], a);  // mh
        a = mfma_bf16(af[0], bfr[2][nb], a);  // hl
        a = mfma_bf16(af[2], bfr[0][nb], a);  // lh
        a = mfma_bf16(af[1], bfr[1][nb], a);  // mm
        acc[nb] = a;
      }
    }
    // fused argmax over groups of 8 cols (first-max tie-break = np.argmax)
#pragma unroll
    for (int nb = 0; nb < 4; nb++) {
      int n = n0 + nb * 16 + lm;
      float btv = bt[n];
#pragma unroll
      for (int r = 0; r < 4; r++) {
        float v = acc[nb][r] + btv;
        int idx = lm & 7;
#pragma unroll
        for (int mask = 1; mask <= 4; mask <<= 1) {
          float pv = __shfl_xor(v, mask);
          int pi = __shfl_xor(idx, mask);
          if (pv > v || (pv == v && pi < idx)) { v = pv; idx = pi; }
        }
        if ((lm & 7) == 0) {
          int m = m0 + w * 16 + qd * 4 + r;
          int g = n >> 3;
          int sel = g >> 4, head = g & 15;
          int bb = m >> 11, s = m & 2047;
          (sel ? kb : qb)[(bb * H_ + head) * S_ + s] = idx;
        }
      }
    }
  }
}

// ---------------------------------------------------------------- bucket sort
// One block per (b,h). Stable counting sort by bucket; wave-parallel scan.
__global__ __launch_bounds__(256) void k_sort(const int* __restrict__ qb,
                                              const int* __restrict__ kb,
                                              int* __restrict__ qidx,
                                              int* __restrict__ kidx,
                                              int2* __restrict__ meta) {
  __shared__ int cnt[8][257];
  __shared__ int bst[2][9];
  __shared__ int tot[2][8];
  const int bh = blockIdx.x;
  const int t = threadIdx.x;
  const int lane = t & 63, w = t >> 6;
  for (int which = 0; which < 2; which++) {
    const int* src = (which ? kb : qb) + bh * S_;
    int* dst = (which ? kidx : qidx) + bh * QPAD;
    for (int i = t; i < QPAD; i += 256) dst[i] = -1;
    int vals[8];
    int lc[8] = {0, 0, 0, 0, 0, 0, 0, 0};
#pragma unroll
    for (int j = 0; j < 8; j++) { int b = src[t * 8 + j]; vals[j] = b; lc[b]++; }
#pragma unroll
    for (int b = 0; b < 8; b++) cnt[b][t] = lc[b];
    __syncthreads();
    // wave-parallel exclusive scan over 256 thread-slots, 2 buckets/wave
    for (int bb = w; bb < 8; bb += 4) {
      int carry = 0;
      for (int round = 0; round < 4; round++) {
        int v = cnt[bb][round * 64 + lane];
        int inc = v;
#pragma unroll
        for (int off = 1; off < 64; off <<= 1) {
          int u = __shfl_up(inc, off);
          if (lane >= off) inc += u;
        }
        cnt[bb][round * 64 + lane] = carry + inc - v;
        carry += __shfl(inc, 63);
      }
      if (lane == 0) tot[which][bb] = carry;
    }
    __syncthreads();
    if (t == 0) {
      int pos = 0;
      for (int b = 0; b < 8; b++) {
        bst[which][b] = pos;
        pos += (tot[which][b] + 63) & ~63;
      }
      bst[which][8] = pos;
    }
    __syncthreads();
    int run2[8] = {0, 0, 0, 0, 0, 0, 0, 0};
#pragma unroll
    for (int j = 0; j < 8; j++) {
      int b = vals[j];
      int pos = bst[which][b] + cnt[b][t] + run2[b]++;
      dst[pos] = t * 8 + j;
    }
    __syncthreads();
  }
  if (t == 0) {
    for (int tt = 0; tt < NQT; tt++) meta[bh * NQT + tt] = make_int2(0, 0);
    for (int b = 0; b < 8; b++) {
      int t0 = bst[0][b] >> 6;
      int nt = ((tot[0][b] + 63) & ~63) >> 6;
      int ks = bst[1][b];
      int nkt = (tot[1][b] + 63) >> 6;
      for (int tt = t0; tt < t0 + nt; tt++)
        meta[bh * NQT + tt] = make_int2(ks, nkt);
    }
  }
}

// ---------------------------------------------------------------- attention
// Bucket-sorted flash attention. Block = (q-tile slot, h, b).
__global__ __launch_bounds__(256) void k_attn(const bf16* __restrict__ Q,
                                              const bf16* __restrict__ K,
                                              const bf16* __restrict__ V,
                                              const int* __restrict__ qidx,
                                              const int* __restrict__ kidx,
                                              const int2* __restrict__ meta,
                                              bf16* __restrict__ O) {
  constexpr int LDK = 72;  // 144B row stride: 16B-aligned, 2-way (free)
  __shared__ bf16 Kl[64 * LDK];
  __shared__ bf16 Vl[64 * LDK];   // [dim][key]
  __shared__ bf16 Pl[64 * LDK];
  __shared__ int kbl[64];
  __shared__ int qsl[64];
  const int t = threadIdx.x;
  const int qt = blockIdx.x, h = blockIdx.y, b = blockIdx.z;
  const int lane = t & 63, w = t >> 6;
  const int lm = lane & 15, qd = lane >> 4;
  const int bh = b * H_ + h;

  const int2 mt = meta[bh * NQT + qt];
  const int kstart = mt.x, nkt = mt.y;

  if (t < 64) qsl[t] = qidx[bh * QPAD + qt * 64 + t];
  __syncthreads();

  if (nkt == 0) {
#pragma unroll
    for (int r = 0; r < 4; r++) {
      int qs = qsl[w * 16 + qd * 4 + r];
      if (qs >= 0)
#pragma unroll
        for (int nb = 0; nb < 4; nb++)
          O[((b * S_ + qs) * H_ + h) * DK_ + nb * 16 + lm] = (bf16)0.f;
    }
    return;
  }

  int qrow = qsl[w * 16 + lm];
  const bf16* Qp = Q + (bh * S_ + (qrow < 0 ? 0 : qrow)) * DK_;
  bf16x8 qf0 = *(const bf16x8*)(Qp + qd * 8);
  bf16x8 qf1 = *(const bf16x8*)(Qp + 32 + qd * 8);

  f32x4 oacc[4];
  float mrun[4], lrun[4];
#pragma unroll
  for (int nb = 0; nb < 4; nb++) oacc[nb] = zero4();
#pragma unroll
  for (int r = 0; r < 4; r++) { mrun[r] = -1e30f; lrun[r] = 0.f; }

  const bf16* Kbase = K + bh * S_ * DK_;
  const bf16* Vbase = V + bh * S_ * DK_;
  const int* kix = kidx + bh * QPAD + kstart;

  for (int kt = 0; kt < nkt; kt++) {
    const int kt0 = kt * 64;
    __syncthreads();
    if (t < 64) kbl[t] = kix[kt0 + t];
#pragma unroll
    for (int ss = 0; ss < 2; ss++) {
      int seg = t + ss * 256;
      int row = seg >> 3, sg = seg & 7;
      int ki = kix[kt0 + row]; ki = ki < 0 ? 0 : ki;
      *(bf16x8*)&Kl[row * LDK + sg * 8] =
          *(const bf16x8*)&Kbase[ki * DK_ + sg * 8];
    }
#pragma unroll
    for (int ss = 0; ss < 2; ss++) {
      int seg = t + ss * 256;
      int vrow = seg & 63, vsg = seg >> 6;
      int ki = kix[kt0 + vrow]; ki = ki < 0 ? 0 : ki;
      bf16x8 v8 = *(const bf16x8*)&Vbase[ki * DK_ + vsg * 8];
#pragma unroll
      for (int j = 0; j < 8; j++) Vl[(vsg * 8 + j) * LDK + vrow] = v8[j];
    }
    __syncthreads();

    f32x4 sc[4];
#pragma unroll
    for (int nb = 0; nb < 4; nb++) {
      bf16x8 kf0 = *(const bf16x8*)&Kl[(nb * 16 + lm) * LDK + qd * 8];
      bf16x8 kf1 = *(const bf16x8*)&Kl[(nb * 16 + lm) * LDK + 32 + qd * 8];
      f32x4 z = zero4();
      z = mfma_bf16(qf0, kf0, z);
      z = mfma_bf16(qf1, kf1, z);
      sc[nb] = z;
    }
#pragma unroll
    for (int nb = 0; nb < 4; nb++) {
      bool valid = kbl[nb * 16 + lm] >= 0;
#pragma unroll
      for (int r = 0; r < 4; r++)
        sc[nb][r] = valid ? sc[nb][r] * 0.125f : -1e30f;
    }
    float mnew[4], alpha[4], rs[4];
#pragma unroll
    for (int r = 0; r < 4; r++) {
      float tm = fmaxf(fmaxf(sc[0][r], sc[1][r]), fmaxf(sc[2][r], sc[3][r]));
      tm = fmaxf(tm, __shfl_xor(tm, 1));
      tm = fmaxf(tm, __shfl_xor(tm, 2));
      tm = fmaxf(tm, __shfl_xor(tm, 4));
      tm = fmaxf(tm, __shfl_xor(tm, 8));
      mnew[r] = fmaxf(mrun[r], tm);
      alpha[r] = __expf(mrun[r] - mnew[r]);
      mrun[r] = mnew[r];
      rs[r] = 0.f;
    }
#pragma unroll
    for (int nb = 0; nb < 4; nb++)
#pragma unroll
      for (int r = 0; r < 4; r++) {
        float p = (sc[nb][r] > -1e29f) ? __expf(sc[nb][r] - mnew[r]) : 0.f;
        sc[nb][r] = p;
        rs[r] += p;
      }
#pragma unroll
    for (int r = 0; r < 4; r++) {
      float s = rs[r];
      s += __shfl_xor(s, 1);
      s += __shfl_xor(s, 2);
      s += __shfl_xor(s, 4);
      s += __shfl_xor(s, 8);
      lrun[r] = lrun[r] * alpha[r] + s;
    }
#pragma unroll
    for (int nb = 0; nb < 4; nb++)
#pragma unroll
      for (int r = 0; r < 4; r++) oacc[nb][r] *= alpha[r];
#pragma unroll
    for (int nb = 0; nb < 4; nb++)
#pragma unroll
      for (int r = 0; r < 4; r++)
        Pl[(w * 16 + qd * 4 + r) * LDK + nb * 16 + lm] = (bf16)sc[nb][r];
    __syncthreads();
    bf16x8 pa0 = *(const bf16x8*)&Pl[(w * 16 + lm) * LDK + qd * 8];
    bf16x8 pa1 = *(const bf16x8*)&Pl[(w * 16 + lm) * LDK + 32 + qd * 8];
#pragma unroll
    for (int nb = 0; nb < 4; nb++) {
      bf16x8 vf0 = *(const bf16x8*)&Vl[(nb * 16 + lm) * LDK + qd * 8];
      bf16x8 vf1 = *(const bf16x8*)&Vl[(nb * 16 + lm) * LDK + 32 + qd * 8];
      oacc[nb] = mfma_bf16(pa0, vf0, oacc[nb]);
      oacc[nb] = mfma_bf16(pa1, vf1, oacc[nb]);
    }
  }
#pragma unroll
  for (int r = 0; r < 4; r++) {
    int qs = qsl[w * 16 + qd * 4 + r];
    if (qs < 0) continue;
    float l = lrun[r];
    float inv = (l > 0.f) ? 1.f / l : 0.f;
#pragma unroll
    for (int nb = 0; nb < 4; nb++)
      O[((b * S_ + qs) * H_ + h) * DK_ + nb * 16 + lm] = (bf16)(oacc[nb][r] * inv);
  }
}

// ---------------------------------------------------------------- out GEMM
// C[m][n] = sum_k A[m][k]*Bt[n][k] + bias[n] -> fp32; 64x128 tile (512 blocks)
__global__ __launch_bounds__(256) void k_gout(const bf16* __restrict__ A,
                                              const bf16* __restrict__ Bt,
                                              const float* __restrict__ bias,
                                              float* __restrict__ out) {
  __shared__ __align__(16) bf16 Al[64 * 32];
  __shared__ __align__(16) bf16 Bl[128 * 32];
  const int t = threadIdx.x;
  const int lane = t & 63, w = t >> 6;
  const int lm = lane & 15, qd = lane >> 4;
  const int srow = lane >> 2, sseg = lane & 3;
  const int m0 = blockIdx.x * 64, n0 = blockIdx.y * 128;
  const int wm = w >> 1, wn = w & 1;

  f32x4 acc[2][4];
#pragma unroll
  for (int i = 0; i < 2; i++)
#pragma unroll
    for (int j = 0; j < 4; j++) acc[i][j] = zero4();

  for (int k0 = 0; k0 < D_; k0 += 32) {
    __syncthreads();
    load_lds16(&A[(m0 + w * 16 + srow) * D_ + k0 + sseg * 8],
               &Al[(w * 16) * 32]);
    load_lds16(&Bt[(n0 + w * 16 + srow) * D_ + k0 + sseg * 8],
               &Bl[(w * 16) * 32]);
    load_lds16(&Bt[(n0 + 64 + w * 16 + srow) * D_ + k0 + sseg * 8],
               &Bl[(64 + w * 16) * 32]);
    __syncthreads();
    bf16x8 af[2], bfr[4];
#pragma unroll
    for (int i = 0; i < 2; i++)
      af[i] = *(const bf16x8*)&Al[(wm * 32 + i * 16 + lm) * 32 + qd * 8];
#pragma unroll
    for (int j = 0; j < 4; j++)
      bfr[j] = *(const bf16x8*)&Bl[(wn * 64 + j * 16 + lm) * 32 + qd * 8];
#pragma unroll
    for (int i = 0; i < 2; i++)
#pragma unroll
      for (int j = 0; j < 4; j++) acc[i][j] = mfma_bf16(af[i], bfr[j], acc[i][j]);
  }
#pragma unroll
  for (int j = 0; j < 4; j++) {
    int n = n0 + wn * 64 + j * 16 + lm;
    float bv = bias[n];
#pragma unroll
    for (int i = 0; i < 2; i++) {
      int mbase = m0 + wm * 32 + i * 16 + qd * 4;
#pragma unroll
      for (int r = 0; r < 4; r++)
        out[(mbase + r) * D_ + n] = acc[i][j][r] + bv;
    }
  }
}

// ---------------------------------------------------------------- launch
extern "C" void kernel_launch(void* const* d_in, const int* in_sizes, int n_in,
                              void* d_out, int out_size, void* d_ws, size_t ws_size,
                              hipStream_t stream) {
  (void)in_sizes; (void)n_in; (void)out_size; (void)ws_size;
  const float* x  = (const float*)d_in[0];
  const float* Wq = (const float*)d_in[1];
  const float* bq = (const float*)d_in[2];
  const float* Wk = (const float*)d_in[3];
  const float* bk = (const float*)d_in[4];
  const float* Wv = (const float*)d_in[5];
  const float* bv = (const float*)d_in[6];
  const float* Wo = (const float*)d_in[7];
  const float* bo = (const float*)d_in[8];
  const float* R  = (const float*)d_in[9];

  char* ws = (char*)d_ws;
  bf16*  xh   = (bf16*)(ws + 0);          // 8 MB
  bf16*  Qb   = (bf16*)(ws + 8388608);    // 8 MB  [B,H,S,DK]
  bf16*  Kb   = (bf16*)(ws + 16777216);   // 8 MB  [B,H,S,DK]
  bf16*  Vb   = (bf16*)(ws + 25165824);   // 8 MB  [B,H,S,DK]
  bf16*  Ob   = (bf16*)(ws + 33554432);   // 8 MB  [B,S,H,DK]
  bf16*  Wtq  = (bf16*)(ws + 41943040);   // 2 MB each
  bf16*  Wtk  = (bf16*)(ws + 44040192);
  bf16*  Wtv  = (bf16*)(ws + 46137344);
  bf16*  Wto  = (bf16*)(ws + 48234496);
  int*   qbuf = (int*)(ws + 51380224);    // 256 KB each
  int*   kbuf = (int*)(ws + 51642368);
  float* bt   = (float*)(ws + 51904512);  // 1 KB
  bf16*  Pth  = (bf16*)(ws + 51905536);   // 512 KB each
  bf16*  Ptm  = (bf16*)(ws + 52429824);
  bf16*  Ptl  = (bf16*)(ws + 52954112);
  int*   qidxp= (int*)(ws + 53478400);    // 320 KB each
  int*   kidxp= (int*)(ws + 53806080);
  int2*  meta = (int2*)(ws + 54133760);   // 10 KB; end ~54.2 MB

  k_prep<<<dim3(16, 16, 6), dim3(256), 0, stream>>>(
      Wq, Wk, Wv, Wo, x, bq, bk, R, Wtq, Wtk, Wtv, Wto, xh, Pth, Ptm, Ptl, bt);

  k_main<<<dim3(64, 28), dim3(256), 0, stream>>>(
      x, xh, Wtq, Wtk, Wtv, bq, bk, bv, Pth, Ptm, Ptl, bt, Qb, Kb, Vb,
      qbuf, kbuf);

  k_sort<<<dim3(32), dim3(256), 0, stream>>>(qbuf, kbuf, qidxp, kidxp, meta);

  k_attn<<<dim3(NQT, H_, B_), dim3(256), 0, stream>>>(Qb, Kb, Vb, qidxp, kidxp,
                                                      meta, Ob);

  k_gout<<<dim3(64, 8), dim3(256), 0, stream>>>(Ob, Wto, bo, (float*)d_out);
}

// Round 7
// 220.548 us; speedup vs baseline: 2.1117x; 1.0917x over previous
//
#include <hip/hip_runtime.h>
#include <hip/hip_bf16.h>

// LSH Attention, MI355X gfx950.  6-dispatch pipeline:
//  1) k_prep  (z-branch): transW x4, x->bf16 cast, P=W@R^T fold + 3-split,
//     bterm
//  2) k_main  (y-branch): Q/K/V projection GEMM (m97-style 128x128,
//     global_load_lds width-16) + bucket-logit GEMM partials (6-term
//     split-bf16, K-split x4 so the logit work gets 4 blocks/CU instead of
//     1 -- R6's 96us tail was this branch at 1 block/CU latency-bound)
//  3) k_amax: deterministic fixed-order partial reduction + bterm + argmax
//  4) k_sort: per-(b,h) counting sort by bucket (wave-parallel prefix scan)
//  5) k_attn: bucket-sorted flash attention
//  6) k_gout: output GEMM 64x128 tiles -> fp32 d_out
//
// MFMA 16x16x32 bf16 layouts (verified in guide):
//  A: lane holds A[m=lane&15][k=(lane>>4)*8+j]
//  B: lane holds B[k=(lane>>4)*8+j][n=lane&15]
//  C/D: lane holds D[m=(lane>>4)*4+r][n=lane&15]

typedef __bf16 bf16;
typedef __bf16 bf16x8 __attribute__((ext_vector_type(8)));
typedef __bf16 bf16x4 __attribute__((ext_vector_type(4)));
typedef float f32x4 __attribute__((ext_vector_type(4)));

#define DEV static __device__ __forceinline__

DEV f32x4 zero4() { f32x4 z; z[0]=0.f; z[1]=0.f; z[2]=0.f; z[3]=0.f; return z; }

DEV f32x4 mfma_bf16(bf16x8 a, bf16x8 b, f32x4 c) {
  return __builtin_amdgcn_mfma_f32_16x16x32_bf16(a, b, c, 0, 0, 0);
}

// async global->LDS, 16B/lane; LDS dest = wave-uniform base + lane*16
DEV void load_lds16(const bf16* g, bf16* l) {
  __builtin_amdgcn_global_load_lds(
      (const __attribute__((address_space(1))) void*)g,
      (__attribute__((address_space(3))) void*)l, 16, 0, 0);
}

DEV void split3(float f, bf16& h, bf16& m, bf16& l) {
  h = (bf16)f;
  float rm = f - (float)h;
  m = (bf16)rm;
  l = (bf16)(rm - (float)m);
}

#define B_  2
#define S_  2048
#define D_  1024
#define H_  16
#define NH_ 8
#define DK_ 64
#define M_  4096   // B_*S_
#define QPAD 2560  // 2048 + 8*64 (per-bucket 64-alignment padding)
#define NQT  40    // max q-tiles per (b,h): 32 + 8

// ---------------------------------------------------------------- prep
// z<4: transW (64x64 transpose+cast); z=4: x->bf16; z=5 (64 blocks):
// P[d][c]=W(:,h*64:)@R[n]^T fold, 3-split transposed write, + bterm.
__global__ __launch_bounds__(256) void k_prep(
    const float* __restrict__ Wq, const float* __restrict__ Wk,
    const float* __restrict__ Wv, const float* __restrict__ Wo,
    const float* __restrict__ x, const float* __restrict__ bq,
    const float* __restrict__ bk, const float* __restrict__ R,
    bf16* __restrict__ Wtq, bf16* __restrict__ Wtk,
    bf16* __restrict__ Wtv, bf16* __restrict__ Wto,
    bf16* __restrict__ xh, bf16* __restrict__ Pth, bf16* __restrict__ Ptm,
    bf16* __restrict__ Ptl, float* __restrict__ bt) {
  __shared__ float tile[64][65];
  __shared__ float Rl[512];
  const int t = threadIdx.x;
  const int z = blockIdx.z;
  if (z < 4) {
    const float* W = z == 0 ? Wq : z == 1 ? Wk : z == 2 ? Wv : Wo;
    bf16* Wt = z == 0 ? Wtq : z == 1 ? Wtk : z == 2 ? Wtv : Wto;
    int k0 = blockIdx.x * 64, n0 = blockIdx.y * 64;
    int c = t & 63, r4 = t >> 6;
#pragma unroll
    for (int i = 0; i < 16; i++) {
      int r = r4 * 16 + i;
      tile[r][c] = W[(k0 + r) * D_ + n0 + c];
    }
    __syncthreads();
#pragma unroll
    for (int i = 0; i < 16; i++) {
      int r = r4 * 16 + i;
      Wt[(n0 + r) * D_ + k0 + c] = (bf16)tile[c][r];
    }
  } else if (z == 4) {
    int bid = blockIdx.y * 16 + blockIdx.x;
    int base = bid * 16384 + t * 4;
#pragma unroll 4
    for (int it = 0; it < 16; it++) {
      int i = base + it * 1024;
      f32x4 v = *(const f32x4*)(x + i);
      bf16x4 o;
#pragma unroll
      for (int j = 0; j < 4; j++) o[j] = (bf16)v[j];
      *(bf16x4*)(xh + i) = o;
    }
  } else {
    int bid = blockIdx.y * 16 + blockIdx.x;
    if (bid >= 64) return;
    Rl[t] = R[t];
    Rl[t + 256] = R[t + 256];
    __syncthreads();
    const int d0 = bid * 16;
    const int sel = t >> 7, hn = t & 127, h = hn >> 3, n = hn & 7;
    const float* W = sel ? Wk : Wq;
    const float* Rr = &Rl[n * 64];
    bf16x8 vh[2], vm[2], vl[2];
#pragma unroll
    for (int dl = 0; dl < 16; dl++) {
      const float* wr = W + (d0 + dl) * D_ + h * 64;
      float acc = 0.f;
#pragma unroll
      for (int k = 0; k < 64; k += 4) {
        f32x4 wv = *(const f32x4*)(wr + k);
        acc += (wv[0] * Rr[k] + wv[1] * Rr[k + 1]) +
               (wv[2] * Rr[k + 2] + wv[3] * Rr[k + 3]);
      }
      bf16 hh, mm, ll;
      split3(acc, hh, mm, ll);
      vh[dl >> 3][dl & 7] = hh;
      vm[dl >> 3][dl & 7] = mm;
      vl[dl >> 3][dl & 7] = ll;
    }
    *(bf16x8*)&Pth[t * D_ + d0] = vh[0];
    *(bf16x8*)&Pth[t * D_ + d0 + 8] = vh[1];
    *(bf16x8*)&Ptm[t * D_ + d0] = vm[0];
    *(bf16x8*)&Ptm[t * D_ + d0 + 8] = vm[1];
    *(bf16x8*)&Ptl[t * D_ + d0] = vl[0];
    *(bf16x8*)&Ptl[t * D_ + d0 + 8] = vl[1];
    if (bid == 0) {
      const float* bb = sel ? bk : bq;
      float acc = 0.f;
#pragma unroll 8
      for (int k = 0; k < 64; k++) acc += bb[h * 64 + k] * Rr[k];
      bt[t] = acc;
    }
  }
}

// ---------------------------------------------------------------- main fused
// y<24 (x<32): QKV projection GEMM, 128x128 tile, mat=y>>3, n0=(y&7)*128.
// y in 24..39: bucket-logit GEMM partial, chunk=(y-24)>>2, n0=((y-24)&3)*64,
// m0=x*64, K in [chunk*256, chunk*256+256): 6-term split-bf16, fp32 partial
// tile -> Lpart[chunk] (deterministic reduction happens in k_amax).
__global__ __launch_bounds__(256) void k_main(
    const float* __restrict__ x, const bf16* __restrict__ xh,
    const bf16* __restrict__ Wtq, const bf16* __restrict__ Wtk,
    const bf16* __restrict__ Wtv, const float* __restrict__ bq,
    const float* __restrict__ bk, const float* __restrict__ bv,
    const bf16* __restrict__ Pth, const bf16* __restrict__ Ptm,
    const bf16* __restrict__ Ptl,
    bf16* __restrict__ Qb, bf16* __restrict__ Kb, bf16* __restrict__ Vb,
    float* __restrict__ Lpart) {
  __shared__ __align__(16) bf16 SA[3][2048];
  __shared__ __align__(16) bf16 SB[3][2048];
  const int t = threadIdx.x;
  const int lane = t & 63, w = t >> 6;
  const int lm = lane & 15, qd = lane >> 4;
  const int srow = lane >> 2, sseg = lane & 3;  // 16 rows x 4 segs per instr

  if (blockIdx.y < 24) {  // ---------------- QKV GEMM
    if (blockIdx.x >= 32) return;
    bf16* Al = &SA[0][0];  // 128x32 contiguous
    bf16* Bl = &SB[0][0];
    const int m0 = blockIdx.x * 128;
    const int mat = blockIdx.y >> 3;
    const int n0 = (blockIdx.y & 7) * 128;
    const bf16* Bt = mat == 0 ? Wtq : (mat == 1 ? Wtk : Wtv);
    const float* bias = mat == 0 ? bq : (mat == 1 ? bk : bv);
    bf16* out = mat == 0 ? Qb : (mat == 1 ? Kb : Vb);
    const int wm = w >> 1, wn = w & 1;

    f32x4 acc[4][4];
#pragma unroll
    for (int i = 0; i < 4; i++)
#pragma unroll
      for (int j = 0; j < 4; j++) acc[i][j] = zero4();

    for (int k0 = 0; k0 < D_; k0 += 32) {
      __syncthreads();
      load_lds16(&xh[(m0 + w * 16 + srow) * D_ + k0 + sseg * 8],
                 &Al[(w * 16) * 32]);
      load_lds16(&xh[(m0 + 64 + w * 16 + srow) * D_ + k0 + sseg * 8],
                 &Al[(64 + w * 16) * 32]);
      load_lds16(&Bt[(n0 + w * 16 + srow) * D_ + k0 + sseg * 8],
                 &Bl[(w * 16) * 32]);
      load_lds16(&Bt[(n0 + 64 + w * 16 + srow) * D_ + k0 + sseg * 8],
                 &Bl[(64 + w * 16) * 32]);
      __syncthreads();
      bf16x8 af[4], bfr[4];
#pragma unroll
      for (int i = 0; i < 4; i++)
        af[i] = *(const bf16x8*)&Al[(wm * 64 + i * 16 + lm) * 32 + qd * 8];
#pragma unroll
      for (int j = 0; j < 4; j++)
        bfr[j] = *(const bf16x8*)&Bl[(wn * 64 + j * 16 + lm) * 32 + qd * 8];
#pragma unroll
      for (int i = 0; i < 4; i++)
#pragma unroll
        for (int j = 0; j < 4; j++)
          acc[i][j] = mfma_bf16(af[i], bfr[j], acc[i][j]);
    }
#pragma unroll
    for (int j = 0; j < 4; j++) {
      int n = n0 + wn * 64 + j * 16 + lm;
      float bv2 = bias[n];
#pragma unroll
      for (int i = 0; i < 4; i++) {
        int mbase = m0 + wm * 64 + i * 16 + qd * 4;
#pragma unroll
        for (int r = 0; r < 4; r++) {
          int m = mbase + r;
          int bb = m >> 11, s = m & 2047, hh = n >> 6, d = n & 63;
          out[((bb * H_ + hh) * S_ + s) * DK_ + d] = (bf16)(acc[i][j][r] + bv2);
        }
      }
    }
  } else {  // ---------------- bucket-logit GEMM partial (K-split x4)
    const int yy = blockIdx.y - 24;
    const int chunk = yy >> 2;
    const int m0 = blockIdx.x * 64, n0 = (yy & 3) * 64;
    f32x4 acc[4];
#pragma unroll
    for (int nb = 0; nb < 4; nb++) acc[nb] = zero4();
    const int xrow = t >> 2, xc8 = (t & 3) * 8;
    const int kbeg = chunk * 256, kend = kbeg + 256;

    for (int k0 = kbeg; k0 < kend; k0 += 32) {
      __syncthreads();
      // x fp32 -> 3-way bf16 split in-register -> LDS
      f32x4 xa = *(const f32x4*)&x[(m0 + xrow) * D_ + k0 + xc8];
      f32x4 xb2 = *(const f32x4*)&x[(m0 + xrow) * D_ + k0 + xc8 + 4];
      bf16x8 vh, vm, vl;
#pragma unroll
      for (int j = 0; j < 4; j++) {
        bf16 hh, mm, ll;
        split3(xa[j], hh, mm, ll);
        vh[j] = hh; vm[j] = mm; vl[j] = ll;
        split3(xb2[j], hh, mm, ll);
        vh[4 + j] = hh; vm[4 + j] = mm; vl[4 + j] = ll;
      }
      *(bf16x8*)&SA[0][xrow * 32 + xc8] = vh;
      *(bf16x8*)&SA[1][xrow * 32 + xc8] = vm;
      *(bf16x8*)&SA[2][xrow * 32 + xc8] = vl;
      // P splits: async, wave w stages quarter w of each array
      load_lds16(&Pth[(n0 + w * 16 + srow) * D_ + k0 + sseg * 8],
                 &SB[0][(w * 16) * 32]);
      load_lds16(&Ptm[(n0 + w * 16 + srow) * D_ + k0 + sseg * 8],
                 &SB[1][(w * 16) * 32]);
      load_lds16(&Ptl[(n0 + w * 16 + srow) * D_ + k0 + sseg * 8],
                 &SB[2][(w * 16) * 32]);
      __syncthreads();
      bf16x8 af[3], bfr[3][4];
#pragma unroll
      for (int i3 = 0; i3 < 3; i3++) {
        af[i3] = *(const bf16x8*)&SA[i3][(w * 16 + lm) * 32 + qd * 8];
#pragma unroll
        for (int nb = 0; nb < 4; nb++)
          bfr[i3][nb] = *(const bf16x8*)&SB[i3][(nb * 16 + lm) * 32 + qd * 8];
      }
#pragma unroll
      for (int nb = 0; nb < 4; nb++) {
        f32x4 a = acc[nb];
        a = mfma_bf16(af[0], bfr[0][nb], a);  // hh
        a = mfma_bf16(af[0], bfr[1][nb], a);  // hm
        a = mfma_bf16(af[1], bfr[0][nb], a);  // mh
        a = mfma_bf16(af[0], bfr[2][nb], a);  // hl
        a = mfma_bf16(af[2], bfr[0][nb], a);  // lh
        a = mfma_bf16(af[1], bfr[1][nb], a);  // mm
        acc[nb] = a;
      }
    }
    // write fp32 partial tile (coalesced 64B runs per quad-row)
    float* Lp = Lpart + chunk * (M_ * 256);
#pragma unroll
    for (int nb = 0; nb < 4; nb++)
#pragma unroll
      for (int r = 0; r < 4; r++)
        Lp[(m0 + w * 16 + qd * 4 + r) * 256 + n0 + nb * 16 + lm] = acc[nb][r];
  }
}

// ---------------------------------------------------------------- amax
// Sum 4 K-chunk partials in FIXED order (deterministic), + bterm, argmax
// per 8-group -> qb/kb.  Block = 16 rows; thread t: row=t>>4, 16 cols.
__global__ __launch_bounds__(256) void k_amax(const float* __restrict__ Lpart,
                                              const float* __restrict__ bt,
                                              int* __restrict__ qb,
                                              int* __restrict__ kb) {
  const int t = threadIdx.x;
  const int row = blockIdx.x * 16 + (t >> 4);
  const int c0 = (t & 15) * 16;
  const float* L0 = Lpart + row * 256 + c0;
  float v[16];
#pragma unroll
  for (int c4 = 0; c4 < 16; c4 += 4) {
    f32x4 p0 = *(const f32x4*)(L0 + c4);
    f32x4 p1 = *(const f32x4*)(L0 + 1 * M_ * 256 + c4);
    f32x4 p2 = *(const f32x4*)(L0 + 2 * M_ * 256 + c4);
    f32x4 p3 = *(const f32x4*)(L0 + 3 * M_ * 256 + c4);
    f32x4 bv = *(const f32x4*)(bt + c0 + c4);
#pragma unroll
    for (int j = 0; j < 4; j++)
      v[c4 + j] = (((p0[j] + p1[j]) + p2[j]) + p3[j]) + bv[j];
  }
  const int bb = row >> 11, s = row & 2047;
#pragma unroll
  for (int g2 = 0; g2 < 2; g2++) {
    float best = v[g2 * 8];
    int bi = 0;
#pragma unroll
    for (int n = 1; n < 8; n++)
      if (v[g2 * 8 + n] > best) { best = v[g2 * 8 + n]; bi = n; }  // first-max
    int g = (c0 >> 3) + g2;           // 0..31
    int sel = g >> 4, head = g & 15;
    (sel ? kb : qb)[(bb * H_ + head) * S_ + s] = bi;
  }
}

// ---------------------------------------------------------------- bucket sort
// One block per (b,h). Stable counting sort by bucket; wave-parallel scan.
__global__ __launch_bounds__(256) void k_sort(const int* __restrict__ qb,
                                              const int* __restrict__ kb,
                                              int* __restrict__ qidx,
                                              int* __restrict__ kidx,
                                              int2* __restrict__ meta) {
  __shared__ int cnt[8][257];
  __shared__ int bst[2][9];
  __shared__ int tot[2][8];
  const int bh = blockIdx.x;
  const int t = threadIdx.x;
  const int lane = t & 63, w = t >> 6;
  for (int which = 0; which < 2; which++) {
    const int* src = (which ? kb : qb) + bh * S_;
    int* dst = (which ? kidx : qidx) + bh * QPAD;
    for (int i = t; i < QPAD; i += 256) dst[i] = -1;
    int vals[8];
    int lc[8] = {0, 0, 0, 0, 0, 0, 0, 0};
#pragma unroll
    for (int j = 0; j < 8; j++) { int b = src[t * 8 + j]; vals[j] = b; lc[b]++; }
#pragma unroll
    for (int b = 0; b < 8; b++) cnt[b][t] = lc[b];
    __syncthreads();
    // wave-parallel exclusive scan over 256 thread-slots, 2 buckets/wave
    for (int bb = w; bb < 8; bb += 4) {
      int carry = 0;
      for (int round = 0; round < 4; round++) {
        int v = cnt[bb][round * 64 + lane];
        int inc = v;
#pragma unroll
        for (int off = 1; off < 64; off <<= 1) {
          int u = __shfl_up(inc, off);
          if (lane >= off) inc += u;
        }
        cnt[bb][round * 64 + lane] = carry + inc - v;
        carry += __shfl(inc, 63);
      }
      if (lane == 0) tot[which][bb] = carry;
    }
    __syncthreads();
    if (t == 0) {
      int pos = 0;
      for (int b = 0; b < 8; b++) {
        bst[which][b] = pos;
        pos += (tot[which][b] + 63) & ~63;
      }
      bst[which][8] = pos;
    }
    __syncthreads();
    int run2[8] = {0, 0, 0, 0, 0, 0, 0, 0};
#pragma unroll
    for (int j = 0; j < 8; j++) {
      int b = vals[j];
      int pos = bst[which][b] + cnt[b][t] + run2[b]++;
      dst[pos] = t * 8 + j;
    }
    __syncthreads();
  }
  if (t == 0) {
    for (int tt = 0; tt < NQT; tt++) meta[bh * NQT + tt] = make_int2(0, 0);
    for (int b = 0; b < 8; b++) {
      int t0 = bst[0][b] >> 6;
      int nt = ((tot[0][b] + 63) & ~63) >> 6;
      int ks = bst[1][b];
      int nkt = (tot[1][b] + 63) >> 6;
      for (int tt = t0; tt < t0 + nt; tt++)
        meta[bh * NQT + tt] = make_int2(ks, nkt);
    }
  }
}

// ---------------------------------------------------------------- attention
// Bucket-sorted flash attention. Block = (q-tile slot, h, b).
__global__ __launch_bounds__(256) void k_attn(const bf16* __restrict__ Q,
                                              const bf16* __restrict__ K,
                                              const bf16* __restrict__ V,
                                              const int* __restrict__ qidx,
                                              const int* __restrict__ kidx,
                                              const int2* __restrict__ meta,
                                              bf16* __restrict__ O) {
  constexpr int LDK = 72;  // 144B row stride: 16B-aligned, 2-way (free)
  __shared__ bf16 Kl[64 * LDK];
  __shared__ bf16 Vl[64 * LDK];   // [dim][key]
  __shared__ bf16 Pl[64 * LDK];
  __shared__ int kbl[64];
  __shared__ int qsl[64];
  const int t = threadIdx.x;
  const int qt = blockIdx.x, h = blockIdx.y, b = blockIdx.z;
  const int lane = t & 63, w = t >> 6;
  const int lm = lane & 15, qd = lane >> 4;
  const int bh = b * H_ + h;

  const int2 mt = meta[bh * NQT + qt];
  const int kstart = mt.x, nkt = mt.y;

  if (t < 64) qsl[t] = qidx[bh * QPAD + qt * 64 + t];
  __syncthreads();

  if (nkt == 0) {
#pragma unroll
    for (int r = 0; r < 4; r++) {
      int qs = qsl[w * 16 + qd * 4 + r];
      if (qs >= 0)
#pragma unroll
        for (int nb = 0; nb < 4; nb++)
          O[((b * S_ + qs) * H_ + h) * DK_ + nb * 16 + lm] = (bf16)0.f;
    }
    return;
  }

  int qrow = qsl[w * 16 + lm];
  const bf16* Qp = Q + (bh * S_ + (qrow < 0 ? 0 : qrow)) * DK_;
  bf16x8 qf0 = *(const bf16x8*)(Qp + qd * 8);
  bf16x8 qf1 = *(const bf16x8*)(Qp + 32 + qd * 8);

  f32x4 oacc[4];
  float mrun[4], lrun[4];
#pragma unroll
  for (int nb = 0; nb < 4; nb++) oacc[nb] = zero4();
#pragma unroll
  for (int r = 0; r < 4; r++) { mrun[r] = -1e30f; lrun[r] = 0.f; }

  const bf16* Kbase = K + bh * S_ * DK_;
  const bf16* Vbase = V + bh * S_ * DK_;
  const int* kix = kidx + bh * QPAD + kstart;

  for (int kt = 0; kt < nkt; kt++) {
    const int kt0 = kt * 64;
    __syncthreads();
    if (t < 64) kbl[t] = kix[kt0 + t];
#pragma unroll
    for (int ss = 0; ss < 2; ss++) {
      int seg = t + ss * 256;
      int row = seg >> 3, sg = seg & 7;
      int ki = kix[kt0 + row]; ki = ki < 0 ? 0 : ki;
      *(bf16x8*)&Kl[row * LDK + sg * 8] =
          *(const bf16x8*)&Kbase[ki * DK_ + sg * 8];
    }
#pragma unroll
    for (int ss = 0; ss < 2; ss++) {
      int seg = t + ss * 256;
      int vrow = seg & 63, vsg = seg >> 6;
      int ki = kix[kt0 + vrow]; ki = ki < 0 ? 0 : ki;
      bf16x8 v8 = *(const bf16x8*)&Vbase[ki * DK_ + vsg * 8];
#pragma unroll
      for (int j = 0; j < 8; j++) Vl[(vsg * 8 + j) * LDK + vrow] = v8[j];
    }
    __syncthreads();

    f32x4 sc[4];
#pragma unroll
    for (int nb = 0; nb < 4; nb++) {
      bf16x8 kf0 = *(const bf16x8*)&Kl[(nb * 16 + lm) * LDK + qd * 8];
      bf16x8 kf1 = *(const bf16x8*)&Kl[(nb * 16 + lm) * LDK + 32 + qd * 8];
      f32x4 z = zero4();
      z = mfma_bf16(qf0, kf0, z);
      z = mfma_bf16(qf1, kf1, z);
      sc[nb] = z;
    }
#pragma unroll
    for (int nb = 0; nb < 4; nb++) {
      bool valid = kbl[nb * 16 + lm] >= 0;
#pragma unroll
      for (int r = 0; r < 4; r++)
        sc[nb][r] = valid ? sc[nb][r] * 0.125f : -1e30f;
    }
    float mnew[4], alpha[4], rs[4];
#pragma unroll
    for (int r = 0; r < 4; r++) {
      float tm = fmaxf(fmaxf(sc[0][r], sc[1][r]), fmaxf(sc[2][r], sc[3][r]));
      tm = fmaxf(tm, __shfl_xor(tm, 1));
      tm = fmaxf(tm, __shfl_xor(tm, 2));
      tm = fmaxf(tm, __shfl_xor(tm, 4));
      tm = fmaxf(tm, __shfl_xor(tm, 8));
      mnew[r] = fmaxf(mrun[r], tm);
      alpha[r] = __expf(mrun[r] - mnew[r]);
      mrun[r] = mnew[r];
      rs[r] = 0.f;
    }
#pragma unroll
    for (int nb = 0; nb < 4; nb++)
#pragma unroll
      for (int r = 0; r < 4; r++) {
        float p = (sc[nb][r] > -1e29f) ? __expf(sc[nb][r] - mnew[r]) : 0.f;
        sc[nb][r] = p;
        rs[r] += p;
      }
#pragma unroll
    for (int r = 0; r < 4; r++) {
      float s = rs[r];
      s += __shfl_xor(s, 1);
      s += __shfl_xor(s, 2);
      s += __shfl_xor(s, 4);
      s += __shfl_xor(s, 8);
      lrun[r] = lrun[r] * alpha[r] + s;
    }
#pragma unroll
    for (int nb = 0; nb < 4; nb++)
#pragma unroll
      for (int r = 0; r < 4; r++) oacc[nb][r] *= alpha[r];
#pragma unroll
    for (int nb = 0; nb < 4; nb++)
#pragma unroll
      for (int r = 0; r < 4; r++)
        Pl[(w * 16 + qd * 4 + r) * LDK + nb * 16 + lm] = (bf16)sc[nb][r];
    __syncthreads();
    bf16x8 pa0 = *(const bf16x8*)&Pl[(w * 16 + lm) * LDK + qd * 8];
    bf16x8 pa1 = *(const bf16x8*)&Pl[(w * 16 + lm) * LDK + 32 + qd * 8];
#pragma unroll
    for (int nb = 0; nb < 4; nb++) {
      bf16x8 vf0 = *(const bf16x8*)&Vl[(nb * 16 + lm) * LDK + qd * 8];
      bf16x8 vf1 = *(const bf16x8*)&Vl[(nb * 16 + lm) * LDK + 32 + qd * 8];
      oacc[nb] = mfma_bf16(pa0, vf0, oacc[nb]);
      oacc[nb] = mfma_bf16(pa1, vf1, oacc[nb]);
    }
  }
#pragma unroll
  for (int r = 0; r < 4; r++) {
    int qs = qsl[w * 16 + qd * 4 + r];
    if (qs < 0) continue;
    float l = lrun[r];
    float inv = (l > 0.f) ? 1.f / l : 0.f;
#pragma unroll
    for (int nb = 0; nb < 4; nb++)
      O[((b * S_ + qs) * H_ + h) * DK_ + nb * 16 + lm] = (bf16)(oacc[nb][r] * inv);
  }
}

// ---------------------------------------------------------------- out GEMM
// C[m][n] = sum_k A[m][k]*Bt[n][k] + bias[n] -> fp32; 64x128 tile (512 blocks)
__global__ __launch_bounds__(256) void k_gout(const bf16* __restrict__ A,
                                              const bf16* __restrict__ Bt,
                                              const float* __restrict__ bias,
                                              float* __restrict__ out) {
  __shared__ __align__(16) bf16 Al[64 * 32];
  __shared__ __align__(16) bf16 Bl[128 * 32];
  const int t = threadIdx.x;
  const int lane = t & 63, w = t >> 6;
  const int lm = lane & 15, qd = lane >> 4;
  const int srow = lane >> 2, sseg = lane & 3;
  const int m0 = blockIdx.x * 64, n0 = blockIdx.y * 128;
  const int wm = w >> 1, wn = w & 1;

  f32x4 acc[2][4];
#pragma unroll
  for (int i = 0; i < 2; i++)
#pragma unroll
    for (int j = 0; j < 4; j++) acc[i][j] = zero4();

  for (int k0 = 0; k0 < D_; k0 += 32) {
    __syncthreads();
    load_lds16(&A[(m0 + w * 16 + srow) * D_ + k0 + sseg * 8],
               &Al[(w * 16) * 32]);
    load_lds16(&Bt[(n0 + w * 16 + srow) * D_ + k0 + sseg * 8],
               &Bl[(w * 16) * 32]);
    load_lds16(&Bt[(n0 + 64 + w * 16 + srow) * D_ + k0 + sseg * 8],
               &Bl[(64 + w * 16) * 32]);
    __syncthreads();
    bf16x8 af[2], bfr[4];
#pragma unroll
    for (int i = 0; i < 2; i++)
      af[i] = *(const bf16x8*)&Al[(wm * 32 + i * 16 + lm) * 32 + qd * 8];
#pragma unroll
    for (int j = 0; j < 4; j++)
      bfr[j] = *(const bf16x8*)&Bl[(wn * 64 + j * 16 + lm) * 32 + qd * 8];
#pragma unroll
    for (int i = 0; i < 2; i++)
#pragma unroll
      for (int j = 0; j < 4; j++) acc[i][j] = mfma_bf16(af[i], bfr[j], acc[i][j]);
  }
#pragma unroll
  for (int j = 0; j < 4; j++) {
    int n = n0 + wn * 64 + j * 16 + lm;
    float bv = bias[n];
#pragma unroll
    for (int i = 0; i < 2; i++) {
      int mbase = m0 + wm * 32 + i * 16 + qd * 4;
#pragma unroll
      for (int r = 0; r < 4; r++)
        out[(mbase + r) * D_ + n] = acc[i][j][r] + bv;
    }
  }
}

// ---------------------------------------------------------------- launch
extern "C" void kernel_launch(void* const* d_in, const int* in_sizes, int n_in,
                              void* d_out, int out_size, void* d_ws, size_t ws_size,
                              hipStream_t stream) {
  (void)in_sizes; (void)n_in; (void)out_size; (void)ws_size;
  const float* x  = (const float*)d_in[0];
  const float* Wq = (const float*)d_in[1];
  const float* bq = (const float*)d_in[2];
  const float* Wk = (const float*)d_in[3];
  const float* bk = (const float*)d_in[4];
  const float* Wv = (const float*)d_in[5];
  const float* bv = (const float*)d_in[6];
  const float* Wo = (const float*)d_in[7];
  const float* bo = (const float*)d_in[8];
  const float* R  = (const float*)d_in[9];

  char* ws = (char*)d_ws;
  bf16*  xh   = (bf16*)(ws + 0);          // 8 MB
  bf16*  Qb   = (bf16*)(ws + 8388608);    // 8 MB  [B,H,S,DK]
  bf16*  Kb   = (bf16*)(ws + 16777216);   // 8 MB  [B,H,S,DK]
  bf16*  Vb   = (bf16*)(ws + 25165824);   // 8 MB  [B,H,S,DK]
  bf16*  Ob   = (bf16*)(ws + 33554432);   // 8 MB  [B,S,H,DK]
  bf16*  Wtq  = (bf16*)(ws + 41943040);   // 2 MB each
  bf16*  Wtk  = (bf16*)(ws + 44040192);
  bf16*  Wtv  = (bf16*)(ws + 46137344);
  bf16*  Wto  = (bf16*)(ws + 48234496);
  int*   qbuf = (int*)(ws + 51380224);    // 256 KB each
  int*   kbuf = (int*)(ws + 51642368);
  float* bt   = (float*)(ws + 51904512);  // 1 KB
  bf16*  Pth  = (bf16*)(ws + 51905536);   // 512 KB each
  bf16*  Ptm  = (bf16*)(ws + 52429824);
  bf16*  Ptl  = (bf16*)(ws + 52954112);
  int*   qidxp= (int*)(ws + 53478400);    // 320 KB each
  int*   kidxp= (int*)(ws + 53806080);
  int2*  meta = (int2*)(ws + 54133760);   // 10 KB
  float* Lpart= (float*)(ws + 67108864);  // 4 x 4 MB fp32 partials; end 80 MB
                                          // (ws >= 256 MB per harness fills)

  k_prep<<<dim3(16, 16, 6), dim3(256), 0, stream>>>(
      Wq, Wk, Wv, Wo, x, bq, bk, R, Wtq, Wtk, Wtv, Wto, xh, Pth, Ptm, Ptl, bt);

  k_main<<<dim3(64, 40), dim3(256), 0, stream>>>(
      x, xh, Wtq, Wtk, Wtv, bq, bk, bv, Pth, Ptm, Ptl, Qb, Kb, Vb, Lpart);

  k_amax<<<dim3(256), dim3(256), 0, stream>>>(Lpart, bt, qbuf, kbuf);

  k_sort<<<dim3(32), dim3(256), 0, stream>>>(qbuf, kbuf, qidxp, kidxp, meta);

  k_attn<<<dim3(NQT, H_, B_), dim3(256), 0, stream>>>(Qb, Kb, Vb, qidxp, kidxp,
                                                      meta, Ob);

  k_gout<<<dim3(64, 8), dim3(256), 0, stream>>>(Ob, Wto, bo, (float*)d_out);
}

// Round 8
// 220.519 us; speedup vs baseline: 2.1120x; 1.0001x over previous
//
#include <hip/hip_runtime.h>
#include <hip/hip_bf16.h>

// LSH Attention, MI355X gfx950.  6-dispatch pipeline:
//  1) k_prep  (z-branch): transW x4, x->bf16 3-split cast (xh/xm/xl),
//     P=W@R^T fold + 3-split, bterm
//  2) k_main  (y-branch): Q/K/V projection GEMM (m97-style 128x128,
//     global_load_lds width-16) + bucket-logit GEMM partials (6-term
//     split-bf16, K-split x4, ALL operands async-staged -- R7's 55us had
//     sync fp32 x loads + split3 VALU on the critical path)
//  3) k_amax: deterministic fixed-order partial reduction + bterm + argmax
//  4) k_sort: per-(b,h) counting sort by bucket (wave-parallel prefix scan)
//  5) k_attn: bucket-sorted flash attention
//  6) k_gout: output GEMM 64x128 tiles -> fp32 d_out
//
// MFMA 16x16x32 bf16 layouts (verified in guide):
//  A: lane holds A[m=lane&15][k=(lane>>4)*8+j]
//  B: lane holds B[k=(lane>>4)*8+j][n=lane&15]
//  C/D: lane holds D[m=(lane>>4)*4+r][n=lane&15]

typedef __bf16 bf16;
typedef __bf16 bf16x8 __attribute__((ext_vector_type(8)));
typedef __bf16 bf16x4 __attribute__((ext_vector_type(4)));
typedef float f32x4 __attribute__((ext_vector_type(4)));

#define DEV static __device__ __forceinline__

DEV f32x4 zero4() { f32x4 z; z[0]=0.f; z[1]=0.f; z[2]=0.f; z[3]=0.f; return z; }

DEV f32x4 mfma_bf16(bf16x8 a, bf16x8 b, f32x4 c) {
  return __builtin_amdgcn_mfma_f32_16x16x32_bf16(a, b, c, 0, 0, 0);
}

// async global->LDS, 16B/lane; LDS dest = wave-uniform base + lane*16
DEV void load_lds16(const bf16* g, bf16* l) {
  __builtin_amdgcn_global_load_lds(
      (const __attribute__((address_space(1))) void*)g,
      (__attribute__((address_space(3))) void*)l, 16, 0, 0);
}

DEV void split3(float f, bf16& h, bf16& m, bf16& l) {
  h = (bf16)f;
  float rm = f - (float)h;
  m = (bf16)rm;
  l = (bf16)(rm - (float)m);
}

#define B_  2
#define S_  2048
#define D_  1024
#define H_  16
#define NH_ 8
#define DK_ 64
#define M_  4096   // B_*S_
#define QPAD 2560  // 2048 + 8*64 (per-bucket 64-alignment padding)
#define NQT  40    // max q-tiles per (b,h): 32 + 8

// ---------------------------------------------------------------- prep
// z<4: transW (64x64 transpose+cast); z=4: x->bf16 3-split; z=5 (64 blocks):
// P[d][c]=W(:,h*64:)@R[n]^T fold, 3-split transposed write, + bterm.
__global__ __launch_bounds__(256) void k_prep(
    const float* __restrict__ Wq, const float* __restrict__ Wk,
    const float* __restrict__ Wv, const float* __restrict__ Wo,
    const float* __restrict__ x, const float* __restrict__ bq,
    const float* __restrict__ bk, const float* __restrict__ R,
    bf16* __restrict__ Wtq, bf16* __restrict__ Wtk,
    bf16* __restrict__ Wtv, bf16* __restrict__ Wto,
    bf16* __restrict__ xh, bf16* __restrict__ xm, bf16* __restrict__ xl,
    bf16* __restrict__ Pth, bf16* __restrict__ Ptm,
    bf16* __restrict__ Ptl, float* __restrict__ bt) {
  __shared__ float tile[64][65];
  __shared__ float Rl[512];
  const int t = threadIdx.x;
  const int z = blockIdx.z;
  if (z < 4) {
    const float* W = z == 0 ? Wq : z == 1 ? Wk : z == 2 ? Wv : Wo;
    bf16* Wt = z == 0 ? Wtq : z == 1 ? Wtk : z == 2 ? Wtv : Wto;
    int k0 = blockIdx.x * 64, n0 = blockIdx.y * 64;
    int c = t & 63, r4 = t >> 6;
#pragma unroll
    for (int i = 0; i < 16; i++) {
      int r = r4 * 16 + i;
      tile[r][c] = W[(k0 + r) * D_ + n0 + c];
    }
    __syncthreads();
#pragma unroll
    for (int i = 0; i < 16; i++) {
      int r = r4 * 16 + i;
      Wt[(n0 + r) * D_ + k0 + c] = (bf16)tile[c][r];
    }
  } else if (z == 4) {
    int bid = blockIdx.y * 16 + blockIdx.x;
    int base = bid * 16384 + t * 4;
#pragma unroll 4
    for (int it = 0; it < 16; it++) {
      int i = base + it * 1024;
      f32x4 v = *(const f32x4*)(x + i);
      bf16x4 oh, om, ol;
#pragma unroll
      for (int j = 0; j < 4; j++) {
        bf16 hh, mm, ll;
        split3(v[j], hh, mm, ll);
        oh[j] = hh; om[j] = mm; ol[j] = ll;
      }
      *(bf16x4*)(xh + i) = oh;
      *(bf16x4*)(xm + i) = om;
      *(bf16x4*)(xl + i) = ol;
    }
  } else {
    int bid = blockIdx.y * 16 + blockIdx.x;
    if (bid >= 64) return;
    Rl[t] = R[t];
    Rl[t + 256] = R[t + 256];
    __syncthreads();
    const int d0 = bid * 16;
    const int sel = t >> 7, hn = t & 127, h = hn >> 3, n = hn & 7;
    const float* W = sel ? Wk : Wq;
    const float* Rr = &Rl[n * 64];
    bf16x8 vh[2], vm[2], vl[2];
#pragma unroll
    for (int dl = 0; dl < 16; dl++) {
      const float* wr = W + (d0 + dl) * D_ + h * 64;
      float acc = 0.f;
#pragma unroll
      for (int k = 0; k < 64; k += 4) {
        f32x4 wv = *(const f32x4*)(wr + k);
        acc += (wv[0] * Rr[k] + wv[1] * Rr[k + 1]) +
               (wv[2] * Rr[k + 2] + wv[3] * Rr[k + 3]);
      }
      bf16 hh, mm, ll;
      split3(acc, hh, mm, ll);
      vh[dl >> 3][dl & 7] = hh;
      vm[dl >> 3][dl & 7] = mm;
      vl[dl >> 3][dl & 7] = ll;
    }
    *(bf16x8*)&Pth[t * D_ + d0] = vh[0];
    *(bf16x8*)&Pth[t * D_ + d0 + 8] = vh[1];
    *(bf16x8*)&Ptm[t * D_ + d0] = vm[0];
    *(bf16x8*)&Ptm[t * D_ + d0 + 8] = vm[1];
    *(bf16x8*)&Ptl[t * D_ + d0] = vl[0];
    *(bf16x8*)&Ptl[t * D_ + d0 + 8] = vl[1];
    if (bid == 0) {
      const float* bb = sel ? bk : bq;
      float acc = 0.f;
#pragma unroll 8
      for (int k = 0; k < 64; k++) acc += bb[h * 64 + k] * Rr[k];
      bt[t] = acc;
    }
  }
}

// ---------------------------------------------------------------- main fused
// y<24 (x<32): QKV projection GEMM, 128x128 tile, mat=y>>3, n0=(y&7)*128.
// y in 24..39: bucket-logit GEMM partial, chunk=(y-24)>>2, n0=((y-24)&3)*64,
// m0=x*64, K in [chunk*256, chunk*256+256): 6-term split-bf16, all 6
// operand tiles async-staged, fp32 partial tile -> Lpart[chunk].
__global__ __launch_bounds__(256) void k_main(
    const bf16* __restrict__ xh, const bf16* __restrict__ xm,
    const bf16* __restrict__ xl,
    const bf16* __restrict__ Wtq, const bf16* __restrict__ Wtk,
    const bf16* __restrict__ Wtv, const float* __restrict__ bq,
    const float* __restrict__ bk, const float* __restrict__ bv,
    const bf16* __restrict__ Pth, const bf16* __restrict__ Ptm,
    const bf16* __restrict__ Ptl,
    bf16* __restrict__ Qb, bf16* __restrict__ Kb, bf16* __restrict__ Vb,
    float* __restrict__ Lpart) {
  __shared__ __align__(16) bf16 SA[3][2048];
  __shared__ __align__(16) bf16 SB[3][2048];
  const int t = threadIdx.x;
  const int lane = t & 63, w = t >> 6;
  const int lm = lane & 15, qd = lane >> 4;
  const int srow = lane >> 2, sseg = lane & 3;  // 16 rows x 4 segs per instr

  if (blockIdx.y < 24) {  // ---------------- QKV GEMM
    if (blockIdx.x >= 32) return;
    bf16* Al = &SA[0][0];  // 128x32 contiguous
    bf16* Bl = &SB[0][0];
    const int m0 = blockIdx.x * 128;
    const int mat = blockIdx.y >> 3;
    const int n0 = (blockIdx.y & 7) * 128;
    const bf16* Bt = mat == 0 ? Wtq : (mat == 1 ? Wtk : Wtv);
    const float* bias = mat == 0 ? bq : (mat == 1 ? bk : bv);
    bf16* out = mat == 0 ? Qb : (mat == 1 ? Kb : Vb);
    const int wm = w >> 1, wn = w & 1;

    f32x4 acc[4][4];
#pragma unroll
    for (int i = 0; i < 4; i++)
#pragma unroll
      for (int j = 0; j < 4; j++) acc[i][j] = zero4();

    for (int k0 = 0; k0 < D_; k0 += 32) {
      __syncthreads();
      load_lds16(&xh[(m0 + w * 16 + srow) * D_ + k0 + sseg * 8],
                 &Al[(w * 16) * 32]);
      load_lds16(&xh[(m0 + 64 + w * 16 + srow) * D_ + k0 + sseg * 8],
                 &Al[(64 + w * 16) * 32]);
      load_lds16(&Bt[(n0 + w * 16 + srow) * D_ + k0 + sseg * 8],
                 &Bl[(w * 16) * 32]);
      load_lds16(&Bt[(n0 + 64 + w * 16 + srow) * D_ + k0 + sseg * 8],
                 &Bl[(64 + w * 16) * 32]);
      __syncthreads();
      bf16x8 af[4], bfr[4];
#pragma unroll
      for (int i = 0; i < 4; i++)
        af[i] = *(const bf16x8*)&Al[(wm * 64 + i * 16 + lm) * 32 + qd * 8];
#pragma unroll
      for (int j = 0; j < 4; j++)
        bfr[j] = *(const bf16x8*)&Bl[(wn * 64 + j * 16 + lm) * 32 + qd * 8];
#pragma unroll
      for (int i = 0; i < 4; i++)
#pragma unroll
        for (int j = 0; j < 4; j++)
          acc[i][j] = mfma_bf16(af[i], bfr[j], acc[i][j]);
    }
#pragma unroll
    for (int j = 0; j < 4; j++) {
      int n = n0 + wn * 64 + j * 16 + lm;
      float bv2 = bias[n];
#pragma unroll
      for (int i = 0; i < 4; i++) {
        int mbase = m0 + wm * 64 + i * 16 + qd * 4;
#pragma unroll
        for (int r = 0; r < 4; r++) {
          int m = mbase + r;
          int bb = m >> 11, s = m & 2047, hh = n >> 6, d = n & 63;
          out[((bb * H_ + hh) * S_ + s) * DK_ + d] = (bf16)(acc[i][j][r] + bv2);
        }
      }
    }
  } else {  // ---------------- bucket-logit GEMM partial (K-split x4)
    const int yy = blockIdx.y - 24;
    const int chunk = yy >> 2;
    const int m0 = blockIdx.x * 64, n0 = (yy & 3) * 64;
    f32x4 acc[4];
#pragma unroll
    for (int nb = 0; nb < 4; nb++) acc[nb] = zero4();
    const int kbeg = chunk * 256, kend = kbeg + 256;
    const bf16* Axyz[3] = {xh, xm, xl};
    const bf16* Bxyz[3] = {Pth, Ptm, Ptl};

    for (int k0 = kbeg; k0 < kend; k0 += 32) {
      __syncthreads();
      // all 6 operand tiles async: wave w stages quarter w of each array
#pragma unroll
      for (int i3 = 0; i3 < 3; i3++) {
        load_lds16(&Axyz[i3][(m0 + w * 16 + srow) * D_ + k0 + sseg * 8],
                   &SA[i3][(w * 16) * 32]);
        load_lds16(&Bxyz[i3][(n0 + w * 16 + srow) * D_ + k0 + sseg * 8],
                   &SB[i3][(w * 16) * 32]);
      }
      __syncthreads();
      bf16x8 af[3], bfr[3][4];
#pragma unroll
      for (int i3 = 0; i3 < 3; i3++) {
        af[i3] = *(const bf16x8*)&SA[i3][(w * 16 + lm) * 32 + qd * 8];
#pragma unroll
        for (int nb = 0; nb < 4; nb++)
          bfr[i3][nb] = *(const bf16x8*)&SB[i3][(nb * 16 + lm) * 32 + qd * 8];
      }
#pragma unroll
      for (int nb = 0; nb < 4; nb++) {
        f32x4 a = acc[nb];
        a = mfma_bf16(af[0], bfr[0][nb], a);  // hh
        a = mfma_bf16(af[0], bfr[1][nb], a);  // hm
        a = mfma_bf16(af[1], bfr[0][nb], a);  // mh
        a = mfma_bf16(af[0], bfr[2][nb], a);  // hl
        a = mfma_bf16(af[2], bfr[0][nb], a);  // lh
        a = mfma_bf16(af[1], bfr[1][nb], a);  // mm
        acc[nb] = a;
      }
    }
    // write fp32 partial tile (coalesced 64B runs per quad-row)
    float* Lp = Lpart + chunk * (M_ * 256);
#pragma unroll
    for (int nb = 0; nb < 4; nb++)
#pragma unroll
      for (int r = 0; r < 4; r++)
        Lp[(m0 + w * 16 + qd * 4 + r) * 256 + n0 + nb * 16 + lm] = acc[nb][r];
  }
}

// ---------------------------------------------------------------- amax
// Sum 4 K-chunk partials in FIXED order (deterministic), + bterm, argmax
// per 8-group -> qb/kb.  Block = 16 rows; thread t: row=t>>4, 16 cols.
__global__ __launch_bounds__(256) void k_amax(const float* __restrict__ Lpart,
                                              const float* __restrict__ bt,
                                              int* __restrict__ qb,
                                              int* __restrict__ kb) {
  const int t = threadIdx.x;
  const int row = blockIdx.x * 16 + (t >> 4);
  const int c0 = (t & 15) * 16;
  const float* L0 = Lpart + row * 256 + c0;
  float v[16];
#pragma unroll
  for (int c4 = 0; c4 < 16; c4 += 4) {
    f32x4 p0 = *(const f32x4*)(L0 + c4);
    f32x4 p1 = *(const f32x4*)(L0 + 1 * M_ * 256 + c4);
    f32x4 p2 = *(const f32x4*)(L0 + 2 * M_ * 256 + c4);
    f32x4 p3 = *(const f32x4*)(L0 + 3 * M_ * 256 + c4);
    f32x4 bv = *(const f32x4*)(bt + c0 + c4);
#pragma unroll
    for (int j = 0; j < 4; j++)
      v[c4 + j] = (((p0[j] + p1[j]) + p2[j]) + p3[j]) + bv[j];
  }
  const int bb = row >> 11, s = row & 2047;
#pragma unroll
  for (int g2 = 0; g2 < 2; g2++) {
    float best = v[g2 * 8];
    int bi = 0;
#pragma unroll
    for (int n = 1; n < 8; n++)
      if (v[g2 * 8 + n] > best) { best = v[g2 * 8 + n]; bi = n; }  // first-max
    int g = (c0 >> 3) + g2;           // 0..31
    int sel = g >> 4, head = g & 15;
    (sel ? kb : qb)[(bb * H_ + head) * S_ + s] = bi;
  }
}

// ---------------------------------------------------------------- bucket sort
// One block per (b,h). Stable counting sort by bucket; wave-parallel scan.
__global__ __launch_bounds__(256) void k_sort(const int* __restrict__ qb,
                                              const int* __restrict__ kb,
                                              int* __restrict__ qidx,
                                              int* __restrict__ kidx,
                                              int2* __restrict__ meta) {
  __shared__ int cnt[8][257];
  __shared__ int bst[2][9];
  __shared__ int tot[2][8];
  const int bh = blockIdx.x;
  const int t = threadIdx.x;
  const int lane = t & 63, w = t >> 6;
  for (int which = 0; which < 2; which++) {
    const int* src = (which ? kb : qb) + bh * S_;
    int* dst = (which ? kidx : qidx) + bh * QPAD;
    for (int i = t; i < QPAD; i += 256) dst[i] = -1;
    int vals[8];
    int lc[8] = {0, 0, 0, 0, 0, 0, 0, 0};
#pragma unroll
    for (int j = 0; j < 8; j++) { int b = src[t * 8 + j]; vals[j] = b; lc[b]++; }
#pragma unroll
    for (int b = 0; b < 8; b++) cnt[b][t] = lc[b];
    __syncthreads();
    // wave-parallel exclusive scan over 256 thread-slots, 2 buckets/wave
    for (int bb = w; bb < 8; bb += 4) {
      int carry = 0;
      for (int round = 0; round < 4; round++) {
        int v = cnt[bb][round * 64 + lane];
        int inc = v;
#pragma unroll
        for (int off = 1; off < 64; off <<= 1) {
          int u = __shfl_up(inc, off);
          if (lane >= off) inc += u;
        }
        cnt[bb][round * 64 + lane] = carry + inc - v;
        carry += __shfl(inc, 63);
      }
      if (lane == 0) tot[which][bb] = carry;
    }
    __syncthreads();
    if (t == 0) {
      int pos = 0;
      for (int b = 0; b < 8; b++) {
        bst[which][b] = pos;
        pos += (tot[which][b] + 63) & ~63;
      }
      bst[which][8] = pos;
    }
    __syncthreads();
    int run2[8] = {0, 0, 0, 0, 0, 0, 0, 0};
#pragma unroll
    for (int j = 0; j < 8; j++) {
      int b = vals[j];
      int pos = bst[which][b] + cnt[b][t] + run2[b]++;
      dst[pos] = t * 8 + j;
    }
    __syncthreads();
  }
  if (t == 0) {
    for (int tt = 0; tt < NQT; tt++) meta[bh * NQT + tt] = make_int2(0, 0);
    for (int b = 0; b < 8; b++) {
      int t0 = bst[0][b] >> 6;
      int nt = ((tot[0][b] + 63) & ~63) >> 6;
      int ks = bst[1][b];
      int nkt = (tot[1][b] + 63) >> 6;
      for (int tt = t0; tt < t0 + nt; tt++)
        meta[bh * NQT + tt] = make_int2(ks, nkt);
    }
  }
}

// ---------------------------------------------------------------- attention
// Bucket-sorted flash attention. Block = (q-tile slot, h, b).
__global__ __launch_bounds__(256) void k_attn(const bf16* __restrict__ Q,
                                              const bf16* __restrict__ K,
                                              const bf16* __restrict__ V,
                                              const int* __restrict__ qidx,
                                              const int* __restrict__ kidx,
                                              const int2* __restrict__ meta,
                                              bf16* __restrict__ O) {
  constexpr int LDK = 72;  // 144B row stride: 16B-aligned, 2-way (free)
  __shared__ bf16 Kl[64 * LDK];
  __shared__ bf16 Vl[64 * LDK];   // [dim][key]
  __shared__ bf16 Pl[64 * LDK];
  __shared__ int kbl[64];
  __shared__ int qsl[64];
  const int t = threadIdx.x;
  const int qt = blockIdx.x, h = blockIdx.y, b = blockIdx.z;
  const int lane = t & 63, w = t >> 6;
  const int lm = lane & 15, qd = lane >> 4;
  const int bh = b * H_ + h;

  const int2 mt = meta[bh * NQT + qt];
  const int kstart = mt.x, nkt = mt.y;

  if (t < 64) qsl[t] = qidx[bh * QPAD + qt * 64 + t];
  __syncthreads();

  if (nkt == 0) {
#pragma unroll
    for (int r = 0; r < 4; r++) {
      int qs = qsl[w * 16 + qd * 4 + r];
      if (qs >= 0)
#pragma unroll
        for (int nb = 0; nb < 4; nb++)
          O[((b * S_ + qs) * H_ + h) * DK_ + nb * 16 + lm] = (bf16)0.f;
    }
    return;
  }

  int qrow = qsl[w * 16 + lm];
  const bf16* Qp = Q + (bh * S_ + (qrow < 0 ? 0 : qrow)) * DK_;
  bf16x8 qf0 = *(const bf16x8*)(Qp + qd * 8);
  bf16x8 qf1 = *(const bf16x8*)(Qp + 32 + qd * 8);

  f32x4 oacc[4];
  float mrun[4], lrun[4];
#pragma unroll
  for (int nb = 0; nb < 4; nb++) oacc[nb] = zero4();
#pragma unroll
  for (int r = 0; r < 4; r++) { mrun[r] = -1e30f; lrun[r] = 0.f; }

  const bf16* Kbase = K + bh * S_ * DK_;
  const bf16* Vbase = V + bh * S_ * DK_;
  const int* kix = kidx + bh * QPAD + kstart;

  for (int kt = 0; kt < nkt; kt++) {
    const int kt0 = kt * 64;
    __syncthreads();
    if (t < 64) kbl[t] = kix[kt0 + t];
#pragma unroll
    for (int ss = 0; ss < 2; ss++) {
      int seg = t + ss * 256;
      int row = seg >> 3, sg = seg & 7;
      int ki = kix[kt0 + row]; ki = ki < 0 ? 0 : ki;
      *(bf16x8*)&Kl[row * LDK + sg * 8] =
          *(const bf16x8*)&Kbase[ki * DK_ + sg * 8];
    }
#pragma unroll
    for (int ss = 0; ss < 2; ss++) {
      int seg = t + ss * 256;
      int vrow = seg & 63, vsg = seg >> 6;
      int ki = kix[kt0 + vrow]; ki = ki < 0 ? 0 : ki;
      bf16x8 v8 = *(const bf16x8*)&Vbase[ki * DK_ + vsg * 8];
#pragma unroll
      for (int j = 0; j < 8; j++) Vl[(vsg * 8 + j) * LDK + vrow] = v8[j];
    }
    __syncthreads();

    f32x4 sc[4];
#pragma unroll
    for (int nb = 0; nb < 4; nb++) {
      bf16x8 kf0 = *(const bf16x8*)&Kl[(nb * 16 + lm) * LDK + qd * 8];
      bf16x8 kf1 = *(const bf16x8*)&Kl[(nb * 16 + lm) * LDK + 32 + qd * 8];
      f32x4 z = zero4();
      z = mfma_bf16(qf0, kf0, z);
      z = mfma_bf16(qf1, kf1, z);
      sc[nb] = z;
    }
#pragma unroll
    for (int nb = 0; nb < 4; nb++) {
      bool valid = kbl[nb * 16 + lm] >= 0;
#pragma unroll
      for (int r = 0; r < 4; r++)
        sc[nb][r] = valid ? sc[nb][r] * 0.125f : -1e30f;
    }
    float mnew[4], alpha[4], rs[4];
#pragma unroll
    for (int r = 0; r < 4; r++) {
      float tm = fmaxf(fmaxf(sc[0][r], sc[1][r]), fmaxf(sc[2][r], sc[3][r]));
      tm = fmaxf(tm, __shfl_xor(tm, 1));
      tm = fmaxf(tm, __shfl_xor(tm, 2));
      tm = fmaxf(tm, __shfl_xor(tm, 4));
      tm = fmaxf(tm, __shfl_xor(tm, 8));
      mnew[r] = fmaxf(mrun[r], tm);
      alpha[r] = __expf(mrun[r] - mnew[r]);
      mrun[r] = mnew[r];
      rs[r] = 0.f;
    }
#pragma unroll
    for (int nb = 0; nb < 4; nb++)
#pragma unroll
      for (int r = 0; r < 4; r++) {
        float p = (sc[nb][r] > -1e29f) ? __expf(sc[nb][r] - mnew[r]) : 0.f;
        sc[nb][r] = p;
        rs[r] += p;
      }
#pragma unroll
    for (int r = 0; r < 4; r++) {
      float s = rs[r];
      s += __shfl_xor(s, 1);
      s += __shfl_xor(s, 2);
      s += __shfl_xor(s, 4);
      s += __shfl_xor(s, 8);
      lrun[r] = lrun[r] * alpha[r] + s;
    }
#pragma unroll
    for (int nb = 0; nb < 4; nb++)
#pragma unroll
      for (int r = 0; r < 4; r++) oacc[nb][r] *= alpha[r];
#pragma unroll
    for (int nb = 0; nb < 4; nb++)
#pragma unroll
      for (int r = 0; r < 4; r++)
        Pl[(w * 16 + qd * 4 + r) * LDK + nb * 16 + lm] = (bf16)sc[nb][r];
    __syncthreads();
    bf16x8 pa0 = *(const bf16x8*)&Pl[(w * 16 + lm) * LDK + qd * 8];
    bf16x8 pa1 = *(const bf16x8*)&Pl[(w * 16 + lm) * LDK + 32 + qd * 8];
#pragma unroll
    for (int nb = 0; nb < 4; nb++) {
      bf16x8 vf0 = *(const bf16x8*)&Vl[(nb * 16 + lm) * LDK + qd * 8];
      bf16x8 vf1 = *(const bf16x8*)&Vl[(nb * 16 + lm) * LDK + 32 + qd * 8];
      oacc[nb] = mfma_bf16(pa0, vf0, oacc[nb]);
      oacc[nb] = mfma_bf16(pa1, vf1, oacc[nb]);
    }
  }
#pragma unroll
  for (int r = 0; r < 4; r++) {
    int qs = qsl[w * 16 + qd * 4 + r];
    if (qs < 0) continue;
    float l = lrun[r];
    float inv = (l > 0.f) ? 1.f / l : 0.f;
#pragma unroll
    for (int nb = 0; nb < 4; nb++)
      O[((b * S_ + qs) * H_ + h) * DK_ + nb * 16 + lm] = (bf16)(oacc[nb][r] * inv);
  }
}

// ---------------------------------------------------------------- out GEMM
// C[m][n] = sum_k A[m][k]*Bt[n][k] + bias[n] -> fp32; 64x128 tile (512 blocks)
__global__ __launch_bounds__(256) void k_gout(const bf16* __restrict__ A,
                                              const bf16* __restrict__ Bt,
                                              const float* __restrict__ bias,
                                              float* __restrict__ out) {
  __shared__ __align__(16) bf16 Al[64 * 32];
  __shared__ __align__(16) bf16 Bl[128 * 32];
  const int t = threadIdx.x;
  const int lane = t & 63, w = t >> 6;
  const int lm = lane & 15, qd = lane >> 4;
  const int srow = lane >> 2, sseg = lane & 3;
  const int m0 = blockIdx.x * 64, n0 = blockIdx.y * 128;
  const int wm = w >> 1, wn = w & 1;

  f32x4 acc[2][4];
#pragma unroll
  for (int i = 0; i < 2; i++)
#pragma unroll
    for (int j = 0; j < 4; j++) acc[i][j] = zero4();

  for (int k0 = 0; k0 < D_; k0 += 32) {
    __syncthreads();
    load_lds16(&A[(m0 + w * 16 + srow) * D_ + k0 + sseg * 8],
               &Al[(w * 16) * 32]);
    load_lds16(&Bt[(n0 + w * 16 + srow) * D_ + k0 + sseg * 8],
               &Bl[(w * 16) * 32]);
    load_lds16(&Bt[(n0 + 64 + w * 16 + srow) * D_ + k0 + sseg * 8],
               &Bl[(64 + w * 16) * 32]);
    __syncthreads();
    bf16x8 af[2], bfr[4];
#pragma unroll
    for (int i = 0; i < 2; i++)
      af[i] = *(const bf16x8*)&Al[(wm * 32 + i * 16 + lm) * 32 + qd * 8];
#pragma unroll
    for (int j = 0; j < 4; j++)
      bfr[j] = *(const bf16x8*)&Bl[(wn * 64 + j * 16 + lm) * 32 + qd * 8];
#pragma unroll
    for (int i = 0; i < 2; i++)
#pragma unroll
      for (int j = 0; j < 4; j++) acc[i][j] = mfma_bf16(af[i], bfr[j], acc[i][j]);
  }
#pragma unroll
  for (int j = 0; j < 4; j++) {
    int n = n0 + wn * 64 + j * 16 + lm;
    float bv = bias[n];
#pragma unroll
    for (int i = 0; i < 2; i++) {
      int mbase = m0 + wm * 32 + i * 16 + qd * 4;
#pragma unroll
      for (int r = 0; r < 4; r++)
        out[(mbase + r) * D_ + n] = acc[i][j][r] + bv;
    }
  }
}

// ---------------------------------------------------------------- launch
extern "C" void kernel_launch(void* const* d_in, const int* in_sizes, int n_in,
                              void* d_out, int out_size, void* d_ws, size_t ws_size,
                              hipStream_t stream) {
  (void)in_sizes; (void)n_in; (void)out_size; (void)ws_size;
  const float* x  = (const float*)d_in[0];
  const float* Wq = (const float*)d_in[1];
  const float* bq = (const float*)d_in[2];
  const float* Wk = (const float*)d_in[3];
  const float* bk = (const float*)d_in[4];
  const float* Wv = (const float*)d_in[5];
  const float* bv = (const float*)d_in[6];
  const float* Wo = (const float*)d_in[7];
  const float* bo = (const float*)d_in[8];
  const float* R  = (const float*)d_in[9];

  char* ws = (char*)d_ws;
  bf16*  xh   = (bf16*)(ws + 0);          // 8 MB
  bf16*  Qb   = (bf16*)(ws + 8388608);    // 8 MB  [B,H,S,DK]
  bf16*  Kb   = (bf16*)(ws + 16777216);   // 8 MB  [B,H,S,DK]
  bf16*  Vb   = (bf16*)(ws + 25165824);   // 8 MB  [B,H,S,DK]
  bf16*  Ob   = (bf16*)(ws + 33554432);   // 8 MB  [B,S,H,DK]
  bf16*  Wtq  = (bf16*)(ws + 41943040);   // 2 MB each
  bf16*  Wtk  = (bf16*)(ws + 44040192);
  bf16*  Wtv  = (bf16*)(ws + 46137344);
  bf16*  Wto  = (bf16*)(ws + 48234496);
  int*   qbuf = (int*)(ws + 51380224);    // 256 KB each
  int*   kbuf = (int*)(ws + 51642368);
  float* bt   = (float*)(ws + 51904512);  // 1 KB
  bf16*  Pth  = (bf16*)(ws + 51905536);   // 512 KB each
  bf16*  Ptm  = (bf16*)(ws + 52429824);
  bf16*  Ptl  = (bf16*)(ws + 52954112);
  int*   qidxp= (int*)(ws + 53478400);    // 320 KB each
  int*   kidxp= (int*)(ws + 53806080);
  int2*  meta = (int2*)(ws + 54133760);   // 10 KB
  float* Lpart= (float*)(ws + 67108864);  // [64MB,80MB): 4 x 4MB fp32 partials
  bf16*  xm   = (bf16*)(ws + 83886080);   // [80MB,88MB)
  bf16*  xl   = (bf16*)(ws + 92274688);   // [88MB,96MB); ws >= 256 MB

  k_prep<<<dim3(16, 16, 6), dim3(256), 0, stream>>>(
      Wq, Wk, Wv, Wo, x, bq, bk, R, Wtq, Wtk, Wtv, Wto, xh, xm, xl,
      Pth, Ptm, Ptl, bt);

  k_main<<<dim3(64, 40), dim3(256), 0, stream>>>(
      xh, xm, xl, Wtq, Wtk, Wtv, bq, bk, bv, Pth, Ptm, Ptl, Qb, Kb, Vb, Lpart);

  k_amax<<<dim3(256), dim3(256), 0, stream>>>(Lpart, bt, qbuf, kbuf);

  k_sort<<<dim3(32), dim3(256), 0, stream>>>(qbuf, kbuf, qidxp, kidxp, meta);

  k_attn<<<dim3(NQT, H_, B_), dim3(256), 0, stream>>>(Qb, Kb, Vb, qidxp, kidxp,
                                                      meta, Ob);

  k_gout<<<dim3(64, 8), dim3(256), 0, stream>>>(Ob, Wto, bo, (float*)d_out);
}

// Round 9
// 217.719 us; speedup vs baseline: 2.1391x; 1.0129x over previous
//
#include <hip/hip_runtime.h>
#include <hip/hip_bf16.h>

// LSH Attention, MI355X gfx950.  6-dispatch pipeline:
//  1) k_prep  (z-branch): transW x4, x->bf16 cast, P=W@R^T fold + 3-split,
//     bterm
//  2) k_main  (y-branch): Q/K/V projection GEMM (m97-style 128x128,
//     global_load_lds width-16; Q prescaled by 0.125 = 1/sqrt(DK), exact)
//     + bucket-logit GEMM partials (6-term split-bf16, K-split x4; x loaded
//     sync fp32 + split3 in-register -- R8 showed all-async 6-stream staging
//     serializes the LDS-DMA queue and LOSES 19us vs this mix)
//  3) k_amax: deterministic fixed-order partial reduction + bterm + argmax
//  4) k_sort: per-(b,h) counting sort by bucket (wave-parallel prefix scan)
//  5) k_attn: bucket-sorted flash attention, double-buffered K/V (1 barrier
//     per tile; P-relayout is wave-private so needs no barrier)
//  6) k_gout: output GEMM 64x128 tiles -> fp32 d_out
//
// MFMA 16x16x32 bf16 layouts (verified in guide):
//  A: lane holds A[m=lane&15][k=(lane>>4)*8+j]
//  B: lane holds B[k=(lane>>4)*8+j][n=lane&15]
//  C/D: lane holds D[m=(lane>>4)*4+r][n=lane&15]

typedef __bf16 bf16;
typedef __bf16 bf16x8 __attribute__((ext_vector_type(8)));
typedef __bf16 bf16x4 __attribute__((ext_vector_type(4)));
typedef float f32x4 __attribute__((ext_vector_type(4)));

#define DEV static __device__ __forceinline__

DEV f32x4 zero4() { f32x4 z; z[0]=0.f; z[1]=0.f; z[2]=0.f; z[3]=0.f; return z; }

DEV f32x4 mfma_bf16(bf16x8 a, bf16x8 b, f32x4 c) {
  return __builtin_amdgcn_mfma_f32_16x16x32_bf16(a, b, c, 0, 0, 0);
}

// async global->LDS, 16B/lane; LDS dest = wave-uniform base + lane*16
DEV void load_lds16(const bf16* g, bf16* l) {
  __builtin_amdgcn_global_load_lds(
      (const __attribute__((address_space(1))) void*)g,
      (__attribute__((address_space(3))) void*)l, 16, 0, 0);
}

DEV void split3(float f, bf16& h, bf16& m, bf16& l) {
  h = (bf16)f;
  float rm = f - (float)h;
  m = (bf16)rm;
  l = (bf16)(rm - (float)m);
}

#define B_  2
#define S_  2048
#define D_  1024
#define H_  16
#define NH_ 8
#define DK_ 64
#define M_  4096   // B_*S_
#define QPAD 2560  // 2048 + 8*64 (per-bucket 64-alignment padding)
#define NQT  40    // max q-tiles per (b,h): 32 + 8

// ---------------------------------------------------------------- prep
// z<4: transW (64x64 transpose+cast); z=4: x->bf16; z=5 (64 blocks):
// P[d][c]=W(:,h*64:)@R[n]^T fold, 3-split transposed write, + bterm.
__global__ __launch_bounds__(256) void k_prep(
    const float* __restrict__ Wq, const float* __restrict__ Wk,
    const float* __restrict__ Wv, const float* __restrict__ Wo,
    const float* __restrict__ x, const float* __restrict__ bq,
    const float* __restrict__ bk, const float* __restrict__ R,
    bf16* __restrict__ Wtq, bf16* __restrict__ Wtk,
    bf16* __restrict__ Wtv, bf16* __restrict__ Wto,
    bf16* __restrict__ xh, bf16* __restrict__ Pth, bf16* __restrict__ Ptm,
    bf16* __restrict__ Ptl, float* __restrict__ bt) {
  __shared__ float tile[64][65];
  __shared__ float Rl[512];
  const int t = threadIdx.x;
  const int z = blockIdx.z;
  if (z < 4) {
    const float* W = z == 0 ? Wq : z == 1 ? Wk : z == 2 ? Wv : Wo;
    bf16* Wt = z == 0 ? Wtq : z == 1 ? Wtk : z == 2 ? Wtv : Wto;
    int k0 = blockIdx.x * 64, n0 = blockIdx.y * 64;
    int c = t & 63, r4 = t >> 6;
#pragma unroll
    for (int i = 0; i < 16; i++) {
      int r = r4 * 16 + i;
      tile[r][c] = W[(k0 + r) * D_ + n0 + c];
    }
    __syncthreads();
#pragma unroll
    for (int i = 0; i < 16; i++) {
      int r = r4 * 16 + i;
      Wt[(n0 + r) * D_ + k0 + c] = (bf16)tile[c][r];
    }
  } else if (z == 4) {
    int bid = blockIdx.y * 16 + blockIdx.x;
    int base = bid * 16384 + t * 4;
#pragma unroll 4
    for (int it = 0; it < 16; it++) {
      int i = base + it * 1024;
      f32x4 v = *(const f32x4*)(x + i);
      bf16x4 o;
#pragma unroll
      for (int j = 0; j < 4; j++) o[j] = (bf16)v[j];
      *(bf16x4*)(xh + i) = o;
    }
  } else {
    int bid = blockIdx.y * 16 + blockIdx.x;
    if (bid >= 64) return;
    Rl[t] = R[t];
    Rl[t + 256] = R[t + 256];
    __syncthreads();
    const int d0 = bid * 16;
    const int sel = t >> 7, hn = t & 127, h = hn >> 3, n = hn & 7;
    const float* W = sel ? Wk : Wq;
    const float* Rr = &Rl[n * 64];
    bf16x8 vh[2], vm[2], vl[2];
#pragma unroll
    for (int dl = 0; dl < 16; dl++) {
      const float* wr = W + (d0 + dl) * D_ + h * 64;
      float acc = 0.f;
#pragma unroll
      for (int k = 0; k < 64; k += 4) {
        f32x4 wv = *(const f32x4*)(wr + k);
        acc += (wv[0] * Rr[k] + wv[1] * Rr[k + 1]) +
               (wv[2] * Rr[k + 2] + wv[3] * Rr[k + 3]);
      }
      bf16 hh, mm, ll;
      split3(acc, hh, mm, ll);
      vh[dl >> 3][dl & 7] = hh;
      vm[dl >> 3][dl & 7] = mm;
      vl[dl >> 3][dl & 7] = ll;
    }
    *(bf16x8*)&Pth[t * D_ + d0] = vh[0];
    *(bf16x8*)&Pth[t * D_ + d0 + 8] = vh[1];
    *(bf16x8*)&Ptm[t * D_ + d0] = vm[0];
    *(bf16x8*)&Ptm[t * D_ + d0 + 8] = vm[1];
    *(bf16x8*)&Ptl[t * D_ + d0] = vl[0];
    *(bf16x8*)&Ptl[t * D_ + d0 + 8] = vl[1];
    if (bid == 0) {
      const float* bb = sel ? bk : bq;
      float acc = 0.f;
#pragma unroll 8
      for (int k = 0; k < 64; k++) acc += bb[h * 64 + k] * Rr[k];
      bt[t] = acc;
    }
  }
}

// ---------------------------------------------------------------- main fused
// y<24 (x<32): QKV projection GEMM, 128x128 tile, mat=y>>3, n0=(y&7)*128.
// Q (mat 0) prescaled by 0.125 (exact pow2; removes per-tile mul in attn).
// y in 24..39: bucket-logit GEMM partial, chunk=(y-24)>>2, n0=((y-24)&3)*64,
// m0=x*64, K in [chunk*256, +256): 6-term split-bf16, x sync-loaded fp32 +
// in-register split3 (overlaps the 3 async P streams), fp32 partial->Lpart.
__global__ __launch_bounds__(256) void k_main(
    const float* __restrict__ x, const bf16* __restrict__ xh,
    const bf16* __restrict__ Wtq, const bf16* __restrict__ Wtk,
    const bf16* __restrict__ Wtv, const float* __restrict__ bq,
    const float* __restrict__ bk, const float* __restrict__ bv,
    const bf16* __restrict__ Pth, const bf16* __restrict__ Ptm,
    const bf16* __restrict__ Ptl,
    bf16* __restrict__ Qb, bf16* __restrict__ Kb, bf16* __restrict__ Vb,
    float* __restrict__ Lpart) {
  __shared__ __align__(16) bf16 SA[3][2048];
  __shared__ __align__(16) bf16 SB[3][2048];
  const int t = threadIdx.x;
  const int lane = t & 63, w = t >> 6;
  const int lm = lane & 15, qd = lane >> 4;
  const int srow = lane >> 2, sseg = lane & 3;  // 16 rows x 4 segs per instr

  if (blockIdx.y < 24) {  // ---------------- QKV GEMM
    if (blockIdx.x >= 32) return;
    bf16* Al = &SA[0][0];  // 128x32 contiguous
    bf16* Bl = &SB[0][0];
    const int m0 = blockIdx.x * 128;
    const int mat = blockIdx.y >> 3;
    const int n0 = (blockIdx.y & 7) * 128;
    const bf16* Bt = mat == 0 ? Wtq : (mat == 1 ? Wtk : Wtv);
    const float* bias = mat == 0 ? bq : (mat == 1 ? bk : bv);
    bf16* out = mat == 0 ? Qb : (mat == 1 ? Kb : Vb);
    const float osc = mat == 0 ? 0.125f : 1.f;  // fold 1/sqrt(DK) into Q
    const int wm = w >> 1, wn = w & 1;

    f32x4 acc[4][4];
#pragma unroll
    for (int i = 0; i < 4; i++)
#pragma unroll
      for (int j = 0; j < 4; j++) acc[i][j] = zero4();

    for (int k0 = 0; k0 < D_; k0 += 32) {
      __syncthreads();
      load_lds16(&xh[(m0 + w * 16 + srow) * D_ + k0 + sseg * 8],
                 &Al[(w * 16) * 32]);
      load_lds16(&xh[(m0 + 64 + w * 16 + srow) * D_ + k0 + sseg * 8],
                 &Al[(64 + w * 16) * 32]);
      load_lds16(&Bt[(n0 + w * 16 + srow) * D_ + k0 + sseg * 8],
                 &Bl[(w * 16) * 32]);
      load_lds16(&Bt[(n0 + 64 + w * 16 + srow) * D_ + k0 + sseg * 8],
                 &Bl[(64 + w * 16) * 32]);
      __syncthreads();
      bf16x8 af[4], bfr[4];
#pragma unroll
      for (int i = 0; i < 4; i++)
        af[i] = *(const bf16x8*)&Al[(wm * 64 + i * 16 + lm) * 32 + qd * 8];
#pragma unroll
      for (int j = 0; j < 4; j++)
        bfr[j] = *(const bf16x8*)&Bl[(wn * 64 + j * 16 + lm) * 32 + qd * 8];
#pragma unroll
      for (int i = 0; i < 4; i++)
#pragma unroll
        for (int j = 0; j < 4; j++)
          acc[i][j] = mfma_bf16(af[i], bfr[j], acc[i][j]);
    }
#pragma unroll
    for (int j = 0; j < 4; j++) {
      int n = n0 + wn * 64 + j * 16 + lm;
      float bv2 = bias[n];
#pragma unroll
      for (int i = 0; i < 4; i++) {
        int mbase = m0 + wm * 64 + i * 16 + qd * 4;
#pragma unroll
        for (int r = 0; r < 4; r++) {
          int m = mbase + r;
          int bb = m >> 11, s = m & 2047, hh = n >> 6, d = n & 63;
          out[((bb * H_ + hh) * S_ + s) * DK_ + d] =
              (bf16)((acc[i][j][r] + bv2) * osc);
        }
      }
    }
  } else {  // ---------------- bucket-logit GEMM partial (K-split x4)
    const int yy = blockIdx.y - 24;
    const int chunk = yy >> 2;
    const int m0 = blockIdx.x * 64, n0 = (yy & 3) * 64;
    f32x4 acc[4];
#pragma unroll
    for (int nb = 0; nb < 4; nb++) acc[nb] = zero4();
    const int xrow = t >> 2, xc8 = (t & 3) * 8;
    const int kbeg = chunk * 256, kend = kbeg + 256;

    for (int k0 = kbeg; k0 < kend; k0 += 32) {
      __syncthreads();
      // x fp32 -> 3-way bf16 split in-register -> LDS (overlaps async below)
      f32x4 xa = *(const f32x4*)&x[(m0 + xrow) * D_ + k0 + xc8];
      f32x4 xb2 = *(const f32x4*)&x[(m0 + xrow) * D_ + k0 + xc8 + 4];
      // P splits: async, wave w stages quarter w of each array
      load_lds16(&Pth[(n0 + w * 16 + srow) * D_ + k0 + sseg * 8],
                 &SB[0][(w * 16) * 32]);
      load_lds16(&Ptm[(n0 + w * 16 + srow) * D_ + k0 + sseg * 8],
                 &SB[1][(w * 16) * 32]);
      load_lds16(&Ptl[(n0 + w * 16 + srow) * D_ + k0 + sseg * 8],
                 &SB[2][(w * 16) * 32]);
      bf16x8 vh, vm, vl;
#pragma unroll
      for (int j = 0; j < 4; j++) {
        bf16 hh, mm, ll;
        split3(xa[j], hh, mm, ll);
        vh[j] = hh; vm[j] = mm; vl[j] = ll;
        split3(xb2[j], hh, mm, ll);
        vh[4 + j] = hh; vm[4 + j] = mm; vl[4 + j] = ll;
      }
      *(bf16x8*)&SA[0][xrow * 32 + xc8] = vh;
      *(bf16x8*)&SA[1][xrow * 32 + xc8] = vm;
      *(bf16x8*)&SA[2][xrow * 32 + xc8] = vl;
      __syncthreads();
      bf16x8 af[3], bfr[3][4];
#pragma unroll
      for (int i3 = 0; i3 < 3; i3++) {
        af[i3] = *(const bf16x8*)&SA[i3][(w * 16 + lm) * 32 + qd * 8];
#pragma unroll
        for (int nb = 0; nb < 4; nb++)
          bfr[i3][nb] = *(const bf16x8*)&SB[i3][(nb * 16 + lm) * 32 + qd * 8];
      }
#pragma unroll
      for (int nb = 0; nb < 4; nb++) {
        f32x4 a = acc[nb];
        a = mfma_bf16(af[0], bfr[0][nb], a);  // hh
        a = mfma_bf16(af[0], bfr[1][nb], a);  // hm
        a = mfma_bf16(af[1], bfr[0][nb], a);  // mh
        a = mfma_bf16(af[0], bfr[2][nb], a);  // hl
        a = mfma_bf16(af[2], bfr[0][nb], a);  // lh
        a = mfma_bf16(af[1], bfr[1][nb], a);  // mm
        acc[nb] = a;
      }
    }
    // write fp32 partial tile (coalesced 64B runs per quad-row)
    float* Lp = Lpart + chunk * (M_ * 256);
#pragma unroll
    for (int nb = 0; nb < 4; nb++)
#pragma unroll
      for (int r = 0; r < 4; r++)
        Lp[(m0 + w * 16 + qd * 4 + r) * 256 + n0 + nb * 16 + lm] = acc[nb][r];
  }
}

// ---------------------------------------------------------------- amax
// Sum 4 K-chunk partials in FIXED order (deterministic), + bterm, argmax
// per 8-group -> qb/kb.  Block = 16 rows; thread t: row=t>>4, 16 cols.
__global__ __launch_bounds__(256) void k_amax(const float* __restrict__ Lpart,
                                              const float* __restrict__ bt,
                                              int* __restrict__ qb,
                                              int* __restrict__ kb) {
  const int t = threadIdx.x;
  const int row = blockIdx.x * 16 + (t >> 4);
  const int c0 = (t & 15) * 16;
  const float* L0 = Lpart + row * 256 + c0;
  float v[16];
#pragma unroll
  for (int c4 = 0; c4 < 16; c4 += 4) {
    f32x4 p0 = *(const f32x4*)(L0 + c4);
    f32x4 p1 = *(const f32x4*)(L0 + 1 * M_ * 256 + c4);
    f32x4 p2 = *(const f32x4*)(L0 + 2 * M_ * 256 + c4);
    f32x4 p3 = *(const f32x4*)(L0 + 3 * M_ * 256 + c4);
    f32x4 bv = *(const f32x4*)(bt + c0 + c4);
#pragma unroll
    for (int j = 0; j < 4; j++)
      v[c4 + j] = (((p0[j] + p1[j]) + p2[j]) + p3[j]) + bv[j];
  }
  const int bb = row >> 11, s = row & 2047;
#pragma unroll
  for (int g2 = 0; g2 < 2; g2++) {
    float best = v[g2 * 8];
    int bi = 0;
#pragma unroll
    for (int n = 1; n < 8; n++)
      if (v[g2 * 8 + n] > best) { best = v[g2 * 8 + n]; bi = n; }  // first-max
    int g = (c0 >> 3) + g2;           // 0..31
    int sel = g >> 4, head = g & 15;
    (sel ? kb : qb)[(bb * H_ + head) * S_ + s] = bi;
  }
}

// ---------------------------------------------------------------- bucket sort
// One block per (b,h). Stable counting sort by bucket; wave-parallel scan.
__global__ __launch_bounds__(256) void k_sort(const int* __restrict__ qb,
                                              const int* __restrict__ kb,
                                              int* __restrict__ qidx,
                                              int* __restrict__ kidx,
                                              int2* __restrict__ meta) {
  __shared__ int cnt[8][257];
  __shared__ int bst[2][9];
  __shared__ int tot[2][8];
  const int bh = blockIdx.x;
  const int t = threadIdx.x;
  const int lane = t & 63, w = t >> 6;
  for (int which = 0; which < 2; which++) {
    const int* src = (which ? kb : qb) + bh * S_;
    int* dst = (which ? kidx : qidx) + bh * QPAD;
    for (int i = t; i < QPAD; i += 256) dst[i] = -1;
    int vals[8];
    int lc[8] = {0, 0, 0, 0, 0, 0, 0, 0};
#pragma unroll
    for (int j = 0; j < 8; j++) { int b = src[t * 8 + j]; vals[j] = b; lc[b]++; }
#pragma unroll
    for (int b = 0; b < 8; b++) cnt[b][t] = lc[b];
    __syncthreads();
    // wave-parallel exclusive scan over 256 thread-slots, 2 buckets/wave
    for (int bb = w; bb < 8; bb += 4) {
      int carry = 0;
      for (int round = 0; round < 4; round++) {
        int v = cnt[bb][round * 64 + lane];
        int inc = v;
#pragma unroll
        for (int off = 1; off < 64; off <<= 1) {
          int u = __shfl_up(inc, off);
          if (lane >= off) inc += u;
        }
        cnt[bb][round * 64 + lane] = carry + inc - v;
        carry += __shfl(inc, 63);
      }
      if (lane == 0) tot[which][bb] = carry;
    }
    __syncthreads();
    if (t == 0) {
      int pos = 0;
      for (int b = 0; b < 8; b++) {
        bst[which][b] = pos;
        pos += (tot[which][b] + 63) & ~63;
      }
      bst[which][8] = pos;
    }
    __syncthreads();
    int run2[8] = {0, 0, 0, 0, 0, 0, 0, 0};
#pragma unroll
    for (int j = 0; j < 8; j++) {
      int b = vals[j];
      int pos = bst[which][b] + cnt[b][t] + run2[b]++;
      dst[pos] = t * 8 + j;
    }
    __syncthreads();
  }
  if (t == 0) {
    for (int tt = 0; tt < NQT; tt++) meta[bh * NQT + tt] = make_int2(0, 0);
    for (int b = 0; b < 8; b++) {
      int t0 = bst[0][b] >> 6;
      int nt = ((tot[0][b] + 63) & ~63) >> 6;
      int ks = bst[1][b];
      int nkt = (tot[1][b] + 63) >> 6;
      for (int tt = t0; tt < t0 + nt; tt++)
        meta[bh * NQT + tt] = make_int2(ks, nkt);
    }
  }
}

// ---------------------------------------------------------------- attention
// Bucket-sorted flash attention, double-buffered K/V. Block = (q-tile,h,b).
// One barrier per key-tile: next-tile gathers are issued into registers at
// loop top (overlap compute), written to the OTHER LDS buffer after PV.
// P-relayout LDS region is wave-private (rows w*16..w*16+15) -> no barrier.
__global__ __launch_bounds__(256) void k_attn(const bf16* __restrict__ Q,
                                              const bf16* __restrict__ K,
                                              const bf16* __restrict__ V,
                                              const int* __restrict__ qidx,
                                              const int* __restrict__ kidx,
                                              const int2* __restrict__ meta,
                                              bf16* __restrict__ O) {
  constexpr int LDK = 72;  // 144B row stride: 16B-aligned, 2-way (free)
  __shared__ bf16 Kl[2][64 * LDK];
  __shared__ bf16 Vl[2][64 * LDK];   // [dim][key]
  __shared__ bf16 Pl[64 * LDK];
  __shared__ int kbl[2][64];
  __shared__ int qsl[64];
  const int t = threadIdx.x;
  const int qt = blockIdx.x, h = blockIdx.y, b = blockIdx.z;
  const int lane = t & 63, w = t >> 6;
  const int lm = lane & 15, qd = lane >> 4;
  const int bh = b * H_ + h;

  const int2 mt = meta[bh * NQT + qt];
  const int kstart = mt.x, nkt = mt.y;

  if (t < 64) qsl[t] = qidx[bh * QPAD + qt * 64 + t];
  __syncthreads();

  if (nkt == 0) {
#pragma unroll
    for (int r = 0; r < 4; r++) {
      int qs = qsl[w * 16 + qd * 4 + r];
      if (qs >= 0)
#pragma unroll
        for (int nb = 0; nb < 4; nb++)
          O[((b * S_ + qs) * H_ + h) * DK_ + nb * 16 + lm] = (bf16)0.f;
    }
    return;
  }

  int qrow = qsl[w * 16 + lm];
  const bf16* Qp = Q + (bh * S_ + (qrow < 0 ? 0 : qrow)) * DK_;
  bf16x8 qf0 = *(const bf16x8*)(Qp + qd * 8);
  bf16x8 qf1 = *(const bf16x8*)(Qp + 32 + qd * 8);

  f32x4 oacc[4];
  float mrun[4], lrun[4];
#pragma unroll
  for (int nb = 0; nb < 4; nb++) oacc[nb] = zero4();
#pragma unroll
  for (int r = 0; r < 4; r++) { mrun[r] = -1e30f; lrun[r] = 0.f; }

  const bf16* Kbase = K + bh * S_ * DK_;
  const bf16* Vbase = V + bh * S_ * DK_;
  const int* kix = kidx + bh * QPAD + kstart;

  // staging geometry (per thread, 2 segments each for K and V)
  const int krow0 = t >> 3, ksg = t & 7;          // K: row, 16B seg
  const int krow1 = (t + 256) >> 3;
  const int vrow0 = t & 63, vsg0 = t >> 6;        // V: key, 16B dim-seg
  const int vsg1 = vsg0 + 4;

  // prologue: stage tile 0 into buffer 0
  {
    if (t < 64) kbl[0][t] = kix[t];
    int ki0 = kix[krow0]; ki0 = ki0 < 0 ? 0 : ki0;
    int ki1 = kix[krow1]; ki1 = ki1 < 0 ? 0 : ki1;
    *(bf16x8*)&Kl[0][krow0 * LDK + ksg * 8] =
        *(const bf16x8*)&Kbase[ki0 * DK_ + ksg * 8];
    *(bf16x8*)&Kl[0][krow1 * LDK + ksg * 8] =
        *(const bf16x8*)&Kbase[ki1 * DK_ + ksg * 8];
    int kv = kix[vrow0]; kv = kv < 0 ? 0 : kv;
    bf16x8 v0 = *(const bf16x8*)&Vbase[kv * DK_ + vsg0 * 8];
    bf16x8 v1 = *(const bf16x8*)&Vbase[kv * DK_ + vsg1 * 8];
#pragma unroll
    for (int j = 0; j < 8; j++) {
      Vl[0][(vsg0 * 8 + j) * LDK + vrow0] = v0[j];
      Vl[0][(vsg1 * 8 + j) * LDK + vrow0] = v1[j];
    }
  }
  __syncthreads();

  for (int kt = 0; kt < nkt; kt++) {
    const int cur = kt & 1, nxt = cur ^ 1;
    const bool more = (kt + 1 < nkt);
    // issue next-tile gathers into registers (overlaps with compute below)
    bf16x8 kn0, kn1, vn0, vn1;
    int kbn = 0;
    if (more) {
      const int kt1 = (kt + 1) * 64;
      if (t < 64) kbn = kix[kt1 + t];
      int ki0 = kix[kt1 + krow0]; ki0 = ki0 < 0 ? 0 : ki0;
      int ki1 = kix[kt1 + krow1]; ki1 = ki1 < 0 ? 0 : ki1;
      kn0 = *(const bf16x8*)&Kbase[ki0 * DK_ + ksg * 8];
      kn1 = *(const bf16x8*)&Kbase[ki1 * DK_ + ksg * 8];
      int kv = kix[kt1 + vrow0]; kv = kv < 0 ? 0 : kv;
      vn0 = *(const bf16x8*)&Vbase[kv * DK_ + vsg0 * 8];
      vn1 = *(const bf16x8*)&Vbase[kv * DK_ + vsg1 * 8];
    }

    // scores 16x64 per wave (C-layout: row=qd*4+r, col=nb*16+lm)
    f32x4 sc[4];
#pragma unroll
    for (int nb = 0; nb < 4; nb++) {
      bf16x8 kf0 = *(const bf16x8*)&Kl[cur][(nb * 16 + lm) * LDK + qd * 8];
      bf16x8 kf1 = *(const bf16x8*)&Kl[cur][(nb * 16 + lm) * LDK + 32 + qd * 8];
      f32x4 z = zero4();
      z = mfma_bf16(qf0, kf0, z);
      z = mfma_bf16(qf1, kf1, z);
      sc[nb] = z;
    }
    // sentinel slots (bucket padding) -> masked (Q already prescaled 1/8)
#pragma unroll
    for (int nb = 0; nb < 4; nb++) {
      bool valid = kbl[cur][nb * 16 + lm] >= 0;
#pragma unroll
      for (int r = 0; r < 4; r++)
        sc[nb][r] = valid ? sc[nb][r] : -1e30f;
    }
    float mnew[4], alpha[4], rs[4];
#pragma unroll
    for (int r = 0; r < 4; r++) {
      float tm = fmaxf(fmaxf(sc[0][r], sc[1][r]), fmaxf(sc[2][r], sc[3][r]));
      tm = fmaxf(tm, __shfl_xor(tm, 1));
      tm = fmaxf(tm, __shfl_xor(tm, 2));
      tm = fmaxf(tm, __shfl_xor(tm, 4));
      tm = fmaxf(tm, __shfl_xor(tm, 8));
      mnew[r] = fmaxf(mrun[r], tm);
      alpha[r] = __expf(mrun[r] - mnew[r]);
      mrun[r] = mnew[r];
      rs[r] = 0.f;
    }
#pragma unroll
    for (int nb = 0; nb < 4; nb++)
#pragma unroll
      for (int r = 0; r < 4; r++) {
        float p = (sc[nb][r] > -1e29f) ? __expf(sc[nb][r] - mnew[r]) : 0.f;
        sc[nb][r] = p;
        rs[r] += p;
      }
#pragma unroll
    for (int r = 0; r < 4; r++) {
      float s = rs[r];
      s += __shfl_xor(s, 1);
      s += __shfl_xor(s, 2);
      s += __shfl_xor(s, 4);
      s += __shfl_xor(s, 8);
      lrun[r] = lrun[r] * alpha[r] + s;
    }
#pragma unroll
    for (int nb = 0; nb < 4; nb++)
#pragma unroll
      for (int r = 0; r < 4; r++) oacc[nb][r] *= alpha[r];
    // P: C-layout -> A-layout via wave-private LDS rows (no barrier needed)
#pragma unroll
    for (int nb = 0; nb < 4; nb++)
#pragma unroll
      for (int r = 0; r < 4; r++)
        Pl[(w * 16 + qd * 4 + r) * LDK + nb * 16 + lm] = (bf16)sc[nb][r];
    bf16x8 pa0 = *(const bf16x8*)&Pl[(w * 16 + lm) * LDK + qd * 8];
    bf16x8 pa1 = *(const bf16x8*)&Pl[(w * 16 + lm) * LDK + 32 + qd * 8];
#pragma unroll
    for (int nb = 0; nb < 4; nb++) {
      bf16x8 vf0 = *(const bf16x8*)&Vl[cur][(nb * 16 + lm) * LDK + qd * 8];
      bf16x8 vf1 = *(const bf16x8*)&Vl[cur][(nb * 16 + lm) * LDK + 32 + qd * 8];
      oacc[nb] = mfma_bf16(pa0, vf0, oacc[nb]);
      oacc[nb] = mfma_bf16(pa1, vf1, oacc[nb]);
    }
    // commit next tile to the other buffer, then one barrier
    if (more) {
      if (t < 64) kbl[nxt][t] = kbn;
      *(bf16x8*)&Kl[nxt][krow0 * LDK + ksg * 8] = kn0;
      *(bf16x8*)&Kl[nxt][krow1 * LDK + ksg * 8] = kn1;
#pragma unroll
      for (int j = 0; j < 8; j++) {
        Vl[nxt][(vsg0 * 8 + j) * LDK + vrow0] = vn0[j];
        Vl[nxt][(vsg1 * 8 + j) * LDK + vrow0] = vn1[j];
      }
      __syncthreads();
    }
  }
  // epilogue: scatter O rows back to original positions
#pragma unroll
  for (int r = 0; r < 4; r++) {
    int qs = qsl[w * 16 + qd * 4 + r];
    if (qs < 0) continue;
    float l = lrun[r];
    float inv = (l > 0.f) ? 1.f / l : 0.f;
#pragma unroll
    for (int nb = 0; nb < 4; nb++)
      O[((b * S_ + qs) * H_ + h) * DK_ + nb * 16 + lm] = (bf16)(oacc[nb][r] * inv);
  }
}

// ---------------------------------------------------------------- out GEMM
// C[m][n] = sum_k A[m][k]*Bt[n][k] + bias[n] -> fp32; 64x128 tile (512 blocks)
__global__ __launch_bounds__(256) void k_gout(const bf16* __restrict__ A,
                                              const bf16* __restrict__ Bt,
                                              const float* __restrict__ bias,
                                              float* __restrict__ out) {
  __shared__ __align__(16) bf16 Al[64 * 32];
  __shared__ __align__(16) bf16 Bl[128 * 32];
  const int t = threadIdx.x;
  const int lane = t & 63, w = t >> 6;
  const int lm = lane & 15, qd = lane >> 4;
  const int srow = lane >> 2, sseg = lane & 3;
  const int m0 = blockIdx.x * 64, n0 = blockIdx.y * 128;
  const int wm = w >> 1, wn = w & 1;

  f32x4 acc[2][4];
#pragma unroll
  for (int i = 0; i < 2; i++)
#pragma unroll
    for (int j = 0; j < 4; j++) acc[i][j] = zero4();

  for (int k0 = 0; k0 < D_; k0 += 32) {
    __syncthreads();
    load_lds16(&A[(m0 + w * 16 + srow) * D_ + k0 + sseg * 8],
               &Al[(w * 16) * 32]);
    load_lds16(&Bt[(n0 + w * 16 + srow) * D_ + k0 + sseg * 8],
               &Bl[(w * 16) * 32]);
    load_lds16(&Bt[(n0 + 64 + w * 16 + srow) * D_ + k0 + sseg * 8],
               &Bl[(64 + w * 16) * 32]);
    __syncthreads();
    bf16x8 af[2], bfr[4];
#pragma unroll
    for (int i = 0; i < 2; i++)
      af[i] = *(const bf16x8*)&Al[(wm * 32 + i * 16 + lm) * 32 + qd * 8];
#pragma unroll
    for (int j = 0; j < 4; j++)
      bfr[j] = *(const bf16x8*)&Bl[(wn * 64 + j * 16 + lm) * 32 + qd * 8];
#pragma unroll
    for (int i = 0; i < 2; i++)
#pragma unroll
      for (int j = 0; j < 4; j++) acc[i][j] = mfma_bf16(af[i], bfr[j], acc[i][j]);
  }
#pragma unroll
  for (int j = 0; j < 4; j++) {
    int n = n0 + wn * 64 + j * 16 + lm;
    float bv = bias[n];
#pragma unroll
    for (int i = 0; i < 2; i++) {
      int mbase = m0 + wm * 32 + i * 16 + qd * 4;
#pragma unroll
      for (int r = 0; r < 4; r++)
        out[(mbase + r) * D_ + n] = acc[i][j][r] + bv;
    }
  }
}

// ---------------------------------------------------------------- launch
extern "C" void kernel_launch(void* const* d_in, const int* in_sizes, int n_in,
                              void* d_out, int out_size, void* d_ws, size_t ws_size,
                              hipStream_t stream) {
  (void)in_sizes; (void)n_in; (void)out_size; (void)ws_size;
  const float* x  = (const float*)d_in[0];
  const float* Wq = (const float*)d_in[1];
  const float* bq = (const float*)d_in[2];
  const float* Wk = (const float*)d_in[3];
  const float* bk = (const float*)d_in[4];
  const float* Wv = (const float*)d_in[5];
  const float* bv = (const float*)d_in[6];
  const float* Wo = (const float*)d_in[7];
  const float* bo = (const float*)d_in[8];
  const float* R  = (const float*)d_in[9];

  char* ws = (char*)d_ws;
  bf16*  xh   = (bf16*)(ws + 0);          // 8 MB
  bf16*  Qb   = (bf16*)(ws + 8388608);    // 8 MB  [B,H,S,DK] (prescaled 1/8)
  bf16*  Kb   = (bf16*)(ws + 16777216);   // 8 MB  [B,H,S,DK]
  bf16*  Vb   = (bf16*)(ws + 25165824);   // 8 MB  [B,H,S,DK]
  bf16*  Ob   = (bf16*)(ws + 33554432);   // 8 MB  [B,S,H,DK]
  bf16*  Wtq  = (bf16*)(ws + 41943040);   // 2 MB each
  bf16*  Wtk  = (bf16*)(ws + 44040192);
  bf16*  Wtv  = (bf16*)(ws + 46137344);
  bf16*  Wto  = (bf16*)(ws + 48234496);
  int*   qbuf = (int*)(ws + 51380224);    // 256 KB each
  int*   kbuf = (int*)(ws + 51642368);
  float* bt   = (float*)(ws + 51904512);  // 1 KB
  bf16*  Pth  = (bf16*)(ws + 51905536);   // 512 KB each
  bf16*  Ptm  = (bf16*)(ws + 52429824);
  bf16*  Ptl  = (bf16*)(ws + 52954112);
  int*   qidxp= (int*)(ws + 53478400);    // 320 KB each
  int*   kidxp= (int*)(ws + 53806080);
  int2*  meta = (int2*)(ws + 54133760);   // 10 KB
  float* Lpart= (float*)(ws + 67108864);  // [64MB,80MB): 4 x 4MB fp32 partials

  k_prep<<<dim3(16, 16, 6), dim3(256), 0, stream>>>(
      Wq, Wk, Wv, Wo, x, bq, bk, R, Wtq, Wtk, Wtv, Wto, xh,
      Pth, Ptm, Ptl, bt);

  k_main<<<dim3(64, 40), dim3(256), 0, stream>>>(
      x, xh, Wtq, Wtk, Wtv, bq, bk, bv, Pth, Ptm, Ptl, Qb, Kb, Vb, Lpart);

  k_amax<<<dim3(256), dim3(256), 0, stream>>>(Lpart, bt, qbuf, kbuf);

  k_sort<<<dim3(32), dim3(256), 0, stream>>>(qbuf, kbuf, qidxp, kidxp, meta);

  k_attn<<<dim3(NQT, H_, B_), dim3(256), 0, stream>>>(Qb, Kb, Vb, qidxp, kidxp,
                                                      meta, Ob);

  k_gout<<<dim3(64, 8), dim3(256), 0, stream>>>(Ob, Wto, bo, (float*)d_out);
}